// Round 1
// baseline (793.615 us; speedup 1.0000x reference)
//
#include <hip/hip_runtime.h>

#define EN 5
#define KT 3
#define BB 16
#define CC 128
#define HH 64
#define WW 64
#define HWP (HH*WW)      // 4096
#define DWC (2*CC)       // 256
#define NPAIR (BB*KT)    // 48
#define EPSLN 1e-6f

// ---------------- gate: top-3 per sample, counts, weights passthrough ----------------
__global__ void gate_kernel(const float* __restrict__ weights, float* __restrict__ gate_w,
                            int* __restrict__ pair_e, float* __restrict__ out_counts,
                            float* __restrict__ out_weights) {
  __shared__ int sel[NPAIR];
  int tid = threadIdx.x;
  if (tid < BB) {
    float w[EN];
    for (int e = 0; e < EN; e++) w[e] = weights[tid * EN + e];
    int ch[KT]; float cv[KT]; float sum = 0.f;
    for (int j = 0; j < KT; j++) {
      int best = -1; float bv = -3.4e38f;
      for (int e = 0; e < EN; e++) {
        bool used = false;
        for (int q = 0; q < j; q++) if (ch[q] == e) used = true;
        if (!used && w[e] > bv) { bv = w[e]; best = e; }
      }
      ch[j] = best; cv[j] = bv; sum += bv;
    }
    float inv = 1.f / sum;
    for (int j = 0; j < KT; j++) {
      gate_w[tid * KT + j] = cv[j] * inv;
      pair_e[tid * KT + j] = ch[j];
      sel[tid * KT + j] = ch[j];
    }
  }
  __syncthreads();
  if (tid < EN) {
    int cnt = 0;
    for (int i = 0; i < NPAIR; i++) if (sel[i] == tid) cnt++;
    out_counts[tid] = (float)cnt;
  }
  if (tid < BB * EN) out_weights[tid] = weights[tid];
}

// ---------------- fold LN scale/bias into conv1 / conv4 weights ----------------
__global__ void fold_kernel(const float* __restrict__ conv1_w, const float* __restrict__ conv1_b,
                            const float* __restrict__ ln1_w, const float* __restrict__ ln1_b,
                            const float* __restrict__ conv4_w, const float* __restrict__ conv4_b,
                            const float* __restrict__ ln2_w, const float* __restrict__ ln2_b,
                            float* __restrict__ W1eff, float* __restrict__ b1eff,
                            float* __restrict__ W4eff, float* __restrict__ b4eff) {
  int gid = blockIdx.x * blockDim.x + threadIdx.x;
  if (gid >= 2 * EN * DWC) return;
  int which = gid / (EN * DWC);
  int rem = gid - which * EN * DWC;
  int e = rem / DWC, o = rem % DWC;
  const float* src = (which ? conv4_w : conv1_w) + (size_t)(e * DWC + o) * CC;
  const float* lw = (which ? ln2_w : ln1_w) + e * CC;
  const float* lb = (which ? ln2_b : ln1_b) + e * CC;
  float bacc = (which ? conv4_b : conv1_b)[e * DWC + o];
  float* dst = (which ? W4eff : W1eff) + (size_t)(e * DWC + o) * CC;
  for (int c = 0; c < CC; c++) {
    float wv = src[c];
    dst[c] = wv * lw[c];
    bacc += wv * lb[c];
  }
  (which ? b4eff : b1eff)[e * DWC + o] = bacc;
}

// ---------------- channel LayerNorm (normalize only; scale/bias folded) ----------------
// x layout: [img][C][HW]; one thread per pixel, two passes over C.
__global__ void ln_kernel(const float* __restrict__ x, float* __restrict__ xh) {
  int gid = blockIdx.x * blockDim.x + threadIdx.x;
  int img = gid >> 12;
  int hw = gid & 4095;
  const float* px = x + (size_t)img * CC * HWP + hw;
  float s = 0.f, s2 = 0.f;
#pragma unroll 8
  for (int c = 0; c < CC; c++) { float v = px[(size_t)c * HWP]; s += v; s2 += v * v; }
  float mu = s * (1.f / CC);
  float var = s2 * (1.f / CC) - mu * mu;
  float r = rsqrtf(var + EPSLN);
  float* po = xh + (size_t)img * CC * HWP + hw;
#pragma unroll 8
  for (int c = 0; c < CC; c++) { po[(size_t)c * HWP] = (px[(size_t)c * HWP] - mu) * r; }
}

#define FMA16(a0,a1,a2,a3,bv)                                                     \
  acc[0][0] = fmaf(a0, bv.x, acc[0][0]); acc[0][1] = fmaf(a0, bv.y, acc[0][1]);   \
  acc[0][2] = fmaf(a0, bv.z, acc[0][2]); acc[0][3] = fmaf(a0, bv.w, acc[0][3]);   \
  acc[1][0] = fmaf(a1, bv.x, acc[1][0]); acc[1][1] = fmaf(a1, bv.y, acc[1][1]);   \
  acc[1][2] = fmaf(a1, bv.z, acc[1][2]); acc[1][3] = fmaf(a1, bv.w, acc[1][3]);   \
  acc[2][0] = fmaf(a2, bv.x, acc[2][0]); acc[2][1] = fmaf(a2, bv.y, acc[2][1]);   \
  acc[2][2] = fmaf(a2, bv.z, acc[2][2]); acc[2][3] = fmaf(a2, bv.w, acc[2][3]);   \
  acc[3][0] = fmaf(a3, bv.x, acc[3][0]); acc[3][1] = fmaf(a3, bv.y, acc[3][1]);   \
  acc[3][2] = fmaf(a3, bv.z, acc[3][2]); acc[3][3] = fmaf(a3, bv.w, acc[3][3]);

// ---------------- generic GEMM for conv1 / conv4: out = Aeff[e] @ B(img) + bias ----------------
// A: [E][DWC][CC] row-major. B: [img][CC][HWP]. out: [pc][DWC][HWP].
__global__ __launch_bounds__(256) void mm_gemm(const float* __restrict__ Aall,
                                               const float* __restrict__ ball,
                                               const float* __restrict__ Bsrc,
                                               const int* __restrict__ pair_e,
                                               int pair_lo, int b_mode,
                                               float* __restrict__ t_out) {
  __shared__ float As[64][68];
  __shared__ float Bs[64][64];
  int pc = blockIdx.z, p = pair_lo + pc;
  int e = pair_e[p];
  int img = b_mode ? pc : (p / KT);
  int n0 = blockIdx.x * 64, m0 = blockIdx.y * 64;
  const float* A = Aall + (size_t)e * DWC * CC;
  const float* Bm = Bsrc + (size_t)img * CC * HWP;
  int tid = threadIdx.x, tx = tid & 15, ty = tid >> 4;
  float acc[4][4] = {};
  for (int kt = 0; kt < 2; kt++) {
#pragma unroll
    for (int i = 0; i < 4; i++) {
      int idx = tid + i * 256; int m = idx >> 4, kc = (idx & 15) << 2;
      float4 v = *(const float4*)(A + (size_t)(m0 + m) * CC + kt * 64 + kc);
      *(float4*)&As[m][kc] = v;
    }
#pragma unroll
    for (int i = 0; i < 4; i++) {
      int idx = tid + i * 256; int k = idx >> 4, nc = (idx & 15) << 2;
      float4 v = *(const float4*)(Bm + (size_t)(kt * 64 + k) * HWP + n0 + nc);
      *(float4*)&Bs[k][nc] = v;
    }
    __syncthreads();
#pragma unroll 8
    for (int k = 0; k < 64; k++) {
      float4 bv = *(const float4*)&Bs[k][tx << 2];
      int mb = ty << 2;
      float a0 = As[mb + 0][k], a1 = As[mb + 1][k], a2 = As[mb + 2][k], a3 = As[mb + 3][k];
      FMA16(a0, a1, a2, a3, bv)
    }
    __syncthreads();
  }
#pragma unroll
  for (int i = 0; i < 4; i++) {
    int m = m0 + (ty << 2) + i;
    float bias = ball[e * DWC + m];
    float4 o;
    o.x = acc[i][0] + bias; o.y = acc[i][1] + bias; o.z = acc[i][2] + bias; o.w = acc[i][3] + bias;
    *(float4*)(t_out + ((size_t)pc * DWC + m) * HWP + n0 + (tx << 2)) = o;
  }
}

// ---------------- depthwise 3x3 + bias + SimpleGate + spatial mean ----------------
__global__ __launch_bounds__(256) void dwsg_kernel(const float* __restrict__ t_buf,
                                                   const float* __restrict__ conv2_w,
                                                   const float* __restrict__ conv2_b,
                                                   const int* __restrict__ pair_e, int pair_lo,
                                                   float* __restrict__ y_buf,
                                                   float* __restrict__ mean_y) {
  __shared__ float pa[64][64];
  __shared__ float pg[64][64];
  __shared__ float red[256];
  int c = blockIdx.x, pc = blockIdx.y, p = pair_lo + pc;
  int e = pair_e[p];
  int tid = threadIdx.x;
  const float* ta = t_buf + ((size_t)pc * DWC + c) * HWP;
  const float* tg = t_buf + ((size_t)pc * DWC + CC + c) * HWP;
#pragma unroll
  for (int i = 0; i < 4; i++) {
    int idx = tid + i * 256;
    ((float4*)pa)[idx] = ((const float4*)ta)[idx];
    ((float4*)pg)[idx] = ((const float4*)tg)[idx];
  }
  __syncthreads();
  const float* wa = conv2_w + (size_t)(e * DWC + c) * 9;
  const float* wg = conv2_w + (size_t)(e * DWC + CC + c) * 9;
  float w_a[9], w_g[9];
#pragma unroll
  for (int i = 0; i < 9; i++) { w_a[i] = wa[i]; w_g[i] = wg[i]; }
  float ba = conv2_b[e * DWC + c], bg = conv2_b[e * DWC + CC + c];
  int px = (tid & 15) * 4, py = (tid >> 4) * 4;
  float acca[4][4] = {}, accg[4][4] = {};
#pragma unroll
  for (int rr = 0; rr < 6; rr++) {
    int ir = py + rr - 1;
    bool rok = (ir >= 0 && ir < 64);
    int irc = min(max(ir, 0), 63);
    float ca[6], cg[6];
#pragma unroll
    for (int cc2 = 0; cc2 < 6; cc2++) {
      int ic = px + cc2 - 1;
      bool ok = rok && (ic >= 0) && (ic < 64);
      int icc = min(max(ic, 0), 63);
      float va = pa[irc][icc], vg = pg[irc][icc];
      ca[cc2] = ok ? va : 0.f;
      cg[cc2] = ok ? vg : 0.f;
    }
#pragma unroll
    for (int oh = 0; oh < 4; oh++) {
      int dh = rr - oh;
      if (dh < 0 || dh > 2) continue;
#pragma unroll
      for (int ow = 0; ow < 4; ow++) {
#pragma unroll
        for (int dw = 0; dw < 3; dw++) {
          acca[oh][ow] = fmaf(ca[ow + dw], w_a[dh * 3 + dw], acca[oh][ow]);
          accg[oh][ow] = fmaf(cg[ow + dw], w_g[dh * 3 + dw], accg[oh][ow]);
        }
      }
    }
  }
  float sum = 0.f;
  float* yrow = y_buf + ((size_t)pc * CC + c) * HWP;
#pragma unroll
  for (int oh = 0; oh < 4; oh++) {
    float4 o;
    o.x = (acca[oh][0] + ba) * (accg[oh][0] + bg);
    o.y = (acca[oh][1] + ba) * (accg[oh][1] + bg);
    o.z = (acca[oh][2] + ba) * (accg[oh][2] + bg);
    o.w = (acca[oh][3] + ba) * (accg[oh][3] + bg);
    sum += o.x + o.y + o.z + o.w;
    *(float4*)(yrow + (py + oh) * WW + px) = o;
  }
  red[tid] = sum;
  __syncthreads();
  for (int s = 128; s > 0; s >>= 1) {
    if (tid < s) red[tid] += red[tid + s];
    __syncthreads();
  }
  if (tid == 0) mean_y[pc * CC + c] = red[0] * (1.f / HWP);
}

// ---------------- SCA: s = sca_w[e] @ mean + sca_b[e] ----------------
__global__ void sca_kernel(const float* __restrict__ mean_y, const float* __restrict__ sca_w,
                           const float* __restrict__ sca_b, const int* __restrict__ pair_e,
                           int pair_lo, float* __restrict__ s_buf) {
  __shared__ float m[CC];
  int pc = blockIdx.x, e = pair_e[pair_lo + pc];
  int tid = threadIdx.x;
  m[tid] = mean_y[pc * CC + tid];
  __syncthreads();
  const float* wr = sca_w + (size_t)(e * CC + tid) * CC;
  float acc = sca_b[e * CC + tid];
#pragma unroll 8
  for (int c = 0; c < CC; c++) acc = fmaf(wr[c], m[c], acc);
  s_buf[pc * CC + tid] = acc;
}

// ---------------- conv3 (1x1, with SCA scale on B) + residual: x1 = feat + beta*(...) ----------------
__global__ __launch_bounds__(256) void conv3_gemm(const float* __restrict__ conv3_w,
                                                  const float* __restrict__ conv3_b,
                                                  const float* __restrict__ y_buf,
                                                  const float* __restrict__ s_buf,
                                                  const float* __restrict__ feat,
                                                  const float* __restrict__ beta,
                                                  const int* __restrict__ pair_e, int pair_lo,
                                                  float* __restrict__ x1_buf) {
  __shared__ float As[64][68];
  __shared__ float Bs[64][64];
  int pc = blockIdx.z, p = pair_lo + pc, e = pair_e[p], b = p / KT;
  int n0 = blockIdx.x * 64, m0 = blockIdx.y * 64;
  const float* A = conv3_w + (size_t)e * CC * CC;
  const float* Bm = y_buf + (size_t)pc * CC * HWP;
  int tid = threadIdx.x, tx = tid & 15, ty = tid >> 4;
  float acc[4][4] = {};
  for (int kt = 0; kt < 2; kt++) {
#pragma unroll
    for (int i = 0; i < 4; i++) {
      int idx = tid + i * 256; int m = idx >> 4, kc = (idx & 15) << 2;
      float4 v = *(const float4*)(A + (size_t)(m0 + m) * CC + kt * 64 + kc);
      *(float4*)&As[m][kc] = v;
    }
#pragma unroll
    for (int i = 0; i < 4; i++) {
      int idx = tid + i * 256; int k = idx >> 4, nc = (idx & 15) << 2;
      float sc = s_buf[pc * CC + kt * 64 + k];
      float4 v = *(const float4*)(Bm + (size_t)(kt * 64 + k) * HWP + n0 + nc);
      v.x *= sc; v.y *= sc; v.z *= sc; v.w *= sc;
      *(float4*)&Bs[k][nc] = v;
    }
    __syncthreads();
#pragma unroll 8
    for (int k = 0; k < 64; k++) {
      float4 bv = *(const float4*)&Bs[k][tx << 2];
      int mb = ty << 2;
      float a0 = As[mb + 0][k], a1 = As[mb + 1][k], a2 = As[mb + 2][k], a3 = As[mb + 3][k];
      FMA16(a0, a1, a2, a3, bv)
    }
    __syncthreads();
  }
#pragma unroll
  for (int i = 0; i < 4; i++) {
    int m = m0 + (ty << 2) + i;
    float bt = beta[e * CC + m], bb = conv3_b[e * CC + m];
    float4 fv = *(const float4*)(feat + ((size_t)b * CC + m) * HWP + n0 + (tx << 2));
    float4 o;
    o.x = fv.x + bt * (acc[i][0] + bb);
    o.y = fv.y + bt * (acc[i][1] + bb);
    o.z = fv.z + bt * (acc[i][2] + bb);
    o.w = fv.w + bt * (acc[i][3] + bb);
    *(float4*)(x1_buf + ((size_t)pc * CC + m) * HWP + n0 + (tx << 2)) = o;
  }
}

// ---------------- conv5 (1x1 over SG(t2)) + residual + gate-weighted accumulation over 3 pairs ----------------
__global__ __launch_bounds__(256) void conv5_gemm(const float* __restrict__ conv5_w,
                                                  const float* __restrict__ conv5_b,
                                                  const float* __restrict__ t_buf,
                                                  const float* __restrict__ x1_buf,
                                                  const float* __restrict__ gamma,
                                                  const float* __restrict__ gate_w,
                                                  const int* __restrict__ pair_e, int pair_lo,
                                                  float* __restrict__ out) {
  __shared__ float As[64][68];
  __shared__ float Bs[64][64];
  int sl = blockIdx.z;
  int n0 = blockIdx.x * 64, m0 = blockIdx.y * 64;
  int b = pair_lo / KT + sl;
  int tid = threadIdx.x, tx = tid & 15, ty = tid >> 4;
  float fout[4][4] = {};
  for (int j = 0; j < KT; j++) {
    int pc = sl * KT + j, p = pair_lo + pc, e = pair_e[p];
    float g = gate_w[p];
    const float* A = conv5_w + (size_t)e * CC * CC;
    float acc[4][4] = {};
    for (int kt = 0; kt < 2; kt++) {
      __syncthreads();
#pragma unroll
      for (int i = 0; i < 4; i++) {
        int idx = tid + i * 256; int m = idx >> 4, kc = (idx & 15) << 2;
        float4 v = *(const float4*)(A + (size_t)(m0 + m) * CC + kt * 64 + kc);
        *(float4*)&As[m][kc] = v;
      }
#pragma unroll
      for (int i = 0; i < 4; i++) {
        int idx = tid + i * 256; int k = idx >> 4, nc = (idx & 15) << 2;
        const float* t0 = t_buf + ((size_t)pc * DWC + kt * 64 + k) * HWP + n0 + nc;
        float4 va = *(const float4*)t0;
        float4 vg = *(const float4*)(t0 + (size_t)CC * HWP);
        va.x *= vg.x; va.y *= vg.y; va.z *= vg.z; va.w *= vg.w;
        *(float4*)&Bs[k][nc] = va;
      }
      __syncthreads();
#pragma unroll 8
      for (int k = 0; k < 64; k++) {
        float4 bv = *(const float4*)&Bs[k][tx << 2];
        int mb = ty << 2;
        float a0 = As[mb + 0][k], a1 = As[mb + 1][k], a2 = As[mb + 2][k], a3 = As[mb + 3][k];
        FMA16(a0, a1, a2, a3, bv)
      }
    }
#pragma unroll
    for (int i = 0; i < 4; i++) {
      int m = m0 + (ty << 2) + i;
      float gm = gamma[e * CC + m], b5 = conv5_b[e * CC + m];
      float4 xv = *(const float4*)(x1_buf + ((size_t)pc * CC + m) * HWP + n0 + (tx << 2));
      fout[i][0] += g * fmaf(gm, acc[i][0] + b5, xv.x);
      fout[i][1] += g * fmaf(gm, acc[i][1] + b5, xv.y);
      fout[i][2] += g * fmaf(gm, acc[i][2] + b5, xv.z);
      fout[i][3] += g * fmaf(gm, acc[i][3] + b5, xv.w);
    }
  }
#pragma unroll
  for (int i = 0; i < 4; i++) {
    int m = m0 + (ty << 2) + i;
    float4 o; o.x = fout[i][0]; o.y = fout[i][1]; o.z = fout[i][2]; o.w = fout[i][3];
    *(float4*)(out + ((size_t)b * CC + m) * HWP + n0 + (tx << 2)) = o;
  }
}

extern "C" void kernel_launch(void* const* d_in, const int* in_sizes, int n_in,
                              void* d_out, int out_size, void* d_ws, size_t ws_size,
                              hipStream_t stream) {
  const float* feat    = (const float*)d_in[0];
  const float* weights = (const float*)d_in[1];
  const float* ln1_w   = (const float*)d_in[2];
  const float* ln1_b   = (const float*)d_in[3];
  const float* conv1_w = (const float*)d_in[4];
  const float* conv1_b = (const float*)d_in[5];
  const float* conv2_w = (const float*)d_in[6];
  const float* conv2_b = (const float*)d_in[7];
  const float* sca_w   = (const float*)d_in[8];
  const float* sca_b   = (const float*)d_in[9];
  const float* conv3_w = (const float*)d_in[10];
  const float* conv3_b = (const float*)d_in[11];
  const float* ln2_w   = (const float*)d_in[12];
  const float* ln2_b   = (const float*)d_in[13];
  const float* conv4_w = (const float*)d_in[14];
  const float* conv4_b = (const float*)d_in[15];
  const float* conv5_w = (const float*)d_in[16];
  const float* conv5_b = (const float*)d_in[17];
  const float* beta    = (const float*)d_in[18];
  const float* gamma   = (const float*)d_in[19];

  float* out = (float*)d_out;
  float* out_counts = out + (size_t)BB * CC * HWP;
  float* out_weights = out_counts + EN;

  char* base = (char*)d_ws;
  size_t off = 0;
  auto carveF = [&](size_t n) -> float* { float* p = (float*)(base + off); off += n * 4; return p; };
  float* W1eff = carveF((size_t)EN * DWC * CC);
  float* b1eff = carveF(EN * DWC);
  float* W4eff = carveF((size_t)EN * DWC * CC);
  float* b4eff = carveF(EN * DWC);
  float* gate_w = carveF(64);
  int*   pair_e = (int*)carveF(64);
  float* mean_y = carveF(NPAIR * CC);
  float* s_buf  = carveF(NPAIR * CC);
  float* xhat   = carveF((size_t)BB * CC * HWP);

  int ns = 16;
  while (ns > 1) {
    size_t pr = (size_t)ns * KT;
    size_t need = off + (pr * CC * HWP * 3 + pr * DWC * HWP) * 4;
    if (need <= ws_size) break;
    ns >>= 1;
  }
  size_t pr = (size_t)ns * KT;
  float* x1_buf  = carveF(pr * CC * HWP);
  float* xh2_buf = carveF(pr * CC * HWP);
  float* y_buf   = carveF(pr * CC * HWP);
  float* t_buf   = carveF(pr * DWC * HWP);

  gate_kernel<<<1, 256, 0, stream>>>(weights, gate_w, pair_e, out_counts, out_weights);
  fold_kernel<<<10, 256, 0, stream>>>(conv1_w, conv1_b, ln1_w, ln1_b,
                                      conv4_w, conv4_b, ln2_w, ln2_b,
                                      W1eff, b1eff, W4eff, b4eff);
  ln_kernel<<<BB * HWP / 256, 256, 0, stream>>>(feat, xhat);

  for (int s0 = 0; s0 < BB; s0 += ns) {
    int np = ns * KT, plo = s0 * KT;
    dim3 g1(HWP / 64, DWC / 64, np);
    mm_gemm<<<g1, 256, 0, stream>>>(W1eff, b1eff, xhat, pair_e, plo, 0, t_buf);
    dwsg_kernel<<<dim3(CC, np), 256, 0, stream>>>(t_buf, conv2_w, conv2_b, pair_e, plo, y_buf, mean_y);
    sca_kernel<<<np, CC, 0, stream>>>(mean_y, sca_w, sca_b, pair_e, plo, s_buf);
    conv3_gemm<<<dim3(HWP / 64, CC / 64, np), 256, 0, stream>>>(conv3_w, conv3_b, y_buf, s_buf,
                                                                feat, beta, pair_e, plo, x1_buf);
    ln_kernel<<<np * HWP / 256, 256, 0, stream>>>(x1_buf, xh2_buf);
    mm_gemm<<<g1, 256, 0, stream>>>(W4eff, b4eff, xh2_buf, pair_e, plo, 1, t_buf);
    conv5_gemm<<<dim3(HWP / 64, CC / 64, ns), 256, 0, stream>>>(conv5_w, conv5_b, t_buf, x1_buf,
                                                                gamma, gate_w, pair_e, plo, out);
  }
}

// Round 2
// 378.925 us; speedup vs baseline: 2.0944x; 2.0944x over previous
//
#include <hip/hip_runtime.h>

#define EN 5
#define KT 3
#define BB 16
#define CC 128
#define HWP 4096
#define DWC 256
#define NPAIR 48
#define EPSLN 1e-6f

typedef float f32x4 __attribute__((ext_vector_type(4)));
typedef __bf16 bf16x8 __attribute__((ext_vector_type(8)));

__device__ __forceinline__ float bf2f(ushort u) {
  union { unsigned int u; float f; } v; v.u = ((unsigned int)u) << 16; return v.f;
}
__device__ __forceinline__ ushort f2bf(float f) {
  union { float f; unsigned int u; } v; v.f = f;
  unsigned int r = v.u + 0x7FFFu + ((v.u >> 16) & 1u);
  return (ushort)(r >> 16);
}
__device__ __forceinline__ ushort4 pack4(float a, float b, float c, float d) {
  ushort4 r; r.x = f2bf(a); r.y = f2bf(b); r.z = f2bf(c); r.w = f2bf(d); return r;
}

// ---------------- gate: top-3 per sample, counts, weights, zero mean_raw ----------------
__global__ void gate_kernel(const float* __restrict__ weights, float* __restrict__ gate_w,
                            int* __restrict__ pair_e, float* __restrict__ out_counts,
                            float* __restrict__ out_weights, float* __restrict__ mean_raw) {
  __shared__ int sel[NPAIR];
  int tid = threadIdx.x;
  if (tid < BB) {
    float w[EN];
    for (int e = 0; e < EN; e++) w[e] = weights[tid * EN + e];
    int ch[KT]; float cv[KT]; float sum = 0.f;
    for (int j = 0; j < KT; j++) {
      int best = -1; float bv = -3.4e38f;
      for (int e = 0; e < EN; e++) {
        bool used = false;
        for (int q = 0; q < j; q++) if (ch[q] == e) used = true;
        if (!used && w[e] > bv) { bv = w[e]; best = e; }
      }
      ch[j] = best; cv[j] = bv; sum += bv;
    }
    float inv = 1.f / sum;
    for (int j = 0; j < KT; j++) {
      gate_w[tid * KT + j] = cv[j] * inv;
      pair_e[tid * KT + j] = ch[j];
      sel[tid * KT + j] = ch[j];
    }
  }
  for (int i = tid; i < NPAIR * CC; i += 256) mean_raw[i] = 0.f;
  __syncthreads();
  if (tid < EN) {
    int cnt = 0;
    for (int i = 0; i < NPAIR; i++) if (sel[i] == tid) cnt++;
    out_counts[tid] = (float)cnt;
  }
  if (tid < BB * EN) out_weights[tid] = weights[tid];
}

// ---------------- fold LN into conv1/conv4 (bf16 weights), b3eff = beta*b3 ----------------
__global__ void fold_kernel(const float* __restrict__ conv1_w, const float* __restrict__ conv1_b,
                            const float* __restrict__ ln1_w, const float* __restrict__ ln1_b,
                            const float* __restrict__ conv4_w, const float* __restrict__ conv4_b,
                            const float* __restrict__ ln2_w, const float* __restrict__ ln2_b,
                            const float* __restrict__ conv3_b, const float* __restrict__ beta,
                            ushort* __restrict__ W1eff, float* __restrict__ b1eff,
                            ushort* __restrict__ W4eff, float* __restrict__ b4eff,
                            float* __restrict__ b3eff) {
  int gid = blockIdx.x * 256 + threadIdx.x;
  if (gid < 2 * EN * DWC) {
    int which = gid / (EN * DWC), rem = gid % (EN * DWC);
    int e = rem / DWC, o = rem % DWC;
    const float* src = (which ? conv4_w : conv1_w) + (size_t)(e * DWC + o) * CC;
    const float* lw = (which ? ln2_w : ln1_w) + e * CC;
    const float* lb = (which ? ln2_b : ln1_b) + e * CC;
    float bacc = (which ? conv4_b : conv1_b)[e * DWC + o];
    ushort* dst = (which ? W4eff : W1eff) + (size_t)(e * DWC + o) * CC;
    for (int c = 0; c < CC; c++) {
      float wv = src[c];
      dst[c] = f2bf(wv * lw[c]);
      bacc += wv * lb[c];
    }
    (which ? b4eff : b1eff)[e * DWC + o] = bacc;
  } else if (gid < 2 * EN * DWC + EN * CC) {
    int x = gid - 2 * EN * DWC;
    b3eff[x] = beta[x] * conv3_b[x];
  }
}

// ---------------- fold2 (after gate): W5eff[p] = conv5_w[e]*gamma*gate; b5tot[b] ----------------
__global__ void fold2_kernel(const float* __restrict__ conv5_w, const float* __restrict__ conv5_b,
                             const float* __restrict__ gamma, const float* __restrict__ gate_w,
                             const int* __restrict__ pair_e,
                             ushort* __restrict__ W5eff, float* __restrict__ b5tot) {
  int gid = blockIdx.x * 256 + threadIdx.x;
  const int nW = NPAIR * CC * CC / 8;
  if (gid < nW) {
    int base = gid * 8;
    int p = base >> 14, rem = base & 16383;
    int o = rem >> 7, k0 = rem & 127;
    int e = pair_e[p];
    float sc = gamma[e * CC + o] * gate_w[p];
    const float* src = conv5_w + ((size_t)e * CC + o) * CC + k0;
    ushort* dst = W5eff + ((size_t)p * CC + o) * CC + k0;
    for (int q = 0; q < 8; q++) dst[q] = f2bf(src[q] * sc);
  } else if (gid < nW + BB * CC) {
    int x = gid - nW;
    int b = x >> 7, o = x & 127;
    float s = 0.f;
    for (int j = 0; j < KT; j++) {
      int p = b * KT + j, e = pair_e[p];
      s += gate_w[p] * gamma[e * CC + o] * conv5_b[e * CC + o];
    }
    b5tot[x] = s;
  }
}

// ---------------- LN1 + transpose: feat [b][C][HWP] fp32 -> xhatT, featT [b][HWP][C] bf16 ----------------
__global__ __launch_bounds__(256) void ln1_kernel(const float* __restrict__ feat,
                                                  ushort* __restrict__ xhatT,
                                                  ushort* __restrict__ featT) {
  __shared__ float tile[CC * 64];
  __shared__ float pS[4][64], pS2[4][64], bcM[64], bcR[64];
  int bimg = blockIdx.x >> 6;
  int n0 = (blockIdx.x & 63) * 64;
  int tid = threadIdx.x;
  const float* src = feat + (size_t)bimg * CC * HWP + n0;
#pragma unroll
  for (int i = 0; i < 8; i++) {
    int ch = tid + i * 256;
    int row = ch >> 4, c16 = ch & 15;
    *(float4*)&tile[row * 64 + c16 * 4] = *(const float4*)(src + (size_t)row * HWP + c16 * 4);
  }
  __syncthreads();
  int lane = tid & 63, w = tid >> 6;
  float s = 0.f, s2 = 0.f;
#pragma unroll
  for (int i = 0; i < 32; i++) {
    float v = tile[(w * 32 + i) * 64 + lane];
    s += v; s2 += v * v;
  }
  pS[w][lane] = s; pS2[w][lane] = s2;
  __syncthreads();
  if (w == 0) {
    float t1 = pS[0][lane] + pS[1][lane] + pS[2][lane] + pS[3][lane];
    float t2 = pS2[0][lane] + pS2[1][lane] + pS2[2][lane] + pS2[3][lane];
    float mu = t1 * (1.f / CC);
    float var = t2 * (1.f / CC) - mu * mu;
    bcM[lane] = mu; bcR[lane] = rsqrtf(var + EPSLN);
  }
  __syncthreads();
  float mu = bcM[lane], r = bcR[lane];
  size_t obase = ((size_t)bimg * HWP + n0 + lane) * CC + w * 32;
#pragma unroll
  for (int i = 0; i < 4; i++) {
    float v[8];
#pragma unroll
    for (int q = 0; q < 8; q++) v[q] = tile[(w * 32 + i * 8 + q) * 64 + lane];
    *(ushort4*)(featT + obase + i * 8)     = pack4(v[0], v[1], v[2], v[3]);
    *(ushort4*)(featT + obase + i * 8 + 4) = pack4(v[4], v[5], v[6], v[7]);
    *(ushort4*)(xhatT + obase + i * 8)     = pack4((v[0]-mu)*r, (v[1]-mu)*r, (v[2]-mu)*r, (v[3]-mu)*r);
    *(ushort4*)(xhatT + obase + i * 8 + 4) = pack4((v[4]-mu)*r, (v[5]-mu)*r, (v[6]-mu)*r, (v[7]-mu)*r);
  }
}

// ---------------- stage 128x128 bf16 tile (32KB contiguous) into LDS with XOR swizzle ----------------
__device__ __forceinline__ void stage_tile(const ushort* __restrict__ g, ushort* lds, int tid) {
#pragma unroll
  for (int i = 0; i < 8; i++) {
    int d = (tid + i * 256) * 16;
    int row = d >> 8;
    uint4 v = *(const uint4*)((const char*)g + d);
    *(uint4*)((char*)lds + (d ^ ((row & 7) << 4))) = v;
  }
}

__device__ __forceinline__ bf16x8 ldfrag(const ushort* lds, int row, int kb) {
  return *(const bf16x8*)((const char*)lds + row * 256 + (kb ^ ((row & 7) << 4)));
}

// ---------------- MFMA GEMM: out[px][o] = W[o][:] . act[px][:] (+epilogues) ----------------
// MODE 0: bias add, bf16 pixel-major out (conv1 / conv4)
// MODE 1: conv3: x1 = featT + (acc + b3eff)   (beta folded into W3eff/b3eff)
template<int MODE>
__global__ __launch_bounds__(256, 2) void gemm_kernel(
    const ushort* __restrict__ Wall, const float* __restrict__ ball,
    const ushort* __restrict__ Bact, const ushort* __restrict__ featT,
    const int* __restrict__ pair_e, int pair_lo, int bmode, int OC,
    ushort* __restrict__ outT) {
  __shared__ ushort Ws[CC * CC];
  __shared__ ushort As[CC * CC];
  int pc = blockIdx.z, p = pair_lo + pc, e = pair_e[p];
  int img = bmode ? pc : (p / KT);
  int n0 = blockIdx.x * 128;
  int m0 = blockIdx.y * 128;
  int tid = threadIdx.x, lane = tid & 63, w = tid >> 6;
  const ushort* Wsrc = (MODE == 1) ? (Wall + ((size_t)pc * CC + m0) * CC)
                                   : (Wall + ((size_t)e * OC + m0) * CC);
  const ushort* Asrc = Bact + ((size_t)((MODE == 1) ? pc : img) * HWP + n0) * CC;
  stage_tile(Wsrc, Ws, tid);
  stage_tile(Asrc, As, tid);
  __syncthreads();
  int wr = w >> 1, wc = w & 1;
  int fr = lane & 15;
  int kb0 = (lane >> 4) * 16;
  int og = (lane >> 4) * 4;
  f32x4 acc[4][4] = {};
#pragma unroll
  for (int ks = 0; ks < 4; ks++) {
    bf16x8 a[4], b[4];
#pragma unroll
    for (int m = 0; m < 4; m++) a[m] = ldfrag(Ws, wr * 64 + m * 16 + fr, ks * 64 + kb0);
#pragma unroll
    for (int n = 0; n < 4; n++) b[n] = ldfrag(As, wc * 64 + n * 16 + fr, ks * 64 + kb0);
#pragma unroll
    for (int m = 0; m < 4; m++)
#pragma unroll
      for (int n = 0; n < 4; n++)
        acc[m][n] = __builtin_amdgcn_mfma_f32_16x16x32_bf16(a[m], b[n], acc[m][n], 0, 0, 0);
  }
#pragma unroll
  for (int m = 0; m < 4; m++) {
    int o = m0 + wr * 64 + m * 16 + og;
    float4 bv = (MODE == 1) ? *(const float4*)&ball[e * CC + o]
                            : *(const float4*)&ball[e * OC + o];
#pragma unroll
    for (int n = 0; n < 4; n++) {
      int px = n0 + wc * 64 + n * 16 + fr;
      f32x4 v = acc[m][n];
      ushort4 st;
      if (MODE == 0) {
        st = pack4(v.x + bv.x, v.y + bv.y, v.z + bv.z, v.w + bv.w);
      } else {
        ushort4 f4 = *(const ushort4*)(featT + ((size_t)img * HWP + px) * CC + o);
        st = pack4(bf2f(f4.x) + v.x + bv.x, bf2f(f4.y) + v.y + bv.y,
                   bf2f(f4.z) + v.z + bv.z, bf2f(f4.w) + v.w + bv.w);
      }
      *(ushort4*)&outT[((size_t)pc * HWP + px) * OC + o] = st;
    }
  }
}

// ---------------- depthwise 3x3 + SG + channel-mean (pixel-major bf16) ----------------
#define HALO 18
__global__ __launch_bounds__(256) void dwsg_kernel(
    const ushort* __restrict__ tT, const float* __restrict__ conv2_w,
    const float* __restrict__ conv2_b, const int* __restrict__ pair_e, int pair_lo,
    ushort* __restrict__ yT, float* __restrict__ mean_raw) {
  __shared__ ushort halo[HALO * HALO * 64];
  __shared__ float part[4][32];
  int cg = blockIdx.x;
  int ts = blockIdx.y;
  int pc = blockIdx.z, p = pair_lo + pc, e = pair_e[p];
  int c0 = cg * 32;
  int th = (ts >> 2) * 16, tw = (ts & 3) * 16;
  int tid = threadIdx.x;
  for (int it = 0; it < 11; it++) {
    int ch = tid + it * 256;
    if (ch < HALO * HALO * 8) {
      int px = ch >> 3, sub = ch & 7;
      int hh = px / HALO - 1 + th, ww = px % HALO - 1 + tw;
      uint4 v = {0u, 0u, 0u, 0u};
      if (hh >= 0 && hh < 64 && ww >= 0 && ww < 64) {
        int n = hh * 64 + ww;
        int cbase = (sub < 4) ? (c0 + sub * 8) : (CC + c0 + (sub - 4) * 8);
        v = *(const uint4*)(tT + ((size_t)pc * HWP + n) * DWC + cbase);
      }
      *(uint4*)((char*)halo + px * 128 + ((sub * 16) ^ ((px & 7) << 4))) = v;
    }
  }
  __syncthreads();
  int ww_ = tid & 15, hh_ = tid >> 4;
  int n = (th + hh_) * 64 + tw + ww_;
  int wave = tid >> 6, lane = tid & 63;
  const float* wA = conv2_w + ((size_t)e * DWC + c0) * 9;
  const float* wG = conv2_w + ((size_t)e * DWC + CC + c0) * 9;
  const float* bA = conv2_b + e * DWC + c0;
  const float* bG = conv2_b + e * DWC + CC + c0;
  for (int ci = 0; ci < 32; ci += 4) {
    float accA[4] = {}, accG[4] = {};
#pragma unroll
    for (int dh = 0; dh < 3; dh++) {
#pragma unroll
      for (int dw = 0; dw < 3; dw++) {
        int px = (hh_ + dh) * HALO + ww_ + dw;
        int swz = (px & 7) << 4;
        ushort4 va = *(const ushort4*)((const char*)halo + px * 128 + ((ci * 2) ^ swz));
        ushort4 vg = *(const ushort4*)((const char*)halo + px * 128 + ((64 + ci * 2) ^ swz));
        float fa0 = bf2f(va.x), fa1 = bf2f(va.y), fa2 = bf2f(va.z), fa3 = bf2f(va.w);
        float fg0 = bf2f(vg.x), fg1 = bf2f(vg.y), fg2 = bf2f(vg.z), fg3 = bf2f(vg.w);
        int wo = dh * 3 + dw;
        accA[0] = fmaf(fa0, wA[(ci+0)*9 + wo], accA[0]);
        accA[1] = fmaf(fa1, wA[(ci+1)*9 + wo], accA[1]);
        accA[2] = fmaf(fa2, wA[(ci+2)*9 + wo], accA[2]);
        accA[3] = fmaf(fa3, wA[(ci+3)*9 + wo], accA[3]);
        accG[0] = fmaf(fg0, wG[(ci+0)*9 + wo], accG[0]);
        accG[1] = fmaf(fg1, wG[(ci+1)*9 + wo], accG[1]);
        accG[2] = fmaf(fg2, wG[(ci+2)*9 + wo], accG[2]);
        accG[3] = fmaf(fg3, wG[(ci+3)*9 + wo], accG[3]);
      }
    }
    float ys[4];
#pragma unroll
    for (int q = 0; q < 4; q++) ys[q] = (accA[q] + bA[ci + q]) * (accG[q] + bG[ci + q]);
    *(ushort4*)(yT + ((size_t)pc * HWP + n) * CC + c0 + ci) = pack4(ys[0], ys[1], ys[2], ys[3]);
#pragma unroll
    for (int q = 0; q < 4; q++) {
      float v = ys[q];
      for (int off = 32; off > 0; off >>= 1) v += __shfl_down(v, off, 64);
      if (lane == 0) part[wave][ci + q] = v;
    }
  }
  __syncthreads();
  if (tid < 32) {
    float s = part[0][tid] + part[1][tid] + part[2][tid] + part[3][tid];
    atomicAdd(&mean_raw[p * CC + c0 + tid], s);
  }
}

// ---------------- SCA ----------------
__global__ void sca_kernel(const float* __restrict__ mean_raw, const float* __restrict__ sca_w,
                           const float* __restrict__ sca_b, const int* __restrict__ pair_e,
                           int pair_lo, float* __restrict__ s_buf) {
  __shared__ float m[CC];
  int pc = blockIdx.x, p = pair_lo + pc, e = pair_e[p];
  int tid = threadIdx.x;
  m[tid] = mean_raw[p * CC + tid] * (1.f / HWP);
  __syncthreads();
  const float* wr = sca_w + (size_t)(e * CC + tid) * CC;
  float acc = sca_b[e * CC + tid];
#pragma unroll 8
  for (int c = 0; c < CC; c++) acc = fmaf(wr[c], m[c], acc);
  s_buf[pc * CC + tid] = acc;
}

// ---------------- W3eff[pc][o][k] = conv3_w[e][o][k] * s[pc][k] * beta[e][o] (bf16) ----------------
__global__ void w3fold_kernel(const float* __restrict__ conv3_w, const float* __restrict__ beta,
                              const float* __restrict__ s_buf, const int* __restrict__ pair_e,
                              int pair_lo, ushort* __restrict__ W3eff) {
  int gid = blockIdx.x * 256 + threadIdx.x;
  int base = gid * 8;
  int pc = base >> 14, rem = base & 16383;
  int o = rem >> 7, k0 = rem & 127;
  int e = pair_e[pair_lo + pc];
  float bt = beta[e * CC + o];
  const float* src = conv3_w + ((size_t)e * CC + o) * CC + k0;
  const float* sv = s_buf + pc * CC + k0;
  ushort* dst = W3eff + ((size_t)pc * CC + o) * CC + k0;
  for (int q = 0; q < 8; q++) dst[q] = f2bf(src[q] * sv[q] * bt);
}

// ---------------- LN2 (pixel-major bf16 in/out) ----------------
__global__ __launch_bounds__(256) void ln2_kernel(const ushort* __restrict__ x,
                                                  ushort* __restrict__ xh) {
  size_t gid = (size_t)blockIdx.x * 256 + threadIdx.x;
  const ushort* px = x + gid * CC;
  ushort4 u[32];
  float s = 0.f, s2 = 0.f;
#pragma unroll
  for (int i = 0; i < 32; i++) {
    u[i] = *(const ushort4*)(px + i * 4);
    float a = bf2f(u[i].x), b = bf2f(u[i].y), c = bf2f(u[i].z), d = bf2f(u[i].w);
    s += a + b + c + d; s2 += a*a + b*b + c*c + d*d;
  }
  float mu = s * (1.f / CC);
  float var = s2 * (1.f / CC) - mu * mu;
  float r = rsqrtf(var + EPSLN);
  ushort* po = xh + gid * CC;
#pragma unroll
  for (int i = 0; i < 32; i++) {
    *(ushort4*)(po + i * 4) = pack4((bf2f(u[i].x)-mu)*r, (bf2f(u[i].y)-mu)*r,
                                    (bf2f(u[i].z)-mu)*r, (bf2f(u[i].w)-mu)*r);
  }
}

// ---------------- conv5: 3-pair accumulated MFMA + transpose epilogue to fp32 NCHW ----------------
__global__ __launch_bounds__(256, 2) void conv5_kernel(
    const ushort* __restrict__ W5eff, const float* __restrict__ b5tot,
    const ushort* __restrict__ t2, const ushort* __restrict__ x1,
    const float* __restrict__ gate_w, int pair_lo, float* __restrict__ out) {
  __shared__ ushort Ws[CC * CC];
  __shared__ ushort As[CC * CC];
  int sl = blockIdx.z;
  int n0 = blockIdx.x * 128;
  int b = pair_lo / KT + sl;
  int tid = threadIdx.x, lane = tid & 63, w = tid >> 6;
  int wr = w >> 1, wc = w & 1;
  int fr = lane & 15, kb0 = (lane >> 4) * 16, og = (lane >> 4) * 4;
  f32x4 acc[4][4] = {};
  for (int j = 0; j < KT; j++) {
    int pc = sl * KT + j, p = pair_lo + pc;
    __syncthreads();
    stage_tile(W5eff + (size_t)p * CC * CC, Ws, tid);
#pragma unroll
    for (int i = 0; i < 8; i++) {
      int d = (tid + i * 256) * 16;
      int row = d >> 8, kb = d & 255;
      const char* src = (const char*)(t2 + ((size_t)pc * HWP + n0 + row) * DWC) + kb;
      ushort4 a0 = *(const ushort4*)src;
      ushort4 a1 = *(const ushort4*)(src + 8);
      ushort4 g0 = *(const ushort4*)(src + 256);
      ushort4 g1 = *(const ushort4*)(src + 264);
      ushort4 r0, r1;
      r0.x = f2bf(bf2f(a0.x) * bf2f(g0.x)); r0.y = f2bf(bf2f(a0.y) * bf2f(g0.y));
      r0.z = f2bf(bf2f(a0.z) * bf2f(g0.z)); r0.w = f2bf(bf2f(a0.w) * bf2f(g0.w));
      r1.x = f2bf(bf2f(a1.x) * bf2f(g1.x)); r1.y = f2bf(bf2f(a1.y) * bf2f(g1.y));
      r1.z = f2bf(bf2f(a1.z) * bf2f(g1.z)); r1.w = f2bf(bf2f(a1.w) * bf2f(g1.w));
      char* dst = (char*)As + (d ^ ((row & 7) << 4));
      *(ushort4*)dst = r0;
      *(ushort4*)(dst + 8) = r1;
    }
    __syncthreads();
#pragma unroll
    for (int ks = 0; ks < 4; ks++) {
      bf16x8 a[4], bfr[4];
#pragma unroll
      for (int m = 0; m < 4; m++) a[m] = ldfrag(Ws, wr * 64 + m * 16 + fr, ks * 64 + kb0);
#pragma unroll
      for (int n = 0; n < 4; n++) bfr[n] = ldfrag(As, wc * 64 + n * 16 + fr, ks * 64 + kb0);
#pragma unroll
      for (int m = 0; m < 4; m++)
#pragma unroll
        for (int n = 0; n < 4; n++)
          acc[m][n] = __builtin_amdgcn_mfma_f32_16x16x32_bf16(a[m], bfr[n], acc[m][n], 0, 0, 0);
    }
  }
  float gw0 = gate_w[pair_lo + sl * KT + 0];
  float gw1 = gate_w[pair_lo + sl * KT + 1];
  float gw2 = gate_w[pair_lo + sl * KT + 2];
  __syncthreads();
  ushort* Ct = As;
#pragma unroll
  for (int m = 0; m < 4; m++) {
    int o = wr * 64 + m * 16 + og;
    float4 bt = *(const float4*)&b5tot[b * CC + o];
#pragma unroll
    for (int n = 0; n < 4; n++) {
      int px = wc * 64 + n * 16 + fr;
      f32x4 v = acc[m][n];
      float r0 = v.x + bt.x, r1 = v.y + bt.y, r2 = v.z + bt.z, r3 = v.w + bt.w;
      size_t xoff = ((size_t)(sl * KT) * HWP + n0 + px) * CC + o;
      ushort4 xa = *(const ushort4*)(x1 + xoff);
      ushort4 xb = *(const ushort4*)(x1 + xoff + (size_t)HWP * CC);
      ushort4 xc = *(const ushort4*)(x1 + xoff + 2 * (size_t)HWP * CC);
      r0 += gw0 * bf2f(xa.x) + gw1 * bf2f(xb.x) + gw2 * bf2f(xc.x);
      r1 += gw0 * bf2f(xa.y) + gw1 * bf2f(xb.y) + gw2 * bf2f(xc.y);
      r2 += gw0 * bf2f(xa.z) + gw1 * bf2f(xb.z) + gw2 * bf2f(xc.z);
      r3 += gw0 * bf2f(xa.w) + gw1 * bf2f(xb.w) + gw2 * bf2f(xc.w);
      *(ushort*)((char*)Ct + (o+0) * 256 + ((px*2) ^ (((o+0) & 7) << 4))) = f2bf(r0);
      *(ushort*)((char*)Ct + (o+1) * 256 + ((px*2) ^ (((o+1) & 7) << 4))) = f2bf(r1);
      *(ushort*)((char*)Ct + (o+2) * 256 + ((px*2) ^ (((o+2) & 7) << 4))) = f2bf(r2);
      *(ushort*)((char*)Ct + (o+3) * 256 + ((px*2) ^ (((o+3) & 7) << 4))) = f2bf(r3);
    }
  }
  __syncthreads();
  int o = tid >> 1, ph = (tid & 1) * 64;
  float* orow = out + ((size_t)(b * CC + o)) * HWP + n0 + ph;
  int swz = (o & 7) << 4;
#pragma unroll
  for (int i = 0; i < 8; i++) {
    const ushort* lp = (const ushort*)((const char*)Ct + o * 256 + ((ph * 2 + i * 16) ^ swz));
    float4 f0, f1;
    f0.x = bf2f(lp[0]); f0.y = bf2f(lp[1]); f0.z = bf2f(lp[2]); f0.w = bf2f(lp[3]);
    f1.x = bf2f(lp[4]); f1.y = bf2f(lp[5]); f1.z = bf2f(lp[6]); f1.w = bf2f(lp[7]);
    *(float4*)(orow + i * 8) = f0;
    *(float4*)(orow + i * 8 + 4) = f1;
  }
}

extern "C" void kernel_launch(void* const* d_in, const int* in_sizes, int n_in,
                              void* d_out, int out_size, void* d_ws, size_t ws_size,
                              hipStream_t stream) {
  const float* feat    = (const float*)d_in[0];
  const float* weights = (const float*)d_in[1];
  const float* ln1_w   = (const float*)d_in[2];
  const float* ln1_b   = (const float*)d_in[3];
  const float* conv1_w = (const float*)d_in[4];
  const float* conv1_b = (const float*)d_in[5];
  const float* conv2_w = (const float*)d_in[6];
  const float* conv2_b = (const float*)d_in[7];
  const float* sca_w   = (const float*)d_in[8];
  const float* sca_b   = (const float*)d_in[9];
  const float* conv3_w = (const float*)d_in[10];
  const float* conv3_b = (const float*)d_in[11];
  const float* ln2_w   = (const float*)d_in[12];
  const float* ln2_b   = (const float*)d_in[13];
  const float* conv4_w = (const float*)d_in[14];
  const float* conv4_b = (const float*)d_in[15];
  const float* conv5_w = (const float*)d_in[16];
  const float* conv5_b = (const float*)d_in[17];
  const float* beta    = (const float*)d_in[18];
  const float* gamma   = (const float*)d_in[19];

  float* out = (float*)d_out;
  float* out_counts = out + (size_t)BB * CC * HWP;
  float* out_weights = out_counts + EN;

  char* base = (char*)d_ws;
  size_t off = 0;
  auto carveU = [&](size_t n) -> ushort* { ushort* p = (ushort*)(base + off); off += n * 2; return p; };
  auto carveF = [&](size_t n) -> float* { float* p = (float*)(base + off); off += n * 4; return p; };

  ushort* W1eff = carveU((size_t)EN * DWC * CC);
  ushort* W4eff = carveU((size_t)EN * DWC * CC);
  ushort* W5eff = carveU((size_t)NPAIR * CC * CC);
  ushort* W3eff = carveU((size_t)NPAIR * CC * CC);
  float* b1eff  = carveF(EN * DWC);
  float* b4eff  = carveF(EN * DWC);
  float* b3eff  = carveF(EN * CC);
  float* b5tot  = carveF(BB * CC);
  float* gate_w = carveF(64);
  int*   pair_e = (int*)carveF(64);
  float* mean_raw = carveF(NPAIR * CC);
  float* s_buf  = carveF(NPAIR * CC);
  ushort* xhatT = carveU((size_t)BB * HWP * CC);
  ushort* featT = carveU((size_t)BB * HWP * CC);

  const size_t per_pair = ((size_t)HWP * DWC + 3 * (size_t)HWP * CC) * 2;  // bytes
  int ns = 16;
  while (ns > 1 && off + (size_t)ns * KT * per_pair > ws_size) ns >>= 1;
  size_t pr = (size_t)ns * KT;
  ushort* t_T   = carveU(pr * HWP * DWC);
  ushort* y_T   = carveU(pr * HWP * CC);
  ushort* x1_T  = carveU(pr * HWP * CC);
  ushort* xh2_T = carveU(pr * HWP * CC);

  gate_kernel<<<1, 256, 0, stream>>>(weights, gate_w, pair_e, out_counts, out_weights, mean_raw);
  fold_kernel<<<13, 256, 0, stream>>>(conv1_w, conv1_b, ln1_w, ln1_b,
                                      conv4_w, conv4_b, ln2_w, ln2_b,
                                      conv3_b, beta, W1eff, b1eff, W4eff, b4eff, b3eff);
  fold2_kernel<<<393, 256, 0, stream>>>(conv5_w, conv5_b, gamma, gate_w, pair_e, W5eff, b5tot);
  ln1_kernel<<<BB * 64, 256, 0, stream>>>(feat, xhatT, featT);

  for (int s0 = 0; s0 < BB; s0 += ns) {
    int np = ns * KT, plo = s0 * KT;
    gemm_kernel<0><<<dim3(32, 2, np), 256, 0, stream>>>(W1eff, b1eff, xhatT, nullptr,
                                                        pair_e, plo, 0, DWC, t_T);
    dwsg_kernel<<<dim3(4, 16, np), 256, 0, stream>>>(t_T, conv2_w, conv2_b, pair_e, plo,
                                                     y_T, mean_raw);
    sca_kernel<<<np, CC, 0, stream>>>(mean_raw, sca_w, sca_b, pair_e, plo, s_buf);
    w3fold_kernel<<<np * 8, 256, 0, stream>>>(conv3_w, beta, s_buf, pair_e, plo, W3eff);
    gemm_kernel<1><<<dim3(32, 1, np), 256, 0, stream>>>(W3eff, b3eff, y_T, featT,
                                                        pair_e, plo, 0, CC, x1_T);
    ln2_kernel<<<np * 16, 256, 0, stream>>>(x1_T, xh2_T);
    gemm_kernel<0><<<dim3(32, 2, np), 256, 0, stream>>>(W4eff, b4eff, xh2_T, nullptr,
                                                        pair_e, plo, 1, DWC, t_T);
    conv5_kernel<<<dim3(32, 1, ns), 256, 0, stream>>>(W5eff, b5tot, t_T, x1_T,
                                                      gate_w, plo, out);
  }
}

// Round 4
// 289.673 us; speedup vs baseline: 2.7397x; 1.3081x over previous
//
#include <hip/hip_runtime.h>

#define EN 5
#define KT 3
#define BB 16
#define CC 128
#define HWP 4096
#define DWC 256
#define NPAIR 48
#define EPSLN 1e-6f

typedef float f32x4 __attribute__((ext_vector_type(4)));
typedef __bf16 bf16x8 __attribute__((ext_vector_type(8)));

__device__ __forceinline__ float bf2f(ushort u) {
  union { unsigned int u; float f; } v; v.u = ((unsigned int)u) << 16; return v.f;
}
__device__ __forceinline__ ushort f2bf(float f) {
  union { float f; unsigned int u; } v; v.f = f;
  unsigned int r = v.u + 0x7FFFu + ((v.u >> 16) & 1u);
  return (ushort)(r >> 16);
}
__device__ __forceinline__ ushort4 pack4(float a, float b, float c, float d) {
  ushort4 r; r.x = f2bf(a); r.y = f2bf(b); r.z = f2bf(c); r.w = f2bf(d); return r;
}

// ---------------- gate ----------------
__global__ void gate_kernel(const float* __restrict__ weights, float* __restrict__ gate_w,
                            int* __restrict__ pair_e, float* __restrict__ out_counts,
                            float* __restrict__ out_weights, float* __restrict__ mean_raw) {
  __shared__ int sel[NPAIR];
  int tid = threadIdx.x;
  if (tid < BB) {
    float w[EN];
    for (int e = 0; e < EN; e++) w[e] = weights[tid * EN + e];
    int ch[KT]; float cv[KT]; float sum = 0.f;
    for (int j = 0; j < KT; j++) {
      int best = -1; float bv = -3.4e38f;
      for (int e = 0; e < EN; e++) {
        bool used = false;
        for (int q = 0; q < j; q++) if (ch[q] == e) used = true;
        if (!used && w[e] > bv) { bv = w[e]; best = e; }
      }
      ch[j] = best; cv[j] = bv; sum += bv;
    }
    float inv = 1.f / sum;
    for (int j = 0; j < KT; j++) {
      gate_w[tid * KT + j] = cv[j] * inv;
      pair_e[tid * KT + j] = ch[j];
      sel[tid * KT + j] = ch[j];
    }
  }
  for (int i = tid; i < NPAIR * CC; i += 256) mean_raw[i] = 0.f;
  __syncthreads();
  if (tid < EN) {
    int cnt = 0;
    for (int i = 0; i < NPAIR; i++) if (sel[i] == tid) cnt++;
    out_counts[tid] = (float)cnt;
  }
  if (tid < BB * EN) out_weights[tid] = weights[tid];
}

// ---------------- fold LN into conv1/conv4 ----------------
__global__ void fold_kernel(const float* __restrict__ conv1_w, const float* __restrict__ conv1_b,
                            const float* __restrict__ ln1_w, const float* __restrict__ ln1_b,
                            const float* __restrict__ conv4_w, const float* __restrict__ conv4_b,
                            const float* __restrict__ ln2_w, const float* __restrict__ ln2_b,
                            const float* __restrict__ conv3_b, const float* __restrict__ beta,
                            ushort* __restrict__ W1eff, float* __restrict__ b1eff,
                            ushort* __restrict__ W4eff, float* __restrict__ b4eff,
                            float* __restrict__ b3eff) {
  int gid = blockIdx.x * 256 + threadIdx.x;
  if (gid < 2 * EN * DWC) {
    int which = gid / (EN * DWC), rem = gid % (EN * DWC);
    int e = rem / DWC, o = rem % DWC;
    const float* src = (which ? conv4_w : conv1_w) + (size_t)(e * DWC + o) * CC;
    const float* lw = (which ? ln2_w : ln1_w) + e * CC;
    const float* lb = (which ? ln2_b : ln1_b) + e * CC;
    float bacc = (which ? conv4_b : conv1_b)[e * DWC + o];
    ushort* dst = (which ? W4eff : W1eff) + (size_t)(e * DWC + o) * CC;
    for (int c = 0; c < CC; c++) {
      float wv = src[c];
      dst[c] = f2bf(wv * lw[c]);
      bacc += wv * lb[c];
    }
    (which ? b4eff : b1eff)[e * DWC + o] = bacc;
  } else if (gid < 2 * EN * DWC + EN * CC) {
    int x = gid - 2 * EN * DWC;
    b3eff[x] = beta[x] * conv3_b[x];
  }
}

// ---------------- fold2: W5eff[p]=conv5_w[e]*gamma*gate; b5tot ----------------
__global__ void fold2_kernel(const float* __restrict__ conv5_w, const float* __restrict__ conv5_b,
                             const float* __restrict__ gamma, const float* __restrict__ gate_w,
                             const int* __restrict__ pair_e,
                             ushort* __restrict__ W5eff, float* __restrict__ b5tot) {
  int gid = blockIdx.x * 256 + threadIdx.x;
  const int nW = NPAIR * CC * CC / 8;
  if (gid < nW) {
    int base = gid * 8;
    int p = base >> 14, rem = base & 16383;
    int o = rem >> 7, k0 = rem & 127;
    int e = pair_e[p];
    float sc = gamma[e * CC + o] * gate_w[p];
    const float* src = conv5_w + ((size_t)e * CC + o) * CC + k0;
    ushort* dst = W5eff + ((size_t)p * CC + o) * CC + k0;
    for (int q = 0; q < 8; q++) dst[q] = f2bf(src[q] * sc);
  } else if (gid < nW + BB * CC) {
    int x = gid - nW;
    int b = x >> 7, o = x & 127;
    float s = 0.f;
    for (int j = 0; j < KT; j++) {
      int p = b * KT + j, e = pair_e[p];
      s += gate_w[p] * gamma[e * CC + o] * conv5_b[e * CC + o];
    }
    b5tot[x] = s;
  }
}

// ---------------- LN1 + transpose ----------------
__global__ __launch_bounds__(256) void ln1_kernel(const float* __restrict__ feat,
                                                  ushort* __restrict__ xhatT,
                                                  ushort* __restrict__ featT) {
  __shared__ float tile[CC * 64];
  __shared__ float pS[4][64], pS2[4][64], bcM[64], bcR[64];
  int bimg = blockIdx.x >> 6;
  int n0 = (blockIdx.x & 63) * 64;
  int tid = threadIdx.x;
  const float* src = feat + (size_t)bimg * CC * HWP + n0;
#pragma unroll
  for (int i = 0; i < 8; i++) {
    int ch = tid + i * 256;
    int row = ch >> 4, c16 = ch & 15;
    *(float4*)&tile[row * 64 + c16 * 4] = *(const float4*)(src + (size_t)row * HWP + c16 * 4);
  }
  __syncthreads();
  int lane = tid & 63, w = tid >> 6;
  float s = 0.f, s2 = 0.f;
#pragma unroll
  for (int i = 0; i < 32; i++) {
    float v = tile[(w * 32 + i) * 64 + lane];
    s += v; s2 += v * v;
  }
  pS[w][lane] = s; pS2[w][lane] = s2;
  __syncthreads();
  if (w == 0) {
    float t1 = pS[0][lane] + pS[1][lane] + pS[2][lane] + pS[3][lane];
    float t2 = pS2[0][lane] + pS2[1][lane] + pS2[2][lane] + pS2[3][lane];
    float mu = t1 * (1.f / CC);
    float var = t2 * (1.f / CC) - mu * mu;
    bcM[lane] = mu; bcR[lane] = rsqrtf(var + EPSLN);
  }
  __syncthreads();
  float mu = bcM[lane], r = bcR[lane];
  size_t obase = ((size_t)bimg * HWP + n0 + lane) * CC + w * 32;
#pragma unroll
  for (int i = 0; i < 4; i++) {
    float v[8];
#pragma unroll
    for (int q = 0; q < 8; q++) v[q] = tile[(w * 32 + i * 8 + q) * 64 + lane];
    *(ushort4*)(featT + obase + i * 8)     = pack4(v[0], v[1], v[2], v[3]);
    *(ushort4*)(featT + obase + i * 8 + 4) = pack4(v[4], v[5], v[6], v[7]);
    *(ushort4*)(xhatT + obase + i * 8)     = pack4((v[0]-mu)*r, (v[1]-mu)*r, (v[2]-mu)*r, (v[3]-mu)*r);
    *(ushort4*)(xhatT + obase + i * 8 + 4) = pack4((v[4]-mu)*r, (v[5]-mu)*r, (v[6]-mu)*r, (v[7]-mu)*r);
  }
}

// ---------------- shared helpers ----------------
__device__ __forceinline__ void stage_tile(const ushort* __restrict__ g, ushort* lds, int tid) {
#pragma unroll
  for (int i = 0; i < 8; i++) {
    int d = (tid + i * 256) * 16;
    int row = d >> 8;
    uint4 v = *(const uint4*)((const char*)g + d);
    *(uint4*)((char*)lds + (d ^ ((row & 7) << 4))) = v;
  }
}
__device__ __forceinline__ bf16x8 ldfrag(const ushort* lds, int row, int kb) {
  return *(const bf16x8*)((const char*)lds + row * 256 + (kb ^ ((row & 7) << 4)));
}
__device__ __forceinline__ void stage8(ushort* st, int px, int o, ushort4 v) {
  *(ushort4*)((char*)st + px * 256 + ((o * 2) ^ ((px & 7) << 4))) = v;
}
__device__ __forceinline__ uint4 ldstage16(const ushort* st, int px, int ck) {
  return *(const uint4*)((const char*)st + px * 256 + ((ck * 16) ^ ((px & 7) << 4)));
}

// ---------------- conv1: MFMA + bias + staged coalesced store ----------------
__global__ __launch_bounds__(256, 2) void conv1_kernel(
    const ushort* __restrict__ W1eff, const float* __restrict__ b1eff,
    const ushort* __restrict__ xhatT, const int* __restrict__ pair_e,
    int pair_lo, ushort* __restrict__ tT) {
  __shared__ ushort Ws[CC * CC];
  __shared__ ushort As[CC * CC];
  int pc = blockIdx.z, p = pair_lo + pc, e = pair_e[p];
  int img = p / KT;
  int n0 = blockIdx.x * 128, m0 = blockIdx.y * 128;
  int tid = threadIdx.x, lane = tid & 63, w = tid >> 6;
  stage_tile(W1eff + ((size_t)e * DWC + m0) * CC, Ws, tid);
  stage_tile(xhatT + ((size_t)img * HWP + n0) * CC, As, tid);
  __syncthreads();
  int wr = w >> 1, wc = w & 1, fr = lane & 15, kb0 = (lane >> 4) * 16, og = (lane >> 4) * 4;
  f32x4 acc[4][4] = {};
#pragma unroll
  for (int ks = 0; ks < 4; ks++) {
    bf16x8 a[4], b[4];
#pragma unroll
    for (int m = 0; m < 4; m++) a[m] = ldfrag(Ws, wr * 64 + m * 16 + fr, ks * 64 + kb0);
#pragma unroll
    for (int n = 0; n < 4; n++) b[n] = ldfrag(As, wc * 64 + n * 16 + fr, ks * 64 + kb0);
#pragma unroll
    for (int m = 0; m < 4; m++)
#pragma unroll
      for (int n = 0; n < 4; n++)
        acc[m][n] = __builtin_amdgcn_mfma_f32_16x16x32_bf16(a[m], b[n], acc[m][n], 0, 0, 0);
  }
  __syncthreads();
#pragma unroll
  for (int m = 0; m < 4; m++) {
    int ol = wr * 64 + m * 16 + og;
    float4 bv = *(const float4*)&b1eff[e * DWC + m0 + ol];
#pragma unroll
    for (int n = 0; n < 4; n++) {
      int px = wc * 64 + n * 16 + fr;
      f32x4 v = acc[m][n];
      stage8(As, px, ol, pack4(v.x + bv.x, v.y + bv.y, v.z + bv.z, v.w + bv.w));
    }
  }
  __syncthreads();
#pragma unroll
  for (int i = 0; i < 8; i++) {
    int idx = tid + i * 256;
    int px = idx >> 4, ck = idx & 15;
    uint4 v = ldstage16(As, px, ck);
    *(uint4*)((char*)(tT + ((size_t)pc * HWP + n0 + px) * DWC + m0) + ck * 16) = v;
  }
}

// ---------------- depthwise 3x3 + SG + mean, interleaved halo, coalesced out ----------------
#define HALO 18
__global__ __launch_bounds__(256) void dwsg_kernel(
    const ushort* __restrict__ tT, const float* __restrict__ conv2_w,
    const float* __restrict__ conv2_b, const int* __restrict__ pair_e, int pair_lo,
    ushort* __restrict__ yT, float* __restrict__ mean_raw) {
  __shared__ ushort halo[HALO * HALO * 64];   // [px][8 slots of (4a|4g)] 128B rows
  __shared__ ushort ystage[256 * 32];         // [px][32ch] 64B rows, swizzled
  __shared__ float psum[8][32];
  int cg4 = blockIdx.x;
  int ts = blockIdx.y;
  int pc = blockIdx.z, p = pair_lo + pc, e = pair_e[p];
  int c0 = cg4 * 32;
  int th = (ts >> 2) * 16, tw = (ts & 3) * 16;
  int tid = threadIdx.x;
  for (int it = 0; it < 11; it++) {
    int idx = tid + it * 256;
    if (idx < HALO * HALO * 8) {
      int px = idx >> 3, sl = idx & 7;
      int hh = px / HALO - 1 + th, ww = px % HALO - 1 + tw;
      ushort4 a = {0, 0, 0, 0}, g = {0, 0, 0, 0};
      if (hh >= 0 && hh < 64 && ww >= 0 && ww < 64) {
        const ushort* src = tT + ((size_t)pc * HWP + hh * 64 + ww) * DWC + c0 + sl * 4;
        a = *(const ushort4*)src;
        g = *(const ushort4*)(src + CC);
      }
      char* dst = (char*)halo + px * 128 + ((sl * 16) ^ ((px & 7) << 4));
      *(ushort4*)dst = a;
      *(ushort4*)(dst + 8) = g;
    }
  }
  __syncthreads();
  int ww_ = tid & 15, hh_ = tid >> 4;
  int ps = hh_ * 16 + ww_;
  const float* wA = conv2_w + ((size_t)e * DWC + c0) * 9;
  const float* wG = conv2_w + ((size_t)e * DWC + CC + c0) * 9;
  const float* bA = conv2_b + e * DWC + c0;
  const float* bG = conv2_b + e * DWC + CC + c0;
  for (int cg = 0; cg < 8; cg++) {
    int ci = cg * 4;
    float accA[4] = {}, accG[4] = {};
#pragma unroll
    for (int dh = 0; dh < 3; dh++) {
#pragma unroll
      for (int dw = 0; dw < 3; dw++) {
        int px = (hh_ + dh) * HALO + ww_ + dw;
        const char* hp = (const char*)halo + px * 128 + ((cg * 16) ^ ((px & 7) << 4));
        ushort4 va = *(const ushort4*)hp;
        ushort4 vg = *(const ushort4*)(hp + 8);
        int wo = dh * 3 + dw;
        accA[0] = fmaf(bf2f(va.x), wA[(ci + 0) * 9 + wo], accA[0]);
        accA[1] = fmaf(bf2f(va.y), wA[(ci + 1) * 9 + wo], accA[1]);
        accA[2] = fmaf(bf2f(va.z), wA[(ci + 2) * 9 + wo], accA[2]);
        accA[3] = fmaf(bf2f(va.w), wA[(ci + 3) * 9 + wo], accA[3]);
        accG[0] = fmaf(bf2f(vg.x), wG[(ci + 0) * 9 + wo], accG[0]);
        accG[1] = fmaf(bf2f(vg.y), wG[(ci + 1) * 9 + wo], accG[1]);
        accG[2] = fmaf(bf2f(vg.z), wG[(ci + 2) * 9 + wo], accG[2]);
        accG[3] = fmaf(bf2f(vg.w), wG[(ci + 3) * 9 + wo], accG[3]);
      }
    }
    float y0 = (accA[0] + bA[ci + 0]) * (accG[0] + bG[ci + 0]);
    float y1 = (accA[1] + bA[ci + 1]) * (accG[1] + bG[ci + 1]);
    float y2 = (accA[2] + bA[ci + 2]) * (accG[2] + bG[ci + 2]);
    float y3 = (accA[3] + bA[ci + 3]) * (accG[3] + bG[ci + 3]);
    *(ushort4*)((char*)ystage + ps * 64 + ((cg * 8) ^ ((ps & 3) << 4))) = pack4(y0, y1, y2, y3);
  }
  __syncthreads();
  // coalesced y write-out
#pragma unroll
  for (int i = 0; i < 4; i++) {
    int idx = tid + i * 256;
    int px = idx >> 2, ck = idx & 3;
    uint4 v = *(const uint4*)((const char*)ystage + px * 64 + ((ck * 16) ^ ((px & 3) << 4)));
    int hh = px >> 4, wwv = px & 15;
    int n = (th + hh) * 64 + tw + wwv;
    *(uint4*)((char*)(yT + ((size_t)pc * HWP + n) * CC + c0) + ck * 16) = v;
  }
  // mean partials
  {
    int ch = tid & 31, grp = tid >> 5;
    int cg = ch >> 2, sub = ch & 3;
    float s = 0.f;
#pragma unroll
    for (int j = 0; j < 32; j++) {
      int px = grp * 32 + j;
      s += bf2f(*(const ushort*)((const char*)ystage + px * 64 + ((cg * 8) ^ ((px & 3) << 4)) + sub * 2));
    }
    psum[grp][ch] = s;
  }
  __syncthreads();
  if (tid < 32) {
    float s = 0.f;
#pragma unroll
    for (int g2 = 0; g2 < 8; g2++) s += psum[g2][tid];
    atomicAdd(&mean_raw[p * CC + c0 + tid], s);
  }
}

// ---------------- SCA ----------------
__global__ void sca_kernel(const float* __restrict__ mean_raw, const float* __restrict__ sca_w,
                           const float* __restrict__ sca_b, const int* __restrict__ pair_e,
                           int pair_lo, float* __restrict__ s_buf) {
  __shared__ float m[CC];
  int pc = blockIdx.x, p = pair_lo + pc, e = pair_e[p];
  int tid = threadIdx.x;
  m[tid] = mean_raw[p * CC + tid] * (1.f / HWP);
  __syncthreads();
  const float* wr = sca_w + (size_t)(e * CC + tid) * CC;
  float acc = sca_b[e * CC + tid];
#pragma unroll 8
  for (int c = 0; c < CC; c++) acc = fmaf(wr[c], m[c], acc);
  s_buf[pc * CC + tid] = acc;
}

// ---------------- W3eff fold ----------------
__global__ void w3fold_kernel(const float* __restrict__ conv3_w, const float* __restrict__ beta,
                              const float* __restrict__ s_buf, const int* __restrict__ pair_e,
                              int pair_lo, ushort* __restrict__ W3eff) {
  int gid = blockIdx.x * 256 + threadIdx.x;
  int base = gid * 8;
  int pc = base >> 14, rem = base & 16383;
  int o = rem >> 7, k0 = rem & 127;
  int e = pair_e[pair_lo + pc];
  float bt = beta[e * CC + o];
  const float* src = conv3_w + ((size_t)e * CC + o) * CC + k0;
  const float* sv = s_buf + pc * CC + k0;
  ushort* dst = W3eff + ((size_t)pc * CC + o) * CC + k0;
  for (int q = 0; q < 8; q++) dst[q] = f2bf(src[q] * sv[q] * bt);
}

// ---------------- conv3 + residual + fused LN2 ----------------
__global__ __launch_bounds__(256, 2) void conv3_ln2_kernel(
    const ushort* __restrict__ W3eff, const float* __restrict__ b3eff,
    const ushort* __restrict__ yT, const ushort* __restrict__ featT,
    const int* __restrict__ pair_e, int pair_lo,
    ushort* __restrict__ x1T, ushort* __restrict__ xh2T) {
  __shared__ ushort Ws[CC * CC];
  __shared__ ushort As[CC * CC];
  int pc = blockIdx.z, p = pair_lo + pc, e = pair_e[p];
  int img = p / KT;
  int n0 = blockIdx.x * 128;
  int tid = threadIdx.x, lane = tid & 63, w = tid >> 6;
  stage_tile(W3eff + (size_t)pc * CC * CC, Ws, tid);
  stage_tile(yT + ((size_t)pc * HWP + n0) * CC, As, tid);
  __syncthreads();
  int wr = w >> 1, wc = w & 1, fr = lane & 15, kb0 = (lane >> 4) * 16, og = (lane >> 4) * 4;
  f32x4 acc[4][4] = {};
#pragma unroll
  for (int ks = 0; ks < 4; ks++) {
    bf16x8 a[4], b[4];
#pragma unroll
    for (int m = 0; m < 4; m++) a[m] = ldfrag(Ws, wr * 64 + m * 16 + fr, ks * 64 + kb0);
#pragma unroll
    for (int n = 0; n < 4; n++) b[n] = ldfrag(As, wc * 64 + n * 16 + fr, ks * 64 + kb0);
#pragma unroll
    for (int m = 0; m < 4; m++)
#pragma unroll
      for (int n = 0; n < 4; n++)
        acc[m][n] = __builtin_amdgcn_mfma_f32_16x16x32_bf16(a[m], b[n], acc[m][n], 0, 0, 0);
  }
  // x1 = featT + acc + b3eff  (fp32 in regs), per-pixel LN stats
  float s[4] = {}, s2[4] = {};
#pragma unroll
  for (int m = 0; m < 4; m++) {
    int o = wr * 64 + m * 16 + og;
    float4 bv = *(const float4*)&b3eff[e * CC + o];
#pragma unroll
    for (int n = 0; n < 4; n++) {
      int px = wc * 64 + n * 16 + fr;
      ushort4 f4 = *(const ushort4*)(featT + ((size_t)img * HWP + n0 + px) * CC + o);
      f32x4 v = acc[m][n];
      v.x += bf2f(f4.x) + bv.x; v.y += bf2f(f4.y) + bv.y;
      v.z += bf2f(f4.z) + bv.z; v.w += bf2f(f4.w) + bv.w;
      acc[m][n] = v;
      s[n] += v.x + v.y + v.z + v.w;
      s2[n] += v.x * v.x + v.y * v.y + v.z * v.z + v.w * v.w;
    }
  }
#pragma unroll
  for (int n = 0; n < 4; n++) {
    s[n] += __shfl_xor(s[n], 16, 64); s[n] += __shfl_xor(s[n], 32, 64);
    s2[n] += __shfl_xor(s2[n], 16, 64); s2[n] += __shfl_xor(s2[n], 32, 64);
  }
  __syncthreads();                       // (A) all MFMA/LDS reads done
  float2* red = (float2*)As;             // reuse As start as [2][128] float2
  if (lane < 16) {
#pragma unroll
    for (int n = 0; n < 4; n++) {
      float2 v; v.x = s[n]; v.y = s2[n];
      red[wr * 128 + wc * 64 + n * 16 + fr] = v;
    }
  }
  __syncthreads();                       // (B)
  float mu[4], rs[4];
#pragma unroll
  for (int n = 0; n < 4; n++) {
    int px = wc * 64 + n * 16 + fr;
    float2 r0 = red[px], r1 = red[128 + px];
    float m_ = (r0.x + r1.x) * (1.f / CC);
    float var = (r0.y + r1.y) * (1.f / CC) - m_ * m_;
    mu[n] = m_; rs[n] = rsqrtf(var + EPSLN);
  }
  __syncthreads();                       // (C) red consumed, stage buffers free
#pragma unroll
  for (int m = 0; m < 4; m++) {
    int o = wr * 64 + m * 16 + og;
#pragma unroll
    for (int n = 0; n < 4; n++) {
      int px = wc * 64 + n * 16 + fr;
      f32x4 v = acc[m][n];
      stage8(As, px, o, pack4(v.x, v.y, v.z, v.w));
      stage8(Ws, px, o, pack4((v.x - mu[n]) * rs[n], (v.y - mu[n]) * rs[n],
                              (v.z - mu[n]) * rs[n], (v.w - mu[n]) * rs[n]));
    }
  }
  __syncthreads();                       // (D)
#pragma unroll
  for (int i = 0; i < 8; i++) {
    int idx = tid + i * 256;
    int px = idx >> 4, ck = idx & 15;
    size_t gb = ((size_t)pc * HWP + n0 + px) * CC;
    *(uint4*)((char*)(x1T + gb) + ck * 16)  = ldstage16(As, px, ck);
    *(uint4*)((char*)(xh2T + gb) + ck * 16) = ldstage16(Ws, px, ck);
  }
}

// ---------------- conv4 both halves + SimpleGate fused ----------------
__global__ __launch_bounds__(256, 2) void conv4sg_kernel(
    const ushort* __restrict__ W4eff, const float* __restrict__ b4eff,
    const ushort* __restrict__ xh2T, const int* __restrict__ pair_e,
    int pair_lo, ushort* __restrict__ g5T) {
  __shared__ ushort Ws[CC * CC];
  __shared__ ushort As[CC * CC];
  int pc = blockIdx.z, p = pair_lo + pc, e = pair_e[p];
  int n0 = blockIdx.x * 128;
  int tid = threadIdx.x, lane = tid & 63, w = tid >> 6;
  int wr = w >> 1, wc = w & 1, fr = lane & 15, kb0 = (lane >> 4) * 16, og = (lane >> 4) * 4;
  stage_tile(W4eff + (size_t)e * DWC * CC, Ws, tid);
  stage_tile(xh2T + ((size_t)pc * HWP + n0) * CC, As, tid);
  __syncthreads();
  f32x4 accA[4][4] = {}, accG[4][4] = {};
#pragma unroll
  for (int ks = 0; ks < 4; ks++) {
    bf16x8 a[4], b[4];
#pragma unroll
    for (int m = 0; m < 4; m++) a[m] = ldfrag(Ws, wr * 64 + m * 16 + fr, ks * 64 + kb0);
#pragma unroll
    for (int n = 0; n < 4; n++) b[n] = ldfrag(As, wc * 64 + n * 16 + fr, ks * 64 + kb0);
#pragma unroll
    for (int m = 0; m < 4; m++)
#pragma unroll
      for (int n = 0; n < 4; n++)
        accA[m][n] = __builtin_amdgcn_mfma_f32_16x16x32_bf16(a[m], b[n], accA[m][n], 0, 0, 0);
  }
  __syncthreads();
  stage_tile(W4eff + ((size_t)e * DWC + CC) * CC, Ws, tid);
  __syncthreads();
#pragma unroll
  for (int ks = 0; ks < 4; ks++) {
    bf16x8 a[4], b[4];
#pragma unroll
    for (int m = 0; m < 4; m++) a[m] = ldfrag(Ws, wr * 64 + m * 16 + fr, ks * 64 + kb0);
#pragma unroll
    for (int n = 0; n < 4; n++) b[n] = ldfrag(As, wc * 64 + n * 16 + fr, ks * 64 + kb0);
#pragma unroll
    for (int m = 0; m < 4; m++)
#pragma unroll
      for (int n = 0; n < 4; n++)
        accG[m][n] = __builtin_amdgcn_mfma_f32_16x16x32_bf16(a[m], b[n], accG[m][n], 0, 0, 0);
  }
  __syncthreads();
#pragma unroll
  for (int m = 0; m < 4; m++) {
    int o = wr * 64 + m * 16 + og;
    float4 ba = *(const float4*)&b4eff[e * DWC + o];
    float4 bg = *(const float4*)&b4eff[e * DWC + CC + o];
#pragma unroll
    for (int n = 0; n < 4; n++) {
      int px = wc * 64 + n * 16 + fr;
      f32x4 va = accA[m][n], vg = accG[m][n];
      stage8(Ws, px, o, pack4((va.x + ba.x) * (vg.x + bg.x), (va.y + ba.y) * (vg.y + bg.y),
                              (va.z + ba.z) * (vg.z + bg.z), (va.w + ba.w) * (vg.w + bg.w)));
    }
  }
  __syncthreads();
#pragma unroll
  for (int i = 0; i < 8; i++) {
    int idx = tid + i * 256;
    int px = idx >> 4, ck = idx & 15;
    uint4 v = ldstage16(Ws, px, ck);
    *(uint4*)((char*)(g5T + ((size_t)pc * HWP + n0 + px) * CC) + ck * 16) = v;
  }
}

// ---------------- conv5: 3-pair accumulated MFMA + transpose epilogue ----------------
__global__ __launch_bounds__(256, 2) void conv5_kernel(
    const ushort* __restrict__ W5eff, const float* __restrict__ b5tot,
    const ushort* __restrict__ g5T, const ushort* __restrict__ x1,
    const float* __restrict__ gate_w, int pair_lo, float* __restrict__ out) {
  __shared__ ushort Ws[CC * CC];
  __shared__ ushort As[CC * CC];
  int sl = blockIdx.z;
  int n0 = blockIdx.x * 128;
  int b = pair_lo / KT + sl;
  int tid = threadIdx.x, lane = tid & 63, w = tid >> 6;
  int wr = w >> 1, wc = w & 1;
  int fr = lane & 15, kb0 = (lane >> 4) * 16, og = (lane >> 4) * 4;
  f32x4 acc[4][4] = {};
  for (int j = 0; j < KT; j++) {
    int pc = sl * KT + j, p = pair_lo + pc;
    __syncthreads();
    stage_tile(W5eff + (size_t)p * CC * CC, Ws, tid);
    stage_tile(g5T + ((size_t)pc * HWP + n0) * CC, As, tid);
    __syncthreads();
#pragma unroll
    for (int ks = 0; ks < 4; ks++) {
      bf16x8 a[4], bfr[4];
#pragma unroll
      for (int m = 0; m < 4; m++) a[m] = ldfrag(Ws, wr * 64 + m * 16 + fr, ks * 64 + kb0);
#pragma unroll
      for (int n = 0; n < 4; n++) bfr[n] = ldfrag(As, wc * 64 + n * 16 + fr, ks * 64 + kb0);
#pragma unroll
      for (int m = 0; m < 4; m++)
#pragma unroll
        for (int n = 0; n < 4; n++)
          acc[m][n] = __builtin_amdgcn_mfma_f32_16x16x32_bf16(a[m], bfr[n], acc[m][n], 0, 0, 0);
    }
  }
  float gw0 = gate_w[pair_lo + sl * KT + 0];
  float gw1 = gate_w[pair_lo + sl * KT + 1];
  float gw2 = gate_w[pair_lo + sl * KT + 2];
  __syncthreads();
  ushort* Ct = As;
#pragma unroll
  for (int m = 0; m < 4; m++) {
    int o = wr * 64 + m * 16 + og;
    float4 bt = *(const float4*)&b5tot[b * CC + o];
#pragma unroll
    for (int n = 0; n < 4; n++) {
      int px = wc * 64 + n * 16 + fr;
      f32x4 v = acc[m][n];
      float r0 = v.x + bt.x, r1 = v.y + bt.y, r2 = v.z + bt.z, r3 = v.w + bt.w;
      size_t xoff = ((size_t)(sl * KT) * HWP + n0 + px) * CC + o;
      ushort4 xa = *(const ushort4*)(x1 + xoff);
      ushort4 xb = *(const ushort4*)(x1 + xoff + (size_t)HWP * CC);
      ushort4 xc = *(const ushort4*)(x1 + xoff + 2 * (size_t)HWP * CC);
      r0 += gw0 * bf2f(xa.x) + gw1 * bf2f(xb.x) + gw2 * bf2f(xc.x);
      r1 += gw0 * bf2f(xa.y) + gw1 * bf2f(xb.y) + gw2 * bf2f(xc.y);
      r2 += gw0 * bf2f(xa.z) + gw1 * bf2f(xb.z) + gw2 * bf2f(xc.z);
      r3 += gw0 * bf2f(xa.w) + gw1 * bf2f(xb.w) + gw2 * bf2f(xc.w);
      *(ushort*)((char*)Ct + (o+0) * 256 + ((px*2) ^ (((o+0) & 7) << 4))) = f2bf(r0);
      *(ushort*)((char*)Ct + (o+1) * 256 + ((px*2) ^ (((o+1) & 7) << 4))) = f2bf(r1);
      *(ushort*)((char*)Ct + (o+2) * 256 + ((px*2) ^ (((o+2) & 7) << 4))) = f2bf(r2);
      *(ushort*)((char*)Ct + (o+3) * 256 + ((px*2) ^ (((o+3) & 7) << 4))) = f2bf(r3);
    }
  }
  __syncthreads();
  int o = tid >> 1, ph = (tid & 1) * 64;
  float* orow = out + ((size_t)(b * CC + o)) * HWP + n0 + ph;
  int swz = (o & 7) << 4;
#pragma unroll
  for (int i = 0; i < 8; i++) {
    const ushort* lp = (const ushort*)((const char*)Ct + o * 256 + ((ph * 2 + i * 16) ^ swz));
    float4 f0, f1;
    f0.x = bf2f(lp[0]); f0.y = bf2f(lp[1]); f0.z = bf2f(lp[2]); f0.w = bf2f(lp[3]);
    f1.x = bf2f(lp[4]); f1.y = bf2f(lp[5]); f1.z = bf2f(lp[6]); f1.w = bf2f(lp[7]);
    *(float4*)(orow + i * 8) = f0;
    *(float4*)(orow + i * 8 + 4) = f1;
  }
}

extern "C" void kernel_launch(void* const* d_in, const int* in_sizes, int n_in,
                              void* d_out, int out_size, void* d_ws, size_t ws_size,
                              hipStream_t stream) {
  const float* feat    = (const float*)d_in[0];
  const float* weights = (const float*)d_in[1];
  const float* ln1_w   = (const float*)d_in[2];
  const float* ln1_b   = (const float*)d_in[3];
  const float* conv1_w = (const float*)d_in[4];
  const float* conv1_b = (const float*)d_in[5];
  const float* conv2_w = (const float*)d_in[6];
  const float* conv2_b = (const float*)d_in[7];
  const float* sca_w   = (const float*)d_in[8];
  const float* sca_b   = (const float*)d_in[9];
  const float* conv3_w = (const float*)d_in[10];
  const float* conv3_b = (const float*)d_in[11];
  const float* ln2_w   = (const float*)d_in[12];
  const float* ln2_b   = (const float*)d_in[13];
  const float* conv4_w = (const float*)d_in[14];
  const float* conv4_b = (const float*)d_in[15];
  const float* conv5_w = (const float*)d_in[16];
  const float* conv5_b = (const float*)d_in[17];
  const float* beta    = (const float*)d_in[18];
  const float* gamma   = (const float*)d_in[19];

  float* out = (float*)d_out;
  float* out_counts = out + (size_t)BB * CC * HWP;
  float* out_weights = out_counts + EN;

  char* base = (char*)d_ws;
  size_t off = 0;
  auto carveU = [&](size_t n) -> ushort* { ushort* p = (ushort*)(base + off); off += n * 2; return p; };
  auto carveF = [&](size_t n) -> float* { float* p = (float*)(base + off); off += n * 4; return p; };

  ushort* W1eff = carveU((size_t)EN * DWC * CC);
  ushort* W4eff = carveU((size_t)EN * DWC * CC);
  ushort* W5eff = carveU((size_t)NPAIR * CC * CC);
  ushort* W3eff = carveU((size_t)NPAIR * CC * CC);
  float* b1eff  = carveF(EN * DWC);
  float* b4eff  = carveF(EN * DWC);
  float* b3eff  = carveF(EN * CC);
  float* b5tot  = carveF(BB * CC);
  float* gate_w = carveF(64);
  int*   pair_e = (int*)carveF(64);
  float* mean_raw = carveF(NPAIR * CC);
  float* s_buf  = carveF(NPAIR * CC);
  ushort* xhatT = carveU((size_t)BB * HWP * CC);
  ushort* featT = carveU((size_t)BB * HWP * CC);

  const size_t per_pair = ((size_t)HWP * DWC + 3 * (size_t)HWP * CC) * 2;  // bytes
  int ns = 16;
  while (ns > 1 && off + (size_t)ns * KT * per_pair > ws_size) ns >>= 1;
  size_t pr = (size_t)ns * KT;
  ushort* t_T   = carveU(pr * HWP * DWC);
  ushort* y_T   = carveU(pr * HWP * CC);
  ushort* x1_T  = carveU(pr * HWP * CC);
  ushort* xh2_T = carveU(pr * HWP * CC);
  ushort* g5_T  = t_T;  // alias: t_T dead after dwsg, reused for conv4 output

  gate_kernel<<<1, 256, 0, stream>>>(weights, gate_w, pair_e, out_counts, out_weights, mean_raw);
  fold_kernel<<<13, 256, 0, stream>>>(conv1_w, conv1_b, ln1_w, ln1_b,
                                      conv4_w, conv4_b, ln2_w, ln2_b,
                                      conv3_b, beta, W1eff, b1eff, W4eff, b4eff, b3eff);
  fold2_kernel<<<393, 256, 0, stream>>>(conv5_w, conv5_b, gamma, gate_w, pair_e, W5eff, b5tot);
  ln1_kernel<<<BB * 64, 256, 0, stream>>>(feat, xhatT, featT);

  for (int s0 = 0; s0 < BB; s0 += ns) {
    int np = ns * KT, plo = s0 * KT;
    conv1_kernel<<<dim3(32, 2, np), 256, 0, stream>>>(W1eff, b1eff, xhatT, pair_e, plo, t_T);
    dwsg_kernel<<<dim3(4, 16, np), 256, 0, stream>>>(t_T, conv2_w, conv2_b, pair_e, plo,
                                                     y_T, mean_raw);
    sca_kernel<<<np, CC, 0, stream>>>(mean_raw, sca_w, sca_b, pair_e, plo, s_buf);
    w3fold_kernel<<<np * 8, 256, 0, stream>>>(conv3_w, beta, s_buf, pair_e, plo, W3eff);
    conv3_ln2_kernel<<<dim3(32, 1, np), 256, 0, stream>>>(W3eff, b3eff, y_T, featT,
                                                          pair_e, plo, x1_T, xh2_T);
    conv4sg_kernel<<<dim3(32, 1, np), 256, 0, stream>>>(W4eff, b4eff, xh2_T, pair_e, plo, g5_T);
    conv5_kernel<<<dim3(32, 1, ns), 256, 0, stream>>>(W5eff, b5tot, g5_T, x1_T,
                                                      gate_w, plo, out);
  }
}

// Round 5
// 262.119 us; speedup vs baseline: 3.0277x; 1.1051x over previous
//
#include <hip/hip_runtime.h>

#define EN 5
#define KT 3
#define BB 16
#define CC 128
#define HWP 4096
#define DWC 256
#define NPAIR 48
#define EPSLN 1e-6f

typedef float f32x4 __attribute__((ext_vector_type(4)));
typedef __bf16 bf16x8 __attribute__((ext_vector_type(8)));

__device__ __forceinline__ float bf2f(ushort u) {
  union { unsigned int u; float f; } v; v.u = ((unsigned int)u) << 16; return v.f;
}
__device__ __forceinline__ ushort f2bf(float f) {
  union { float f; unsigned int u; } v; v.f = f;
  unsigned int r = v.u + 0x7FFFu + ((v.u >> 16) & 1u);
  return (ushort)(r >> 16);
}
__device__ __forceinline__ ushort4 pack4(float a, float b, float c, float d) {
  ushort4 r; r.x = f2bf(a); r.y = f2bf(b); r.z = f2bf(c); r.w = f2bf(d); return r;
}

// ---------------- gate ----------------
__global__ void gate_kernel(const float* __restrict__ weights, float* __restrict__ gate_w,
                            int* __restrict__ pair_e, float* __restrict__ out_counts,
                            float* __restrict__ out_weights, float* __restrict__ mean_raw) {
  __shared__ int sel[NPAIR];
  int tid = threadIdx.x;
  if (tid < BB) {
    float w[EN];
    for (int e = 0; e < EN; e++) w[e] = weights[tid * EN + e];
    int ch[KT]; float cv[KT]; float sum = 0.f;
    for (int j = 0; j < KT; j++) {
      int best = -1; float bv = -3.4e38f;
      for (int e = 0; e < EN; e++) {
        bool used = false;
        for (int q = 0; q < j; q++) if (ch[q] == e) used = true;
        if (!used && w[e] > bv) { bv = w[e]; best = e; }
      }
      ch[j] = best; cv[j] = bv; sum += bv;
    }
    float inv = 1.f / sum;
    for (int j = 0; j < KT; j++) {
      gate_w[tid * KT + j] = cv[j] * inv;
      pair_e[tid * KT + j] = ch[j];
      sel[tid * KT + j] = ch[j];
    }
  }
  for (int i = tid; i < NPAIR * CC; i += 256) mean_raw[i] = 0.f;
  __syncthreads();
  if (tid < EN) {
    int cnt = 0;
    for (int i = 0; i < NPAIR; i++) if (sel[i] == tid) cnt++;
    out_counts[tid] = (float)cnt;
  }
  if (tid < BB * EN) out_weights[tid] = weights[tid];
}

// ---------------- fold LN into conv1/conv4 ----------------
__global__ void fold_kernel(const float* __restrict__ conv1_w, const float* __restrict__ conv1_b,
                            const float* __restrict__ ln1_w, const float* __restrict__ ln1_b,
                            const float* __restrict__ conv4_w, const float* __restrict__ conv4_b,
                            const float* __restrict__ ln2_w, const float* __restrict__ ln2_b,
                            const float* __restrict__ conv3_b, const float* __restrict__ beta,
                            ushort* __restrict__ W1eff, float* __restrict__ b1eff,
                            ushort* __restrict__ W4eff, float* __restrict__ b4eff,
                            float* __restrict__ b3eff) {
  int gid = blockIdx.x * 256 + threadIdx.x;
  if (gid < 2 * EN * DWC) {
    int which = gid / (EN * DWC), rem = gid % (EN * DWC);
    int e = rem / DWC, o = rem % DWC;
    const float* src = (which ? conv4_w : conv1_w) + (size_t)(e * DWC + o) * CC;
    const float* lw = (which ? ln2_w : ln1_w) + e * CC;
    const float* lb = (which ? ln2_b : ln1_b) + e * CC;
    float bacc = (which ? conv4_b : conv1_b)[e * DWC + o];
    ushort* dst = (which ? W4eff : W1eff) + (size_t)(e * DWC + o) * CC;
    for (int c = 0; c < CC; c++) {
      float wv = src[c];
      dst[c] = f2bf(wv * lw[c]);
      bacc += wv * lb[c];
    }
    (which ? b4eff : b1eff)[e * DWC + o] = bacc;
  } else if (gid < 2 * EN * DWC + EN * CC) {
    int x = gid - 2 * EN * DWC;
    b3eff[x] = beta[x] * conv3_b[x];
  }
}

// ---------------- fold2: W5eff[p]=conv5_w[e]*gamma*gate; b5tot ----------------
__global__ void fold2_kernel(const float* __restrict__ conv5_w, const float* __restrict__ conv5_b,
                             const float* __restrict__ gamma, const float* __restrict__ gate_w,
                             const int* __restrict__ pair_e,
                             ushort* __restrict__ W5eff, float* __restrict__ b5tot) {
  int gid = blockIdx.x * 256 + threadIdx.x;
  const int nW = NPAIR * CC * CC / 8;
  if (gid < nW) {
    int base = gid * 8;
    int p = base >> 14, rem = base & 16383;
    int o = rem >> 7, k0 = rem & 127;
    int e = pair_e[p];
    float sc = gamma[e * CC + o] * gate_w[p];
    const float* src = conv5_w + ((size_t)e * CC + o) * CC + k0;
    ushort* dst = W5eff + ((size_t)p * CC + o) * CC + k0;
    for (int q = 0; q < 8; q++) dst[q] = f2bf(src[q] * sc);
  } else if (gid < nW + BB * CC) {
    int x = gid - nW;
    int b = x >> 7, o = x & 127;
    float s = 0.f;
    for (int j = 0; j < KT; j++) {
      int p = b * KT + j, e = pair_e[p];
      s += gate_w[p] * gamma[e * CC + o] * conv5_b[e * CC + o];
    }
    b5tot[x] = s;
  }
}

// ---------------- LN1 + transpose ----------------
__global__ __launch_bounds__(256) void ln1_kernel(const float* __restrict__ feat,
                                                  ushort* __restrict__ xhatT,
                                                  ushort* __restrict__ featT) {
  __shared__ float tile[CC * 64];
  __shared__ float pS[4][64], pS2[4][64], bcM[64], bcR[64];
  int bimg = blockIdx.x >> 6;
  int n0 = (blockIdx.x & 63) * 64;
  int tid = threadIdx.x;
  const float* src = feat + (size_t)bimg * CC * HWP + n0;
#pragma unroll
  for (int i = 0; i < 8; i++) {
    int ch = tid + i * 256;
    int row = ch >> 4, c16 = ch & 15;
    *(float4*)&tile[row * 64 + c16 * 4] = *(const float4*)(src + (size_t)row * HWP + c16 * 4);
  }
  __syncthreads();
  int lane = tid & 63, w = tid >> 6;
  float s = 0.f, s2 = 0.f;
#pragma unroll
  for (int i = 0; i < 32; i++) {
    float v = tile[(w * 32 + i) * 64 + lane];
    s += v; s2 += v * v;
  }
  pS[w][lane] = s; pS2[w][lane] = s2;
  __syncthreads();
  if (w == 0) {
    float t1 = pS[0][lane] + pS[1][lane] + pS[2][lane] + pS[3][lane];
    float t2 = pS2[0][lane] + pS2[1][lane] + pS2[2][lane] + pS2[3][lane];
    float mu = t1 * (1.f / CC);
    float var = t2 * (1.f / CC) - mu * mu;
    bcM[lane] = mu; bcR[lane] = rsqrtf(var + EPSLN);
  }
  __syncthreads();
  float mu = bcM[lane], r = bcR[lane];
  size_t obase = ((size_t)bimg * HWP + n0 + lane) * CC + w * 32;
#pragma unroll
  for (int i = 0; i < 4; i++) {
    float v[8];
#pragma unroll
    for (int q = 0; q < 8; q++) v[q] = tile[(w * 32 + i * 8 + q) * 64 + lane];
    *(ushort4*)(featT + obase + i * 8)     = pack4(v[0], v[1], v[2], v[3]);
    *(ushort4*)(featT + obase + i * 8 + 4) = pack4(v[4], v[5], v[6], v[7]);
    *(ushort4*)(xhatT + obase + i * 8)     = pack4((v[0]-mu)*r, (v[1]-mu)*r, (v[2]-mu)*r, (v[3]-mu)*r);
    *(ushort4*)(xhatT + obase + i * 8 + 4) = pack4((v[4]-mu)*r, (v[5]-mu)*r, (v[6]-mu)*r, (v[7]-mu)*r);
  }
}

// ---------------- shared helpers ----------------
__device__ __forceinline__ void stage_tile(const ushort* __restrict__ g, ushort* lds, int tid) {
#pragma unroll
  for (int i = 0; i < 8; i++) {
    int d = (tid + i * 256) * 16;
    int row = d >> 8;
    uint4 v = *(const uint4*)((const char*)g + d);
    *(uint4*)((char*)lds + (d ^ ((row & 7) << 4))) = v;
  }
}
__device__ __forceinline__ bf16x8 ldfrag(const ushort* lds, int row, int kb) {
  return *(const bf16x8*)((const char*)lds + row * 256 + (kb ^ ((row & 7) << 4)));
}
__device__ __forceinline__ void stage8(ushort* st, int px, int o, ushort4 v) {
  *(ushort4*)((char*)st + px * 256 + ((o * 2) ^ ((px & 7) << 4))) = v;
}
__device__ __forceinline__ uint4 ldstage16(const ushort* st, int px, int ck) {
  return *(const uint4*)((const char*)st + px * 256 + ((ck * 16) ^ ((px & 7) << 4)));
}

// ---------------- conv1: full M=256 per block (A staged once, W in 2 stages) ----------------
__global__ __launch_bounds__(256, 2) void conv1_kernel(
    const ushort* __restrict__ W1eff, const float* __restrict__ b1eff,
    const ushort* __restrict__ xhatT, const int* __restrict__ pair_e,
    int pair_lo, ushort* __restrict__ tT) {
  __shared__ ushort Ws[CC * CC];
  __shared__ ushort As[CC * CC];
  int pc = blockIdx.z, p = pair_lo + pc, e = pair_e[p];
  int img = p / KT;
  int n0 = blockIdx.x * 128;
  int tid = threadIdx.x, lane = tid & 63, w = tid >> 6;
  int wr = w >> 1, wc = w & 1, fr = lane & 15, kb0 = (lane >> 4) * 16, og = (lane >> 4) * 4;
  stage_tile(W1eff + (size_t)e * DWC * CC, Ws, tid);
  stage_tile(xhatT + ((size_t)img * HWP + n0) * CC, As, tid);
  __syncthreads();
  f32x4 accA[4][4] = {}, accG[4][4] = {};
#pragma unroll
  for (int ks = 0; ks < 4; ks++) {
    bf16x8 a[4], b[4];
#pragma unroll
    for (int m = 0; m < 4; m++) a[m] = ldfrag(Ws, wr * 64 + m * 16 + fr, ks * 64 + kb0);
#pragma unroll
    for (int n = 0; n < 4; n++) b[n] = ldfrag(As, wc * 64 + n * 16 + fr, ks * 64 + kb0);
#pragma unroll
    for (int m = 0; m < 4; m++)
#pragma unroll
      for (int n = 0; n < 4; n++)
        accA[m][n] = __builtin_amdgcn_mfma_f32_16x16x32_bf16(a[m], b[n], accA[m][n], 0, 0, 0);
  }
  __syncthreads();
  stage_tile(W1eff + ((size_t)e * DWC + CC) * CC, Ws, tid);
  __syncthreads();
#pragma unroll
  for (int ks = 0; ks < 4; ks++) {
    bf16x8 a[4], b[4];
#pragma unroll
    for (int m = 0; m < 4; m++) a[m] = ldfrag(Ws, wr * 64 + m * 16 + fr, ks * 64 + kb0);
#pragma unroll
    for (int n = 0; n < 4; n++) b[n] = ldfrag(As, wc * 64 + n * 16 + fr, ks * 64 + kb0);
#pragma unroll
    for (int m = 0; m < 4; m++)
#pragma unroll
      for (int n = 0; n < 4; n++)
        accG[m][n] = __builtin_amdgcn_mfma_f32_16x16x32_bf16(a[m], b[n], accG[m][n], 0, 0, 0);
  }
  __syncthreads();
#pragma unroll
  for (int m = 0; m < 4; m++) {
    int o = wr * 64 + m * 16 + og;
    float4 ba = *(const float4*)&b1eff[e * DWC + o];
    float4 bg = *(const float4*)&b1eff[e * DWC + CC + o];
#pragma unroll
    for (int n = 0; n < 4; n++) {
      int px = wc * 64 + n * 16 + fr;
      f32x4 va = accA[m][n], vg = accG[m][n];
      stage8(As, px, o, pack4(va.x + ba.x, va.y + ba.y, va.z + ba.z, va.w + ba.w));
      stage8(Ws, px, o, pack4(vg.x + bg.x, vg.y + bg.y, vg.z + bg.z, vg.w + bg.w));
    }
  }
  __syncthreads();
#pragma unroll
  for (int h = 0; h < 2; h++) {
    const ushort* buf = h ? Ws : As;
#pragma unroll
    for (int i = 0; i < 8; i++) {
      int idx = tid + i * 256;
      int px = idx >> 4, ck = idx & 15;
      uint4 v = ldstage16(buf, px, ck);
      *(uint4*)((char*)(tT + ((size_t)pc * HWP + n0 + px) * DWC + h * CC) + ck * 16) = v;
    }
  }
}

// ---------------- depthwise 3x3 + SG + mean; halo LDS reused as ystage ----------------
#define HALO 18
__global__ __launch_bounds__(256, 3) void dwsg_kernel(
    const ushort* __restrict__ tT, const float* __restrict__ conv2_w,
    const float* __restrict__ conv2_b, const int* __restrict__ pair_e, int pair_lo,
    ushort* __restrict__ yT, float* __restrict__ mean_raw) {
  __shared__ ushort halo[HALO * HALO * 64];   // 41.5 KB; reused as ystage after taps
  __shared__ float psum[8][32];
  int cg4 = blockIdx.x;
  int ts = blockIdx.y;
  int pc = blockIdx.z, p = pair_lo + pc, e = pair_e[p];
  int c0 = cg4 * 32;
  int th = (ts >> 2) * 16, tw = (ts & 3) * 16;
  int tid = threadIdx.x;
  for (int it = 0; it < 11; it++) {
    int idx = tid + it * 256;
    if (idx < HALO * HALO * 8) {
      int px = idx >> 3, sl = idx & 7;
      int hh = px / HALO - 1 + th, ww = px % HALO - 1 + tw;
      ushort4 a = {0, 0, 0, 0}, g = {0, 0, 0, 0};
      if (hh >= 0 && hh < 64 && ww >= 0 && ww < 64) {
        const ushort* src = tT + ((size_t)pc * HWP + hh * 64 + ww) * DWC + c0 + sl * 4;
        a = *(const ushort4*)src;
        g = *(const ushort4*)(src + CC);
      }
      char* dst = (char*)halo + px * 128 + ((sl * 16) ^ ((px & 7) << 4));
      *(ushort4*)dst = a;
      *(ushort4*)(dst + 8) = g;
    }
  }
  __syncthreads();
  int ww_ = tid & 15, hh_ = tid >> 4;
  int ps = hh_ * 16 + ww_;
  const float* wA = conv2_w + ((size_t)e * DWC + c0) * 9;
  const float* wG = conv2_w + ((size_t)e * DWC + CC + c0) * 9;
  const float* bA = conv2_b + e * DWC + c0;
  const float* bG = conv2_b + e * DWC + CC + c0;
  float ys[8][4];
#pragma unroll
  for (int cg = 0; cg < 8; cg++) {
    int ci = cg * 4;
    float accA[4] = {}, accG[4] = {};
#pragma unroll
    for (int dh = 0; dh < 3; dh++) {
#pragma unroll
      for (int dw = 0; dw < 3; dw++) {
        int px = (hh_ + dh) * HALO + ww_ + dw;
        const char* hp = (const char*)halo + px * 128 + ((cg * 16) ^ ((px & 7) << 4));
        ushort4 va = *(const ushort4*)hp;
        ushort4 vg = *(const ushort4*)(hp + 8);
        int wo = dh * 3 + dw;
        accA[0] = fmaf(bf2f(va.x), wA[(ci + 0) * 9 + wo], accA[0]);
        accA[1] = fmaf(bf2f(va.y), wA[(ci + 1) * 9 + wo], accA[1]);
        accA[2] = fmaf(bf2f(va.z), wA[(ci + 2) * 9 + wo], accA[2]);
        accA[3] = fmaf(bf2f(va.w), wA[(ci + 3) * 9 + wo], accA[3]);
        accG[0] = fmaf(bf2f(vg.x), wG[(ci + 0) * 9 + wo], accG[0]);
        accG[1] = fmaf(bf2f(vg.y), wG[(ci + 1) * 9 + wo], accG[1]);
        accG[2] = fmaf(bf2f(vg.z), wG[(ci + 2) * 9 + wo], accG[2]);
        accG[3] = fmaf(bf2f(vg.w), wG[(ci + 3) * 9 + wo], accG[3]);
      }
    }
#pragma unroll
    for (int q = 0; q < 4; q++)
      ys[cg][q] = (accA[q] + bA[ci + q]) * (accG[q] + bG[ci + q]);
  }
  __syncthreads();   // all halo reads done; reuse as ystage
  ushort* ystage = halo;
#pragma unroll
  for (int cg = 0; cg < 8; cg++)
    *(ushort4*)((char*)ystage + ps * 64 + ((cg * 8) ^ ((ps & 3) << 4))) =
        pack4(ys[cg][0], ys[cg][1], ys[cg][2], ys[cg][3]);
  __syncthreads();
  // coalesced y write-out
#pragma unroll
  for (int i = 0; i < 4; i++) {
    int idx = tid + i * 256;
    int px = idx >> 2, ck = idx & 3;
    uint4 v = *(const uint4*)((const char*)ystage + px * 64 + ((ck * 16) ^ ((px & 3) << 4)));
    int hh = px >> 4, wwv = px & 15;
    int n = (th + hh) * 64 + tw + wwv;
    *(uint4*)((char*)(yT + ((size_t)pc * HWP + n) * CC + c0) + ck * 16) = v;
  }
  // mean partials
  {
    int ch = tid & 31, grp = tid >> 5;
    int cg = ch >> 2, sub = ch & 3;
    float s = 0.f;
#pragma unroll
    for (int j = 0; j < 32; j++) {
      int px = grp * 32 + j;
      s += bf2f(*(const ushort*)((const char*)ystage + px * 64 + ((cg * 8) ^ ((px & 3) << 4)) + sub * 2));
    }
    psum[grp][ch] = s;
  }
  __syncthreads();
  if (tid < 32) {
    float s = 0.f;
#pragma unroll
    for (int g2 = 0; g2 < 8; g2++) s += psum[g2][tid];
    atomicAdd(&mean_raw[p * CC + c0 + tid], s);
  }
}

// ---------------- SCA + W3eff fold merged ----------------
__global__ void sca_w3fold_kernel(const float* __restrict__ mean_raw,
                                  const float* __restrict__ sca_w, const float* __restrict__ sca_b,
                                  const float* __restrict__ conv3_w, const float* __restrict__ beta,
                                  const int* __restrict__ pair_e, int pair_lo,
                                  ushort* __restrict__ W3eff) {
  __shared__ float m[CC];
  __shared__ float sv[CC];
  int pc = blockIdx.x, p = pair_lo + pc, e = pair_e[p];
  int tid = threadIdx.x;
  if (tid < CC) m[tid] = mean_raw[p * CC + tid] * (1.f / HWP);
  __syncthreads();
  if (tid < CC) {
    const float* wr = sca_w + (size_t)(e * CC + tid) * CC;
    float acc = sca_b[e * CC + tid];
#pragma unroll 8
    for (int c = 0; c < CC; c++) acc = fmaf(wr[c], m[c], acc);
    sv[tid] = acc;
  }
  __syncthreads();
#pragma unroll
  for (int i = 0; i < 8; i++) {
    int idx = tid + i * 256;
    int o = idx >> 4, k0 = (idx & 15) * 8;
    float bt = beta[e * CC + o];
    const float* src = conv3_w + ((size_t)e * CC + o) * CC + k0;
    ushort* dst = W3eff + ((size_t)pc * CC + o) * CC + k0;
#pragma unroll
    for (int q = 0; q < 8; q++) dst[q] = f2bf(src[q] * sv[k0 + q] * bt);
  }
}

// ---------------- conv3 + residual + fused LN2 ----------------
__global__ __launch_bounds__(256, 2) void conv3_ln2_kernel(
    const ushort* __restrict__ W3eff, const float* __restrict__ b3eff,
    const ushort* __restrict__ yT, const ushort* __restrict__ featT,
    const int* __restrict__ pair_e, int pair_lo,
    ushort* __restrict__ x1T, ushort* __restrict__ xh2T) {
  __shared__ ushort Ws[CC * CC];
  __shared__ ushort As[CC * CC];
  int pc = blockIdx.z, p = pair_lo + pc, e = pair_e[p];
  int img = p / KT;
  int n0 = blockIdx.x * 128;
  int tid = threadIdx.x, lane = tid & 63, w = tid >> 6;
  stage_tile(W3eff + (size_t)pc * CC * CC, Ws, tid);
  stage_tile(yT + ((size_t)pc * HWP + n0) * CC, As, tid);
  __syncthreads();
  int wr = w >> 1, wc = w & 1, fr = lane & 15, kb0 = (lane >> 4) * 16, og = (lane >> 4) * 4;
  f32x4 acc[4][4] = {};
#pragma unroll
  for (int ks = 0; ks < 4; ks++) {
    bf16x8 a[4], b[4];
#pragma unroll
    for (int m = 0; m < 4; m++) a[m] = ldfrag(Ws, wr * 64 + m * 16 + fr, ks * 64 + kb0);
#pragma unroll
    for (int n = 0; n < 4; n++) b[n] = ldfrag(As, wc * 64 + n * 16 + fr, ks * 64 + kb0);
#pragma unroll
    for (int m = 0; m < 4; m++)
#pragma unroll
      for (int n = 0; n < 4; n++)
        acc[m][n] = __builtin_amdgcn_mfma_f32_16x16x32_bf16(a[m], b[n], acc[m][n], 0, 0, 0);
  }
  float s[4] = {}, s2[4] = {};
#pragma unroll
  for (int m = 0; m < 4; m++) {
    int o = wr * 64 + m * 16 + og;
    float4 bv = *(const float4*)&b3eff[e * CC + o];
#pragma unroll
    for (int n = 0; n < 4; n++) {
      int px = wc * 64 + n * 16 + fr;
      ushort4 f4 = *(const ushort4*)(featT + ((size_t)img * HWP + n0 + px) * CC + o);
      f32x4 v = acc[m][n];
      v.x += bf2f(f4.x) + bv.x; v.y += bf2f(f4.y) + bv.y;
      v.z += bf2f(f4.z) + bv.z; v.w += bf2f(f4.w) + bv.w;
      acc[m][n] = v;
      s[n] += v.x + v.y + v.z + v.w;
      s2[n] += v.x * v.x + v.y * v.y + v.z * v.z + v.w * v.w;
    }
  }
#pragma unroll
  for (int n = 0; n < 4; n++) {
    s[n] += __shfl_xor(s[n], 16, 64); s[n] += __shfl_xor(s[n], 32, 64);
    s2[n] += __shfl_xor(s2[n], 16, 64); s2[n] += __shfl_xor(s2[n], 32, 64);
  }
  __syncthreads();
  float2* red = (float2*)As;
  if (lane < 16) {
#pragma unroll
    for (int n = 0; n < 4; n++) {
      float2 v; v.x = s[n]; v.y = s2[n];
      red[wr * 128 + wc * 64 + n * 16 + fr] = v;
    }
  }
  __syncthreads();
  float mu[4], rs[4];
#pragma unroll
  for (int n = 0; n < 4; n++) {
    int px = wc * 64 + n * 16 + fr;
    float2 r0 = red[px], r1 = red[128 + px];
    float m_ = (r0.x + r1.x) * (1.f / CC);
    float var = (r0.y + r1.y) * (1.f / CC) - m_ * m_;
    mu[n] = m_; rs[n] = rsqrtf(var + EPSLN);
  }
  __syncthreads();
#pragma unroll
  for (int m = 0; m < 4; m++) {
    int o = wr * 64 + m * 16 + og;
#pragma unroll
    for (int n = 0; n < 4; n++) {
      int px = wc * 64 + n * 16 + fr;
      f32x4 v = acc[m][n];
      stage8(As, px, o, pack4(v.x, v.y, v.z, v.w));
      stage8(Ws, px, o, pack4((v.x - mu[n]) * rs[n], (v.y - mu[n]) * rs[n],
                              (v.z - mu[n]) * rs[n], (v.w - mu[n]) * rs[n]));
    }
  }
  __syncthreads();
#pragma unroll
  for (int i = 0; i < 8; i++) {
    int idx = tid + i * 256;
    int px = idx >> 4, ck = idx & 15;
    size_t gb = ((size_t)pc * HWP + n0 + px) * CC;
    *(uint4*)((char*)(x1T + gb) + ck * 16)  = ldstage16(As, px, ck);
    *(uint4*)((char*)(xh2T + gb) + ck * 16) = ldstage16(Ws, px, ck);
  }
}

// ---------------- conv4 both halves + SimpleGate fused ----------------
__global__ __launch_bounds__(256, 2) void conv4sg_kernel(
    const ushort* __restrict__ W4eff, const float* __restrict__ b4eff,
    const ushort* __restrict__ xh2T, const int* __restrict__ pair_e,
    int pair_lo, ushort* __restrict__ g5T) {
  __shared__ ushort Ws[CC * CC];
  __shared__ ushort As[CC * CC];
  int pc = blockIdx.z, p = pair_lo + pc, e = pair_e[p];
  int n0 = blockIdx.x * 128;
  int tid = threadIdx.x, lane = tid & 63, w = tid >> 6;
  int wr = w >> 1, wc = w & 1, fr = lane & 15, kb0 = (lane >> 4) * 16, og = (lane >> 4) * 4;
  stage_tile(W4eff + (size_t)e * DWC * CC, Ws, tid);
  stage_tile(xh2T + ((size_t)pc * HWP + n0) * CC, As, tid);
  __syncthreads();
  f32x4 accA[4][4] = {}, accG[4][4] = {};
#pragma unroll
  for (int ks = 0; ks < 4; ks++) {
    bf16x8 a[4], b[4];
#pragma unroll
    for (int m = 0; m < 4; m++) a[m] = ldfrag(Ws, wr * 64 + m * 16 + fr, ks * 64 + kb0);
#pragma unroll
    for (int n = 0; n < 4; n++) b[n] = ldfrag(As, wc * 64 + n * 16 + fr, ks * 64 + kb0);
#pragma unroll
    for (int m = 0; m < 4; m++)
#pragma unroll
      for (int n = 0; n < 4; n++)
        accA[m][n] = __builtin_amdgcn_mfma_f32_16x16x32_bf16(a[m], b[n], accA[m][n], 0, 0, 0);
  }
  __syncthreads();
  stage_tile(W4eff + ((size_t)e * DWC + CC) * CC, Ws, tid);
  __syncthreads();
#pragma unroll
  for (int ks = 0; ks < 4; ks++) {
    bf16x8 a[4], b[4];
#pragma unroll
    for (int m = 0; m < 4; m++) a[m] = ldfrag(Ws, wr * 64 + m * 16 + fr, ks * 64 + kb0);
#pragma unroll
    for (int n = 0; n < 4; n++) b[n] = ldfrag(As, wc * 64 + n * 16 + fr, ks * 64 + kb0);
#pragma unroll
    for (int m = 0; m < 4; m++)
#pragma unroll
      for (int n = 0; n < 4; n++)
        accG[m][n] = __builtin_amdgcn_mfma_f32_16x16x32_bf16(a[m], b[n], accG[m][n], 0, 0, 0);
  }
  __syncthreads();
#pragma unroll
  for (int m = 0; m < 4; m++) {
    int o = wr * 64 + m * 16 + og;
    float4 ba = *(const float4*)&b4eff[e * DWC + o];
    float4 bg = *(const float4*)&b4eff[e * DWC + CC + o];
#pragma unroll
    for (int n = 0; n < 4; n++) {
      int px = wc * 64 + n * 16 + fr;
      f32x4 va = accA[m][n], vg = accG[m][n];
      stage8(Ws, px, o, pack4((va.x + ba.x) * (vg.x + bg.x), (va.y + ba.y) * (vg.y + bg.y),
                              (va.z + ba.z) * (vg.z + bg.z), (va.w + ba.w) * (vg.w + bg.w)));
    }
  }
  __syncthreads();
#pragma unroll
  for (int i = 0; i < 8; i++) {
    int idx = tid + i * 256;
    int px = idx >> 4, ck = idx & 15;
    uint4 v = ldstage16(Ws, px, ck);
    *(uint4*)((char*)(g5T + ((size_t)pc * HWP + n0 + px) * CC) + ck * 16) = v;
  }
}

// ---------------- conv5: 3-pair accumulated MFMA + transpose epilogue ----------------
__global__ __launch_bounds__(256, 2) void conv5_kernel(
    const ushort* __restrict__ W5eff, const float* __restrict__ b5tot,
    const ushort* __restrict__ g5T, const ushort* __restrict__ x1,
    const float* __restrict__ gate_w, int pair_lo, float* __restrict__ out) {
  __shared__ ushort Ws[CC * CC];
  __shared__ ushort As[CC * CC];
  int sl = blockIdx.z;
  int n0 = blockIdx.x * 128;
  int b = pair_lo / KT + sl;
  int tid = threadIdx.x, lane = tid & 63, w = tid >> 6;
  int wr = w >> 1, wc = w & 1;
  int fr = lane & 15, kb0 = (lane >> 4) * 16, og = (lane >> 4) * 4;
  f32x4 acc[4][4] = {};
  for (int j = 0; j < KT; j++) {
    int pc = sl * KT + j, p = pair_lo + pc;
    __syncthreads();
    stage_tile(W5eff + (size_t)p * CC * CC, Ws, tid);
    stage_tile(g5T + ((size_t)pc * HWP + n0) * CC, As, tid);
    __syncthreads();
#pragma unroll
    for (int ks = 0; ks < 4; ks++) {
      bf16x8 a[4], bfr[4];
#pragma unroll
      for (int m = 0; m < 4; m++) a[m] = ldfrag(Ws, wr * 64 + m * 16 + fr, ks * 64 + kb0);
#pragma unroll
      for (int n = 0; n < 4; n++) bfr[n] = ldfrag(As, wc * 64 + n * 16 + fr, ks * 64 + kb0);
#pragma unroll
      for (int m = 0; m < 4; m++)
#pragma unroll
        for (int n = 0; n < 4; n++)
          acc[m][n] = __builtin_amdgcn_mfma_f32_16x16x32_bf16(a[m], bfr[n], acc[m][n], 0, 0, 0);
    }
  }
  float gw0 = gate_w[pair_lo + sl * KT + 0];
  float gw1 = gate_w[pair_lo + sl * KT + 1];
  float gw2 = gate_w[pair_lo + sl * KT + 2];
  __syncthreads();
  ushort* Ct = As;
#pragma unroll
  for (int m = 0; m < 4; m++) {
    int o = wr * 64 + m * 16 + og;
    float4 bt = *(const float4*)&b5tot[b * CC + o];
#pragma unroll
    for (int n = 0; n < 4; n++) {
      int px = wc * 64 + n * 16 + fr;
      f32x4 v = acc[m][n];
      float r0 = v.x + bt.x, r1 = v.y + bt.y, r2 = v.z + bt.z, r3 = v.w + bt.w;
      size_t xoff = ((size_t)(sl * KT) * HWP + n0 + px) * CC + o;
      ushort4 xa = *(const ushort4*)(x1 + xoff);
      ushort4 xb = *(const ushort4*)(x1 + xoff + (size_t)HWP * CC);
      ushort4 xc = *(const ushort4*)(x1 + xoff + 2 * (size_t)HWP * CC);
      r0 += gw0 * bf2f(xa.x) + gw1 * bf2f(xb.x) + gw2 * bf2f(xc.x);
      r1 += gw0 * bf2f(xa.y) + gw1 * bf2f(xb.y) + gw2 * bf2f(xc.y);
      r2 += gw0 * bf2f(xa.z) + gw1 * bf2f(xb.z) + gw2 * bf2f(xc.z);
      r3 += gw0 * bf2f(xa.w) + gw1 * bf2f(xb.w) + gw2 * bf2f(xc.w);
      *(ushort*)((char*)Ct + (o+0) * 256 + ((px*2) ^ (((o+0) & 7) << 4))) = f2bf(r0);
      *(ushort*)((char*)Ct + (o+1) * 256 + ((px*2) ^ (((o+1) & 7) << 4))) = f2bf(r1);
      *(ushort*)((char*)Ct + (o+2) * 256 + ((px*2) ^ (((o+2) & 7) << 4))) = f2bf(r2);
      *(ushort*)((char*)Ct + (o+3) * 256 + ((px*2) ^ (((o+3) & 7) << 4))) = f2bf(r3);
    }
  }
  __syncthreads();
  int o = tid >> 1, ph = (tid & 1) * 64;
  float* orow = out + ((size_t)(b * CC + o)) * HWP + n0 + ph;
  int swz = (o & 7) << 4;
#pragma unroll
  for (int i = 0; i < 8; i++) {
    const ushort* lp = (const ushort*)((const char*)Ct + o * 256 + ((ph * 2 + i * 16) ^ swz));
    float4 f0, f1;
    f0.x = bf2f(lp[0]); f0.y = bf2f(lp[1]); f0.z = bf2f(lp[2]); f0.w = bf2f(lp[3]);
    f1.x = bf2f(lp[4]); f1.y = bf2f(lp[5]); f1.z = bf2f(lp[6]); f1.w = bf2f(lp[7]);
    *(float4*)(orow + i * 8) = f0;
    *(float4*)(orow + i * 8 + 4) = f1;
  }
}

extern "C" void kernel_launch(void* const* d_in, const int* in_sizes, int n_in,
                              void* d_out, int out_size, void* d_ws, size_t ws_size,
                              hipStream_t stream) {
  const float* feat    = (const float*)d_in[0];
  const float* weights = (const float*)d_in[1];
  const float* ln1_w   = (const float*)d_in[2];
  const float* ln1_b   = (const float*)d_in[3];
  const float* conv1_w = (const float*)d_in[4];
  const float* conv1_b = (const float*)d_in[5];
  const float* conv2_w = (const float*)d_in[6];
  const float* conv2_b = (const float*)d_in[7];
  const float* sca_w   = (const float*)d_in[8];
  const float* sca_b   = (const float*)d_in[9];
  const float* conv3_w = (const float*)d_in[10];
  const float* conv3_b = (const float*)d_in[11];
  const float* ln2_w   = (const float*)d_in[12];
  const float* ln2_b   = (const float*)d_in[13];
  const float* conv4_w = (const float*)d_in[14];
  const float* conv4_b = (const float*)d_in[15];
  const float* conv5_w = (const float*)d_in[16];
  const float* conv5_b = (const float*)d_in[17];
  const float* beta    = (const float*)d_in[18];
  const float* gamma   = (const float*)d_in[19];

  float* out = (float*)d_out;
  float* out_counts = out + (size_t)BB * CC * HWP;
  float* out_weights = out_counts + EN;

  char* base = (char*)d_ws;
  size_t off = 0;
  auto carveU = [&](size_t n) -> ushort* { ushort* p = (ushort*)(base + off); off += n * 2; return p; };
  auto carveF = [&](size_t n) -> float* { float* p = (float*)(base + off); off += n * 4; return p; };

  ushort* W1eff = carveU((size_t)EN * DWC * CC);
  ushort* W4eff = carveU((size_t)EN * DWC * CC);
  ushort* W5eff = carveU((size_t)NPAIR * CC * CC);
  ushort* W3eff = carveU((size_t)NPAIR * CC * CC);
  float* b1eff  = carveF(EN * DWC);
  float* b4eff  = carveF(EN * DWC);
  float* b3eff  = carveF(EN * CC);
  float* b5tot  = carveF(BB * CC);
  float* gate_w = carveF(64);
  int*   pair_e = (int*)carveF(64);
  float* mean_raw = carveF(NPAIR * CC);
  float* s_buf  = carveF(NPAIR * CC);
  ushort* xhatT = carveU((size_t)BB * HWP * CC);
  ushort* featT = carveU((size_t)BB * HWP * CC);
  (void)s_buf;

  // per-pair: t (2MB, reused as g5) + y (1MB, reused as xh2) + x1 (1MB)
  const size_t per_pair = ((size_t)HWP * DWC + 2 * (size_t)HWP * CC) * 2;
  int ns = 16;
  while (ns > 1 && off + (size_t)ns * KT * per_pair > ws_size) ns >>= 1;
  size_t pr = (size_t)ns * KT;
  ushort* t_T   = carveU(pr * HWP * DWC);
  ushort* y_T   = carveU(pr * HWP * CC);
  ushort* x1_T  = carveU(pr * HWP * CC);
  ushort* xh2_T = y_T;   // alias: conv3_ln2 reads its own y tile to LDS before writing xh2
  ushort* g5_T  = t_T;   // alias: t dead after dwsg, reused for conv4 output

  gate_kernel<<<1, 256, 0, stream>>>(weights, gate_w, pair_e, out_counts, out_weights, mean_raw);
  fold_kernel<<<13, 256, 0, stream>>>(conv1_w, conv1_b, ln1_w, ln1_b,
                                      conv4_w, conv4_b, ln2_w, ln2_b,
                                      conv3_b, beta, W1eff, b1eff, W4eff, b4eff, b3eff);
  fold2_kernel<<<393, 256, 0, stream>>>(conv5_w, conv5_b, gamma, gate_w, pair_e, W5eff, b5tot);
  ln1_kernel<<<BB * 64, 256, 0, stream>>>(feat, xhatT, featT);

  for (int s0 = 0; s0 < BB; s0 += ns) {
    int np = ns * KT, plo = s0 * KT;
    conv1_kernel<<<dim3(32, 1, np), 256, 0, stream>>>(W1eff, b1eff, xhatT, pair_e, plo, t_T);
    dwsg_kernel<<<dim3(4, 16, np), 256, 0, stream>>>(t_T, conv2_w, conv2_b, pair_e, plo,
                                                     y_T, mean_raw);
    sca_w3fold_kernel<<<np, 256, 0, stream>>>(mean_raw, sca_w, sca_b, conv3_w, beta,
                                              pair_e, plo, W3eff);
    conv3_ln2_kernel<<<dim3(32, 1, np), 256, 0, stream>>>(W3eff, b3eff, y_T, featT,
                                                          pair_e, plo, x1_T, xh2_T);
    conv4sg_kernel<<<dim3(32, 1, np), 256, 0, stream>>>(W4eff, b4eff, xh2_T, pair_e, plo, g5_T);
    conv5_kernel<<<dim3(32, 1, ns), 256, 0, stream>>>(W5eff, b5tot, g5_T, x1_T,
                                                      gate_w, plo, out);
  }
}

// Round 6
// 256.013 us; speedup vs baseline: 3.0999x; 1.0239x over previous
//
#include <hip/hip_runtime.h>

#define EN 5
#define KT 3
#define BB 16
#define CC 128
#define HWP 4096
#define DWC 256
#define NPAIR 48
#define EPSLN 1e-6f
#define HR 10      // 8x8 tile + 1px halo each side
#define HPX 100    // 10*10 halo pixels

typedef float f32x4 __attribute__((ext_vector_type(4)));
typedef __bf16 bf16x8 __attribute__((ext_vector_type(8)));

__device__ __forceinline__ float bf2f(ushort u) {
  union { unsigned int u; float f; } v; v.u = ((unsigned int)u) << 16; return v.f;
}
__device__ __forceinline__ ushort f2bf(float f) {
  union { float f; unsigned int u; } v; v.f = f;
  unsigned int r = v.u + 0x7FFFu + ((v.u >> 16) & 1u);
  return (ushort)(r >> 16);
}
__device__ __forceinline__ ushort4 pack4(float a, float b, float c, float d) {
  ushort4 r; r.x = f2bf(a); r.y = f2bf(b); r.z = f2bf(c); r.w = f2bf(d); return r;
}

// ---------------- gate ----------------
__global__ void gate_kernel(const float* __restrict__ weights, float* __restrict__ gate_w,
                            int* __restrict__ pair_e, float* __restrict__ out_counts,
                            float* __restrict__ out_weights, float* __restrict__ mean_raw) {
  __shared__ int sel[NPAIR];
  int tid = threadIdx.x;
  if (tid < BB) {
    float w[EN];
    for (int e = 0; e < EN; e++) w[e] = weights[tid * EN + e];
    int ch[KT]; float cv[KT]; float sum = 0.f;
    for (int j = 0; j < KT; j++) {
      int best = -1; float bv = -3.4e38f;
      for (int e = 0; e < EN; e++) {
        bool used = false;
        for (int q = 0; q < j; q++) if (ch[q] == e) used = true;
        if (!used && w[e] > bv) { bv = w[e]; best = e; }
      }
      ch[j] = best; cv[j] = bv; sum += bv;
    }
    float inv = 1.f / sum;
    for (int j = 0; j < KT; j++) {
      gate_w[tid * KT + j] = cv[j] * inv;
      pair_e[tid * KT + j] = ch[j];
      sel[tid * KT + j] = ch[j];
    }
  }
  for (int i = tid; i < NPAIR * CC; i += 256) mean_raw[i] = 0.f;
  __syncthreads();
  if (tid < EN) {
    int cnt = 0;
    for (int i = 0; i < NPAIR; i++) if (sel[i] == tid) cnt++;
    out_counts[tid] = (float)cnt;
  }
  if (tid < BB * EN) out_weights[tid] = weights[tid];
}

// ---------------- fold LN into conv1/conv4 ----------------
__global__ void fold_kernel(const float* __restrict__ conv1_w, const float* __restrict__ conv1_b,
                            const float* __restrict__ ln1_w, const float* __restrict__ ln1_b,
                            const float* __restrict__ conv4_w, const float* __restrict__ conv4_b,
                            const float* __restrict__ ln2_w, const float* __restrict__ ln2_b,
                            const float* __restrict__ conv3_b, const float* __restrict__ beta,
                            ushort* __restrict__ W1eff, float* __restrict__ b1eff,
                            ushort* __restrict__ W4eff, float* __restrict__ b4eff,
                            float* __restrict__ b3eff) {
  int gid = blockIdx.x * 256 + threadIdx.x;
  if (gid < 2 * EN * DWC) {
    int which = gid / (EN * DWC), rem = gid % (EN * DWC);
    int e = rem / DWC, o = rem % DWC;
    const float* src = (which ? conv4_w : conv1_w) + (size_t)(e * DWC + o) * CC;
    const float* lw = (which ? ln2_w : ln1_w) + e * CC;
    const float* lb = (which ? ln2_b : ln1_b) + e * CC;
    float bacc = (which ? conv4_b : conv1_b)[e * DWC + o];
    ushort* dst = (which ? W4eff : W1eff) + (size_t)(e * DWC + o) * CC;
    for (int c = 0; c < CC; c++) {
      float wv = src[c];
      dst[c] = f2bf(wv * lw[c]);
      bacc += wv * lb[c];
    }
    (which ? b4eff : b1eff)[e * DWC + o] = bacc;
  } else if (gid < 2 * EN * DWC + EN * CC) {
    int x = gid - 2 * EN * DWC;
    b3eff[x] = beta[x] * conv3_b[x];
  }
}

// ---------------- fold2: W5eff[p]=conv5_w[e]*gamma*gate; b5tot ----------------
__global__ void fold2_kernel(const float* __restrict__ conv5_w, const float* __restrict__ conv5_b,
                             const float* __restrict__ gamma, const float* __restrict__ gate_w,
                             const int* __restrict__ pair_e,
                             ushort* __restrict__ W5eff, float* __restrict__ b5tot) {
  int gid = blockIdx.x * 256 + threadIdx.x;
  const int nW = NPAIR * CC * CC / 8;
  if (gid < nW) {
    int base = gid * 8;
    int p = base >> 14, rem = base & 16383;
    int o = rem >> 7, k0 = rem & 127;
    int e = pair_e[p];
    float sc = gamma[e * CC + o] * gate_w[p];
    const float* src = conv5_w + ((size_t)e * CC + o) * CC + k0;
    ushort* dst = W5eff + ((size_t)p * CC + o) * CC + k0;
    for (int q = 0; q < 8; q++) dst[q] = f2bf(src[q] * sc);
  } else if (gid < nW + BB * CC) {
    int x = gid - nW;
    int b = x >> 7, o = x & 127;
    float s = 0.f;
    for (int j = 0; j < KT; j++) {
      int p = b * KT + j, e = pair_e[p];
      s += gate_w[p] * gamma[e * CC + o] * conv5_b[e * CC + o];
    }
    b5tot[x] = s;
  }
}

// ---------------- LN1 + transpose ----------------
__global__ __launch_bounds__(256) void ln1_kernel(const float* __restrict__ feat,
                                                  ushort* __restrict__ xhatT,
                                                  ushort* __restrict__ featT) {
  __shared__ float tile[CC * 64];
  __shared__ float pS[4][64], pS2[4][64], bcM[64], bcR[64];
  int bimg = blockIdx.x >> 6;
  int n0 = (blockIdx.x & 63) * 64;
  int tid = threadIdx.x;
  const float* src = feat + (size_t)bimg * CC * HWP + n0;
#pragma unroll
  for (int i = 0; i < 8; i++) {
    int ch = tid + i * 256;
    int row = ch >> 4, c16 = ch & 15;
    *(float4*)&tile[row * 64 + c16 * 4] = *(const float4*)(src + (size_t)row * HWP + c16 * 4);
  }
  __syncthreads();
  int lane = tid & 63, w = tid >> 6;
  float s = 0.f, s2 = 0.f;
#pragma unroll
  for (int i = 0; i < 32; i++) {
    float v = tile[(w * 32 + i) * 64 + lane];
    s += v; s2 += v * v;
  }
  pS[w][lane] = s; pS2[w][lane] = s2;
  __syncthreads();
  if (w == 0) {
    float t1 = pS[0][lane] + pS[1][lane] + pS[2][lane] + pS[3][lane];
    float t2 = pS2[0][lane] + pS2[1][lane] + pS2[2][lane] + pS2[3][lane];
    float mu = t1 * (1.f / CC);
    float var = t2 * (1.f / CC) - mu * mu;
    bcM[lane] = mu; bcR[lane] = rsqrtf(var + EPSLN);
  }
  __syncthreads();
  float mu = bcM[lane], r = bcR[lane];
  size_t obase = ((size_t)bimg * HWP + n0 + lane) * CC + w * 32;
#pragma unroll
  for (int i = 0; i < 4; i++) {
    float v[8];
#pragma unroll
    for (int q = 0; q < 8; q++) v[q] = tile[(w * 32 + i * 8 + q) * 64 + lane];
    *(ushort4*)(featT + obase + i * 8)     = pack4(v[0], v[1], v[2], v[3]);
    *(ushort4*)(featT + obase + i * 8 + 4) = pack4(v[4], v[5], v[6], v[7]);
    *(ushort4*)(xhatT + obase + i * 8)     = pack4((v[0]-mu)*r, (v[1]-mu)*r, (v[2]-mu)*r, (v[3]-mu)*r);
    *(ushort4*)(xhatT + obase + i * 8 + 4) = pack4((v[4]-mu)*r, (v[5]-mu)*r, (v[6]-mu)*r, (v[7]-mu)*r);
  }
}

// ---------------- shared helpers ----------------
__device__ __forceinline__ void stage_tile(const ushort* __restrict__ g, ushort* lds, int tid) {
#pragma unroll
  for (int i = 0; i < 8; i++) {
    int d = (tid + i * 256) * 16;
    int row = d >> 8;
    uint4 v = *(const uint4*)((const char*)g + d);
    *(uint4*)((char*)lds + (d ^ ((row & 7) << 4))) = v;
  }
}
__device__ __forceinline__ bf16x8 ldfrag(const ushort* lds, int row, int kb) {
  return *(const bf16x8*)((const char*)lds + row * 256 + (kb ^ ((row & 7) << 4)));
}
__device__ __forceinline__ void stage8(ushort* st, int px, int o, ushort4 v) {
  *(ushort4*)((char*)st + px * 256 + ((o * 2) ^ ((px & 7) << 4))) = v;
}
__device__ __forceinline__ uint4 ldstage16(const ushort* st, int px, int ck) {
  return *(const uint4*)((const char*)st + px * 256 + ((ck * 16) ^ ((px & 7) << 4)));
}

// ---------------- fused conv1 + depthwise3x3 + SimpleGate + mean ----------------
// Block = (pair, 8x8 px tile). t lives only in LDS (10x10 halo, recomputed rim).
__global__ __launch_bounds__(256, 2) void c1dw_kernel(
    const ushort* __restrict__ W1eff, const float* __restrict__ b1eff,
    const ushort* __restrict__ xhatT,
    const float* __restrict__ conv2_w, const float* __restrict__ conv2_b,
    const int* __restrict__ pair_e, int pair_lo,
    ushort* __restrict__ yT, float* __restrict__ mean_raw) {
  __shared__ ushort Ah[HPX * CC];     // xhat halo, rows 256B, swizzled
  __shared__ ushort Th[HPX * DWC];    // t halo, rows 512B, swizzled; reused as f32 psum
  int ts = blockIdx.x;
  int pc = blockIdx.z, p = pair_lo + pc, e = pair_e[p];
  int img = p / KT;
  int th = (ts >> 3) * 8, tw = (ts & 7) * 8;
  int tid = threadIdx.x, lane = tid & 63, w = tid >> 6;
  int fr = lane & 15, qf = lane >> 4;

  // phase 1: stage xhat halo (clamped addresses; invalid px masked at t-store)
#pragma unroll
  for (int i = 0; i < 7; i++) {
    int idx = tid + i * 256;
    if (idx < HPX * 16) {
      int r = idx >> 4, seg = idx & 15;
      int hy = r / HR, hx = r - hy * HR;
      int hh = th + hy - 1, ww = tw + hx - 1;
      int hc = min(max(hh, 0), 63), wc = min(max(ww, 0), 63);
      uint4 v = *(const uint4*)(xhatT + ((size_t)img * HWP + hc * 64 + wc) * CC + seg * 8);
      *(uint4*)((char*)Ah + r * 256 + ((seg * 16) ^ ((r & 7) << 4))) = v;
    }
  }
  __syncthreads();

  // phase 2: MFMA conv1 over halo. A = W1eff rows (global/L2), B = Ah rows.
  // wave w covers out-ch w*64..w*64+63; nf covers px 16nf..16nf+15 (pad past 100 masked).
  f32x4 acc[4][7] = {};
#pragma unroll
  for (int ks = 0; ks < 4; ks++) {
    bf16x8 afr[4], b[7];
#pragma unroll
    for (int mf = 0; mf < 4; mf++)
      afr[mf] = *(const bf16x8*)(W1eff + (size_t)(e * DWC + w * 64 + mf * 16 + fr) * CC + ks * 32 + qf * 8);
#pragma unroll
    for (int nf = 0; nf < 7; nf++) b[nf] = ldfrag(Ah, nf * 16 + fr, ks * 64 + qf * 16);
#pragma unroll
    for (int mf = 0; mf < 4; mf++)
#pragma unroll
      for (int nf = 0; nf < 7; nf++)
        acc[mf][nf] = __builtin_amdgcn_mfma_f32_16x16x32_bf16(afr[mf], b[nf], acc[mf][nf], 0, 0, 0);
  }

  // phase 3: t-store into Th with bias; zero at invalid (zero-pad) px.
  float4 bv[4];
#pragma unroll
  for (int mf = 0; mf < 4; mf++)
    bv[mf] = *(const float4*)&b1eff[e * DWC + w * 64 + mf * 16 + qf * 4];
#pragma unroll
  for (int nf = 0; nf < 7; nf++) {
    int px = nf * 16 + fr;
    if (px < HPX) {
      int hy = px / HR, hx = px - hy * HR;
      int hh = th + hy - 1, ww = tw + hx - 1;
      bool valid = (hh >= 0 && hh < 64 && ww >= 0 && ww < 64);
      int swz = (px & 7) << 4;
#pragma unroll
      for (int mf = 0; mf < 4; mf++) {
        int ch = w * 64 + mf * 16 + qf * 4;
        f32x4 v = acc[mf][nf];
        ushort4 st;
        if (valid) st = pack4(v.x + bv[mf].x, v.y + bv[mf].y, v.z + bv[mf].z, v.w + bv[mf].w);
        else { st.x = 0; st.y = 0; st.z = 0; st.w = 0; }
        *(ushort4*)((char*)Th + px * 512 + ((ch * 2) ^ swz)) = st;
      }
    }
  }
  __syncthreads();

  // phase 4: depthwise 3x3 + SimpleGate. thread = (qt ch-quarter, opx of 8x8)
  int opx = tid & 63, qt = tid >> 6;
  int oy = opx >> 3, ox = opx & 7;
  const float* wA = conv2_w + ((size_t)e * DWC + qt * 32) * 9;
  const float* wG = conv2_w + ((size_t)(e * DWC + CC) + qt * 32) * 9;
  const float* bA = conv2_b + e * DWC + qt * 32;
  const float* bG = conv2_b + e * DWC + CC + qt * 32;
  float ysf[8][4];
#pragma unroll
  for (int cg = 0; cg < 8; cg++) {
    int cb = qt * 64 + cg * 8;   // byte offset of these 4 a-ch in a Th row
    float aA[4] = {}, aG[4] = {};
#pragma unroll
    for (int dh = 0; dh < 3; dh++) {
#pragma unroll
      for (int dw2 = 0; dw2 < 3; dw2++) {
        int r = (oy + dh) * HR + ox + dw2;
        int swz = (r & 7) << 4;
        const char* rp = (const char*)Th + r * 512;
        ushort4 va = *(const ushort4*)(rp + (cb ^ swz));
        ushort4 vg = *(const ushort4*)(rp + ((cb + 256) ^ swz));
        int wo = dh * 3 + dw2;
        aA[0] = fmaf(bf2f(va.x), wA[(cg * 4 + 0) * 9 + wo], aA[0]);
        aA[1] = fmaf(bf2f(va.y), wA[(cg * 4 + 1) * 9 + wo], aA[1]);
        aA[2] = fmaf(bf2f(va.z), wA[(cg * 4 + 2) * 9 + wo], aA[2]);
        aA[3] = fmaf(bf2f(va.w), wA[(cg * 4 + 3) * 9 + wo], aA[3]);
        aG[0] = fmaf(bf2f(vg.x), wG[(cg * 4 + 0) * 9 + wo], aG[0]);
        aG[1] = fmaf(bf2f(vg.y), wG[(cg * 4 + 1) * 9 + wo], aG[1]);
        aG[2] = fmaf(bf2f(vg.z), wG[(cg * 4 + 2) * 9 + wo], aG[2]);
        aG[3] = fmaf(bf2f(vg.w), wG[(cg * 4 + 3) * 9 + wo], aG[3]);
      }
    }
#pragma unroll
    for (int t2 = 0; t2 < 4; t2++)
      ysf[cg][t2] = (aA[t2] + bA[cg * 4 + t2]) * (aG[t2] + bG[cg * 4 + t2]);
  }
  // y global write (64B per thread, pixel-major)
  {
    int n = (th + oy) * 64 + tw + ox;
    ushort* yp = yT + ((size_t)pc * HWP + n) * CC + qt * 32;
#pragma unroll
    for (int cg = 0; cg < 8; cg++)
      *(ushort4*)(yp + cg * 4) = pack4(ysf[cg][0], ysf[cg][1], ysf[cg][2], ysf[cg][3]);
  }
  __syncthreads();   // Th (taps) fully consumed; reuse as f32 psum [4][64][32]
  float* ps = (float*)Th;
#pragma unroll
  for (int cg = 0; cg < 8; cg++) {
    float4 v4; v4.x = ysf[cg][0]; v4.y = ysf[cg][1]; v4.z = ysf[cg][2]; v4.w = ysf[cg][3];
    *(float4*)((char*)ps + qt * 8192 + opx * 128 + ((cg * 16) ^ ((opx & 7) << 4))) = v4;
  }
  __syncthreads();
  if (tid < 128) {
    int qq = tid >> 5, ch = tid & 31;
    float s = 0.f;
#pragma unroll
    for (int px2 = 0; px2 < 64; px2++)
      s += *(const float*)((const char*)ps + qq * 8192 + px2 * 128 +
                           (((ch >> 2) * 16) ^ ((px2 & 7) << 4)) + (ch & 3) * 4);
    atomicAdd(&mean_raw[p * CC + qq * 32 + ch], s);
  }
}

// ---------------- SCA + W3eff fold merged ----------------
__global__ void sca_w3fold_kernel(const float* __restrict__ mean_raw,
                                  const float* __restrict__ sca_w, const float* __restrict__ sca_b,
                                  const float* __restrict__ conv3_w, const float* __restrict__ beta,
                                  const int* __restrict__ pair_e, int pair_lo,
                                  ushort* __restrict__ W3eff) {
  __shared__ float m[CC];
  __shared__ float sv[CC];
  int pc = blockIdx.x, p = pair_lo + pc, e = pair_e[p];
  int tid = threadIdx.x;
  if (tid < CC) m[tid] = mean_raw[p * CC + tid] * (1.f / HWP);
  __syncthreads();
  if (tid < CC) {
    const float* wr = sca_w + (size_t)(e * CC + tid) * CC;
    float acc = sca_b[e * CC + tid];
#pragma unroll 8
    for (int c = 0; c < CC; c++) acc = fmaf(wr[c], m[c], acc);
    sv[tid] = acc;
  }
  __syncthreads();
#pragma unroll
  for (int i = 0; i < 8; i++) {
    int idx = tid + i * 256;
    int o = idx >> 4, k0 = (idx & 15) * 8;
    float bt = beta[e * CC + o];
    const float* src = conv3_w + ((size_t)e * CC + o) * CC + k0;
    ushort* dst = W3eff + ((size_t)pc * CC + o) * CC + k0;
#pragma unroll
    for (int q = 0; q < 8; q++) dst[q] = f2bf(src[q] * sv[k0 + q] * bt);
  }
}

// ---------------- conv3 + residual + fused LN2 ----------------
__global__ __launch_bounds__(256, 2) void conv3_ln2_kernel(
    const ushort* __restrict__ W3eff, const float* __restrict__ b3eff,
    const ushort* __restrict__ yT, const ushort* __restrict__ featT,
    const int* __restrict__ pair_e, int pair_lo,
    ushort* __restrict__ x1T, ushort* __restrict__ xh2T) {
  __shared__ ushort Ws[CC * CC];
  __shared__ ushort As[CC * CC];
  int pc = blockIdx.z, p = pair_lo + pc, e = pair_e[p];
  int img = p / KT;
  int n0 = blockIdx.x * 128;
  int tid = threadIdx.x, lane = tid & 63, w = tid >> 6;
  stage_tile(W3eff + (size_t)pc * CC * CC, Ws, tid);
  stage_tile(yT + ((size_t)pc * HWP + n0) * CC, As, tid);
  __syncthreads();
  int wr = w >> 1, wc = w & 1, fr = lane & 15, kb0 = (lane >> 4) * 16, og = (lane >> 4) * 4;
  f32x4 acc[4][4] = {};
#pragma unroll
  for (int ks = 0; ks < 4; ks++) {
    bf16x8 a[4], b[4];
#pragma unroll
    for (int m = 0; m < 4; m++) a[m] = ldfrag(Ws, wr * 64 + m * 16 + fr, ks * 64 + kb0);
#pragma unroll
    for (int n = 0; n < 4; n++) b[n] = ldfrag(As, wc * 64 + n * 16 + fr, ks * 64 + kb0);
#pragma unroll
    for (int m = 0; m < 4; m++)
#pragma unroll
      for (int n = 0; n < 4; n++)
        acc[m][n] = __builtin_amdgcn_mfma_f32_16x16x32_bf16(a[m], b[n], acc[m][n], 0, 0, 0);
  }
  float s[4] = {}, s2[4] = {};
#pragma unroll
  for (int m = 0; m < 4; m++) {
    int o = wr * 64 + m * 16 + og;
    float4 bvv = *(const float4*)&b3eff[e * CC + o];
#pragma unroll
    for (int n = 0; n < 4; n++) {
      int px = wc * 64 + n * 16 + fr;
      ushort4 f4 = *(const ushort4*)(featT + ((size_t)img * HWP + n0 + px) * CC + o);
      f32x4 v = acc[m][n];
      v.x += bf2f(f4.x) + bvv.x; v.y += bf2f(f4.y) + bvv.y;
      v.z += bf2f(f4.z) + bvv.z; v.w += bf2f(f4.w) + bvv.w;
      acc[m][n] = v;
      s[n] += v.x + v.y + v.z + v.w;
      s2[n] += v.x * v.x + v.y * v.y + v.z * v.z + v.w * v.w;
    }
  }
#pragma unroll
  for (int n = 0; n < 4; n++) {
    s[n] += __shfl_xor(s[n], 16, 64); s[n] += __shfl_xor(s[n], 32, 64);
    s2[n] += __shfl_xor(s2[n], 16, 64); s2[n] += __shfl_xor(s2[n], 32, 64);
  }
  __syncthreads();
  float2* red = (float2*)As;
  if (lane < 16) {
#pragma unroll
    for (int n = 0; n < 4; n++) {
      float2 v; v.x = s[n]; v.y = s2[n];
      red[wr * 128 + wc * 64 + n * 16 + fr] = v;
    }
  }
  __syncthreads();
  float mu[4], rs[4];
#pragma unroll
  for (int n = 0; n < 4; n++) {
    int px = wc * 64 + n * 16 + fr;
    float2 r0 = red[px], r1 = red[128 + px];
    float m_ = (r0.x + r1.x) * (1.f / CC);
    float var = (r0.y + r1.y) * (1.f / CC) - m_ * m_;
    mu[n] = m_; rs[n] = rsqrtf(var + EPSLN);
  }
  __syncthreads();
#pragma unroll
  for (int m = 0; m < 4; m++) {
    int o = wr * 64 + m * 16 + og;
#pragma unroll
    for (int n = 0; n < 4; n++) {
      int px = wc * 64 + n * 16 + fr;
      f32x4 v = acc[m][n];
      stage8(As, px, o, pack4(v.x, v.y, v.z, v.w));
      stage8(Ws, px, o, pack4((v.x - mu[n]) * rs[n], (v.y - mu[n]) * rs[n],
                              (v.z - mu[n]) * rs[n], (v.w - mu[n]) * rs[n]));
    }
  }
  __syncthreads();
#pragma unroll
  for (int i = 0; i < 8; i++) {
    int idx = tid + i * 256;
    int px = idx >> 4, ck = idx & 15;
    size_t gb = ((size_t)pc * HWP + n0 + px) * CC;
    *(uint4*)((char*)(x1T + gb) + ck * 16)  = ldstage16(As, px, ck);
    *(uint4*)((char*)(xh2T + gb) + ck * 16) = ldstage16(Ws, px, ck);
  }
}

// ---------------- conv4 both halves + SimpleGate fused ----------------
__global__ __launch_bounds__(256, 2) void conv4sg_kernel(
    const ushort* __restrict__ W4eff, const float* __restrict__ b4eff,
    const ushort* __restrict__ xh2T, const int* __restrict__ pair_e,
    int pair_lo, ushort* __restrict__ g5T) {
  __shared__ ushort Ws[CC * CC];
  __shared__ ushort As[CC * CC];
  int pc = blockIdx.z, p = pair_lo + pc, e = pair_e[p];
  int n0 = blockIdx.x * 128;
  int tid = threadIdx.x, lane = tid & 63, w = tid >> 6;
  int wr = w >> 1, wc = w & 1, fr = lane & 15, kb0 = (lane >> 4) * 16, og = (lane >> 4) * 4;
  stage_tile(W4eff + (size_t)e * DWC * CC, Ws, tid);
  stage_tile(xh2T + ((size_t)pc * HWP + n0) * CC, As, tid);
  __syncthreads();
  f32x4 accA[4][4] = {}, accG[4][4] = {};
#pragma unroll
  for (int ks = 0; ks < 4; ks++) {
    bf16x8 a[4], b[4];
#pragma unroll
    for (int m = 0; m < 4; m++) a[m] = ldfrag(Ws, wr * 64 + m * 16 + fr, ks * 64 + kb0);
#pragma unroll
    for (int n = 0; n < 4; n++) b[n] = ldfrag(As, wc * 64 + n * 16 + fr, ks * 64 + kb0);
#pragma unroll
    for (int m = 0; m < 4; m++)
#pragma unroll
      for (int n = 0; n < 4; n++)
        accA[m][n] = __builtin_amdgcn_mfma_f32_16x16x32_bf16(a[m], b[n], accA[m][n], 0, 0, 0);
  }
  __syncthreads();
  stage_tile(W4eff + ((size_t)e * DWC + CC) * CC, Ws, tid);
  __syncthreads();
#pragma unroll
  for (int ks = 0; ks < 4; ks++) {
    bf16x8 a[4], b[4];
#pragma unroll
    for (int m = 0; m < 4; m++) a[m] = ldfrag(Ws, wr * 64 + m * 16 + fr, ks * 64 + kb0);
#pragma unroll
    for (int n = 0; n < 4; n++) b[n] = ldfrag(As, wc * 64 + n * 16 + fr, ks * 64 + kb0);
#pragma unroll
    for (int m = 0; m < 4; m++)
#pragma unroll
      for (int n = 0; n < 4; n++)
        accG[m][n] = __builtin_amdgcn_mfma_f32_16x16x32_bf16(a[m], b[n], accG[m][n], 0, 0, 0);
  }
  __syncthreads();
#pragma unroll
  for (int m = 0; m < 4; m++) {
    int o = wr * 64 + m * 16 + og;
    float4 ba = *(const float4*)&b4eff[e * DWC + o];
    float4 bg = *(const float4*)&b4eff[e * DWC + CC + o];
#pragma unroll
    for (int n = 0; n < 4; n++) {
      int px = wc * 64 + n * 16 + fr;
      f32x4 va = accA[m][n], vg = accG[m][n];
      stage8(Ws, px, o, pack4((va.x + ba.x) * (vg.x + bg.x), (va.y + ba.y) * (vg.y + bg.y),
                              (va.z + ba.z) * (vg.z + bg.z), (va.w + ba.w) * (vg.w + bg.w)));
    }
  }
  __syncthreads();
#pragma unroll
  for (int i = 0; i < 8; i++) {
    int idx = tid + i * 256;
    int px = idx >> 4, ck = idx & 15;
    uint4 v = ldstage16(Ws, px, ck);
    *(uint4*)((char*)(g5T + ((size_t)pc * HWP + n0 + px) * CC) + ck * 16) = v;
  }
}

// ---------------- conv5: 3-pair accumulated MFMA + transpose epilogue ----------------
__global__ __launch_bounds__(256, 2) void conv5_kernel(
    const ushort* __restrict__ W5eff, const float* __restrict__ b5tot,
    const ushort* __restrict__ g5T, const ushort* __restrict__ x1,
    const float* __restrict__ gate_w, int pair_lo, float* __restrict__ out) {
  __shared__ ushort Ws[CC * CC];
  __shared__ ushort As[CC * CC];
  int sl = blockIdx.z;
  int n0 = blockIdx.x * 128;
  int b = pair_lo / KT + sl;
  int tid = threadIdx.x, lane = tid & 63, w = tid >> 6;
  int wr = w >> 1, wc = w & 1;
  int fr = lane & 15, kb0 = (lane >> 4) * 16, og = (lane >> 4) * 4;
  f32x4 acc[4][4] = {};
  for (int j = 0; j < KT; j++) {
    int pc = sl * KT + j, p = pair_lo + pc;
    __syncthreads();
    stage_tile(W5eff + (size_t)p * CC * CC, Ws, tid);
    stage_tile(g5T + ((size_t)pc * HWP + n0) * CC, As, tid);
    __syncthreads();
#pragma unroll
    for (int ks = 0; ks < 4; ks++) {
      bf16x8 a[4], bfr[4];
#pragma unroll
      for (int m = 0; m < 4; m++) a[m] = ldfrag(Ws, wr * 64 + m * 16 + fr, ks * 64 + kb0);
#pragma unroll
      for (int n = 0; n < 4; n++) bfr[n] = ldfrag(As, wc * 64 + n * 16 + fr, ks * 64 + kb0);
#pragma unroll
      for (int m = 0; m < 4; m++)
#pragma unroll
        for (int n = 0; n < 4; n++)
          acc[m][n] = __builtin_amdgcn_mfma_f32_16x16x32_bf16(a[m], bfr[n], acc[m][n], 0, 0, 0);
    }
  }
  float gw0 = gate_w[pair_lo + sl * KT + 0];
  float gw1 = gate_w[pair_lo + sl * KT + 1];
  float gw2 = gate_w[pair_lo + sl * KT + 2];
  __syncthreads();
  ushort* Ct = As;
#pragma unroll
  for (int m = 0; m < 4; m++) {
    int o = wr * 64 + m * 16 + og;
    float4 bt = *(const float4*)&b5tot[b * CC + o];
#pragma unroll
    for (int n = 0; n < 4; n++) {
      int px = wc * 64 + n * 16 + fr;
      f32x4 v = acc[m][n];
      float r0 = v.x + bt.x, r1 = v.y + bt.y, r2 = v.z + bt.z, r3 = v.w + bt.w;
      size_t xoff = ((size_t)(sl * KT) * HWP + n0 + px) * CC + o;
      ushort4 xa = *(const ushort4*)(x1 + xoff);
      ushort4 xb = *(const ushort4*)(x1 + xoff + (size_t)HWP * CC);
      ushort4 xc = *(const ushort4*)(x1 + xoff + 2 * (size_t)HWP * CC);
      r0 += gw0 * bf2f(xa.x) + gw1 * bf2f(xb.x) + gw2 * bf2f(xc.x);
      r1 += gw0 * bf2f(xa.y) + gw1 * bf2f(xb.y) + gw2 * bf2f(xc.y);
      r2 += gw0 * bf2f(xa.z) + gw1 * bf2f(xb.z) + gw2 * bf2f(xc.z);
      r3 += gw0 * bf2f(xa.w) + gw1 * bf2f(xb.w) + gw2 * bf2f(xc.w);
      *(ushort*)((char*)Ct + (o+0) * 256 + ((px*2) ^ (((o+0) & 7) << 4))) = f2bf(r0);
      *(ushort*)((char*)Ct + (o+1) * 256 + ((px*2) ^ (((o+1) & 7) << 4))) = f2bf(r1);
      *(ushort*)((char*)Ct + (o+2) * 256 + ((px*2) ^ (((o+2) & 7) << 4))) = f2bf(r2);
      *(ushort*)((char*)Ct + (o+3) * 256 + ((px*2) ^ (((o+3) & 7) << 4))) = f2bf(r3);
    }
  }
  __syncthreads();
  int o = tid >> 1, ph = (tid & 1) * 64;
  float* orow = out + ((size_t)(b * CC + o)) * HWP + n0 + ph;
  int swz = (o & 7) << 4;
#pragma unroll
  for (int i = 0; i < 8; i++) {
    const ushort* lp = (const ushort*)((const char*)Ct + o * 256 + ((ph * 2 + i * 16) ^ swz));
    float4 f0, f1;
    f0.x = bf2f(lp[0]); f0.y = bf2f(lp[1]); f0.z = bf2f(lp[2]); f0.w = bf2f(lp[3]);
    f1.x = bf2f(lp[4]); f1.y = bf2f(lp[5]); f1.z = bf2f(lp[6]); f1.w = bf2f(lp[7]);
    *(float4*)(orow + i * 8) = f0;
    *(float4*)(orow + i * 8 + 4) = f1;
  }
}

extern "C" void kernel_launch(void* const* d_in, const int* in_sizes, int n_in,
                              void* d_out, int out_size, void* d_ws, size_t ws_size,
                              hipStream_t stream) {
  const float* feat    = (const float*)d_in[0];
  const float* weights = (const float*)d_in[1];
  const float* ln1_w   = (const float*)d_in[2];
  const float* ln1_b   = (const float*)d_in[3];
  const float* conv1_w = (const float*)d_in[4];
  const float* conv1_b = (const float*)d_in[5];
  const float* conv2_w = (const float*)d_in[6];
  const float* conv2_b = (const float*)d_in[7];
  const float* sca_w   = (const float*)d_in[8];
  const float* sca_b   = (const float*)d_in[9];
  const float* conv3_w = (const float*)d_in[10];
  const float* conv3_b = (const float*)d_in[11];
  const float* ln2_w   = (const float*)d_in[12];
  const float* ln2_b   = (const float*)d_in[13];
  const float* conv4_w = (const float*)d_in[14];
  const float* conv4_b = (const float*)d_in[15];
  const float* conv5_w = (const float*)d_in[16];
  const float* conv5_b = (const float*)d_in[17];
  const float* beta    = (const float*)d_in[18];
  const float* gamma   = (const float*)d_in[19];

  float* out = (float*)d_out;
  float* out_counts = out + (size_t)BB * CC * HWP;
  float* out_weights = out_counts + EN;

  char* base = (char*)d_ws;
  size_t off = 0;
  auto carveU = [&](size_t n) -> ushort* { ushort* p = (ushort*)(base + off); off += n * 2; return p; };
  auto carveF = [&](size_t n) -> float* { float* p = (float*)(base + off); off += n * 4; return p; };

  ushort* W1eff = carveU((size_t)EN * DWC * CC);
  ushort* W4eff = carveU((size_t)EN * DWC * CC);
  ushort* W5eff = carveU((size_t)NPAIR * CC * CC);
  ushort* W3eff = carveU((size_t)NPAIR * CC * CC);
  float* b1eff  = carveF(EN * DWC);
  float* b4eff  = carveF(EN * DWC);
  float* b3eff  = carveF(EN * CC);
  float* b5tot  = carveF(BB * CC);
  float* gate_w = carveF(64);
  int*   pair_e = (int*)carveF(64);
  float* mean_raw = carveF(NPAIR * CC);
  ushort* xhatT = carveU((size_t)BB * HWP * CC);
  ushort* featT = carveU((size_t)BB * HWP * CC);

  // per-pair: y (1MB, reused as xh2) + x1 (1MB) + g5 (1MB)
  const size_t per_pair = (size_t)3 * HWP * CC * 2;
  int ns = 16;
  while (ns > 1 && off + (size_t)ns * KT * per_pair > ws_size) ns >>= 1;
  size_t pr = (size_t)ns * KT;
  ushort* y_T   = carveU(pr * HWP * CC);
  ushort* x1_T  = carveU(pr * HWP * CC);
  ushort* g5_T  = carveU(pr * HWP * CC);
  ushort* xh2_T = y_T;   // alias: conv3_ln2 reads its own y tile to LDS before writing xh2

  gate_kernel<<<1, 256, 0, stream>>>(weights, gate_w, pair_e, out_counts, out_weights, mean_raw);
  fold_kernel<<<13, 256, 0, stream>>>(conv1_w, conv1_b, ln1_w, ln1_b,
                                      conv4_w, conv4_b, ln2_w, ln2_b,
                                      conv3_b, beta, W1eff, b1eff, W4eff, b4eff, b3eff);
  fold2_kernel<<<393, 256, 0, stream>>>(conv5_w, conv5_b, gamma, gate_w, pair_e, W5eff, b5tot);
  ln1_kernel<<<BB * 64, 256, 0, stream>>>(feat, xhatT, featT);

  for (int s0 = 0; s0 < BB; s0 += ns) {
    int np = ns * KT, plo = s0 * KT;
    c1dw_kernel<<<dim3(64, 1, np), 256, 0, stream>>>(W1eff, b1eff, xhatT, conv2_w, conv2_b,
                                                     pair_e, plo, y_T, mean_raw);
    sca_w3fold_kernel<<<np, 256, 0, stream>>>(mean_raw, sca_w, sca_b, conv3_w, beta,
                                              pair_e, plo, W3eff);
    conv3_ln2_kernel<<<dim3(32, 1, np), 256, 0, stream>>>(W3eff, b3eff, y_T, featT,
                                                          pair_e, plo, x1_T, xh2_T);
    conv4sg_kernel<<<dim3(32, 1, np), 256, 0, stream>>>(W4eff, b4eff, xh2_T, pair_e, plo, g5_T);
    conv5_kernel<<<dim3(32, 1, ns), 256, 0, stream>>>(W5eff, b5tot, g5_T, x1_T,
                                                      gate_w, plo, out);
  }
}

// Round 7
// 230.077 us; speedup vs baseline: 3.4493x; 1.1127x over previous
//
#include <hip/hip_runtime.h>

#define EN 5
#define KT 3
#define BB 16
#define CC 128
#define HWP 4096
#define DWC 256
#define NPAIR 48
#define EPSLN 1e-6f
#define HR 10        // 8x8 tile + 1px halo each side
#define HPX 100      // 10*10 halo pixels
#define TSTRIDE 106  // ushorts per Th channel row (212B; 53 words, odd -> all 32 banks)

typedef float f32x4 __attribute__((ext_vector_type(4)));
typedef __bf16 bf16x8 __attribute__((ext_vector_type(8)));

__device__ __forceinline__ float bf2f(ushort u) {
  union { unsigned int u; float f; } v; v.u = ((unsigned int)u) << 16; return v.f;
}
__device__ __forceinline__ ushort f2bf(float f) {
  union { float f; unsigned int u; } v; v.f = f;
  unsigned int r = v.u + 0x7FFFu + ((v.u >> 16) & 1u);
  return (ushort)(r >> 16);
}
__device__ __forceinline__ ushort4 pack4(float a, float b, float c, float d) {
  ushort4 r; r.x = f2bf(a); r.y = f2bf(b); r.z = f2bf(c); r.w = f2bf(d); return r;
}

// ---------------- gate ----------------
__global__ void gate_kernel(const float* __restrict__ weights, float* __restrict__ gate_w,
                            int* __restrict__ pair_e, float* __restrict__ out_counts,
                            float* __restrict__ out_weights, float* __restrict__ mean_raw) {
  __shared__ int sel[NPAIR];
  int tid = threadIdx.x;
  if (tid < BB) {
    float w[EN];
    for (int e = 0; e < EN; e++) w[e] = weights[tid * EN + e];
    int ch[KT]; float cv[KT]; float sum = 0.f;
    for (int j = 0; j < KT; j++) {
      int best = -1; float bv = -3.4e38f;
      for (int e = 0; e < EN; e++) {
        bool used = false;
        for (int q = 0; q < j; q++) if (ch[q] == e) used = true;
        if (!used && w[e] > bv) { bv = w[e]; best = e; }
      }
      ch[j] = best; cv[j] = bv; sum += bv;
    }
    float inv = 1.f / sum;
    for (int j = 0; j < KT; j++) {
      gate_w[tid * KT + j] = cv[j] * inv;
      pair_e[tid * KT + j] = ch[j];
      sel[tid * KT + j] = ch[j];
    }
  }
  for (int i = tid; i < NPAIR * CC; i += 256) mean_raw[i] = 0.f;
  __syncthreads();
  if (tid < EN) {
    int cnt = 0;
    for (int i = 0; i < NPAIR; i++) if (sel[i] == tid) cnt++;
    out_counts[tid] = (float)cnt;
  }
  if (tid < BB * EN) out_weights[tid] = weights[tid];
}

// ---------------- fold LN into conv1/conv4 ----------------
__global__ void fold_kernel(const float* __restrict__ conv1_w, const float* __restrict__ conv1_b,
                            const float* __restrict__ ln1_w, const float* __restrict__ ln1_b,
                            const float* __restrict__ conv4_w, const float* __restrict__ conv4_b,
                            const float* __restrict__ ln2_w, const float* __restrict__ ln2_b,
                            const float* __restrict__ conv3_b, const float* __restrict__ beta,
                            ushort* __restrict__ W1eff, float* __restrict__ b1eff,
                            ushort* __restrict__ W4eff, float* __restrict__ b4eff,
                            float* __restrict__ b3eff) {
  int gid = blockIdx.x * 256 + threadIdx.x;
  if (gid < 2 * EN * DWC) {
    int which = gid / (EN * DWC), rem = gid % (EN * DWC);
    int e = rem / DWC, o = rem % DWC;
    const float* src = (which ? conv4_w : conv1_w) + (size_t)(e * DWC + o) * CC;
    const float* lw = (which ? ln2_w : ln1_w) + e * CC;
    const float* lb = (which ? ln2_b : ln1_b) + e * CC;
    float bacc = (which ? conv4_b : conv1_b)[e * DWC + o];
    ushort* dst = (which ? W4eff : W1eff) + (size_t)(e * DWC + o) * CC;
    for (int c = 0; c < CC; c++) {
      float wv = src[c];
      dst[c] = f2bf(wv * lw[c]);
      bacc += wv * lb[c];
    }
    (which ? b4eff : b1eff)[e * DWC + o] = bacc;
  } else if (gid < 2 * EN * DWC + EN * CC) {
    int x = gid - 2 * EN * DWC;
    b3eff[x] = beta[x] * conv3_b[x];
  }
}

// ---------------- fold2: W5eff[p]=conv5_w[e]*gamma*gate; b5tot ----------------
__global__ void fold2_kernel(const float* __restrict__ conv5_w, const float* __restrict__ conv5_b,
                             const float* __restrict__ gamma, const float* __restrict__ gate_w,
                             const int* __restrict__ pair_e,
                             ushort* __restrict__ W5eff, float* __restrict__ b5tot) {
  int gid = blockIdx.x * 256 + threadIdx.x;
  const int nW = NPAIR * CC * CC / 8;
  if (gid < nW) {
    int base = gid * 8;
    int p = base >> 14, rem = base & 16383;
    int o = rem >> 7, k0 = rem & 127;
    int e = pair_e[p];
    float sc = gamma[e * CC + o] * gate_w[p];
    const float* src = conv5_w + ((size_t)e * CC + o) * CC + k0;
    ushort* dst = W5eff + ((size_t)p * CC + o) * CC + k0;
    for (int q = 0; q < 8; q++) dst[q] = f2bf(src[q] * sc);
  } else if (gid < nW + BB * CC) {
    int x = gid - nW;
    int b = x >> 7, o = x & 127;
    float s = 0.f;
    for (int j = 0; j < KT; j++) {
      int p = b * KT + j, e = pair_e[p];
      s += gate_w[p] * gamma[e * CC + o] * conv5_b[e * CC + o];
    }
    b5tot[x] = s;
  }
}

// ---------------- LN1 + transpose ----------------
__global__ __launch_bounds__(256) void ln1_kernel(const float* __restrict__ feat,
                                                  ushort* __restrict__ xhatT,
                                                  ushort* __restrict__ featT) {
  __shared__ float tile[CC * 64];
  __shared__ float pS[4][64], pS2[4][64], bcM[64], bcR[64];
  int bimg = blockIdx.x >> 6;
  int n0 = (blockIdx.x & 63) * 64;
  int tid = threadIdx.x;
  const float* src = feat + (size_t)bimg * CC * HWP + n0;
#pragma unroll
  for (int i = 0; i < 8; i++) {
    int ch = tid + i * 256;
    int row = ch >> 4, c16 = ch & 15;
    *(float4*)&tile[row * 64 + c16 * 4] = *(const float4*)(src + (size_t)row * HWP + c16 * 4);
  }
  __syncthreads();
  int lane = tid & 63, w = tid >> 6;
  float s = 0.f, s2 = 0.f;
#pragma unroll
  for (int i = 0; i < 32; i++) {
    float v = tile[(w * 32 + i) * 64 + lane];
    s += v; s2 += v * v;
  }
  pS[w][lane] = s; pS2[w][lane] = s2;
  __syncthreads();
  if (w == 0) {
    float t1 = pS[0][lane] + pS[1][lane] + pS[2][lane] + pS[3][lane];
    float t2 = pS2[0][lane] + pS2[1][lane] + pS2[2][lane] + pS2[3][lane];
    float mu = t1 * (1.f / CC);
    float var = t2 * (1.f / CC) - mu * mu;
    bcM[lane] = mu; bcR[lane] = rsqrtf(var + EPSLN);
  }
  __syncthreads();
  float mu = bcM[lane], r = bcR[lane];
  size_t obase = ((size_t)bimg * HWP + n0 + lane) * CC + w * 32;
#pragma unroll
  for (int i = 0; i < 4; i++) {
    float v[8];
#pragma unroll
    for (int q = 0; q < 8; q++) v[q] = tile[(w * 32 + i * 8 + q) * 64 + lane];
    *(ushort4*)(featT + obase + i * 8)     = pack4(v[0], v[1], v[2], v[3]);
    *(ushort4*)(featT + obase + i * 8 + 4) = pack4(v[4], v[5], v[6], v[7]);
    *(ushort4*)(xhatT + obase + i * 8)     = pack4((v[0]-mu)*r, (v[1]-mu)*r, (v[2]-mu)*r, (v[3]-mu)*r);
    *(ushort4*)(xhatT + obase + i * 8 + 4) = pack4((v[4]-mu)*r, (v[5]-mu)*r, (v[6]-mu)*r, (v[7]-mu)*r);
  }
}

// ---------------- shared helpers ----------------
__device__ __forceinline__ void stage_tile(const ushort* __restrict__ g, ushort* lds, int tid) {
#pragma unroll
  for (int i = 0; i < 8; i++) {
    int d = (tid + i * 256) * 16;
    int row = d >> 8;
    uint4 v = *(const uint4*)((const char*)g + d);
    *(uint4*)((char*)lds + (d ^ ((row & 7) << 4))) = v;
  }
}
__device__ __forceinline__ bf16x8 ldfrag(const ushort* lds, int row, int kb) {
  return *(const bf16x8*)((const char*)lds + row * 256 + (kb ^ ((row & 7) << 4)));
}
__device__ __forceinline__ void stage8(ushort* st, int px, int o, ushort4 v) {
  *(ushort4*)((char*)st + px * 256 + ((o * 2) ^ ((px & 7) << 4))) = v;
}
__device__ __forceinline__ uint4 ldstage16(const ushort* st, int px, int ck) {
  return *(const uint4*)((const char*)st + px * 256 + ((ck * 16) ^ ((px & 7) << 4)));
}

// ---------------- fused conv1 + depthwise3x3 + SimpleGate + mean (v2) ----------------
// One 54.3KB smem region phase-shared: Ah halo -> Th (channel-major) -> ystage+psum.
__global__ __launch_bounds__(256, 3) void c1dw_kernel(
    const ushort* __restrict__ W1eff, const float* __restrict__ b1eff,
    const ushort* __restrict__ xhatT,
    const float* __restrict__ conv2_w, const float* __restrict__ conv2_b,
    const int* __restrict__ pair_e, int pair_lo,
    ushort* __restrict__ yT, float* __restrict__ mean_raw) {
  __shared__ __align__(16) char smem[DWC * TSTRIDE * 2];   // 54272 B
  int ts = blockIdx.x;
  int pc = blockIdx.z, p = pair_lo + pc, e = pair_e[p];
  int img = p / KT;
  int th = (ts >> 3) * 8, tw = (ts & 7) * 8;
  int tid = threadIdx.x, lane = tid & 63, w = tid >> 6;
  int fr = lane & 15, qf = lane >> 4;

  // phase 1: stage xhat halo (256B rows, swizzled) at smem base
#pragma unroll
  for (int i = 0; i < 7; i++) {
    int idx = tid + i * 256;
    if (idx < HPX * 16) {
      int r = idx >> 4, seg = idx & 15;
      int hy = r / HR, hx = r - hy * HR;
      int hh = th + hy - 1, ww = tw + hx - 1;
      int hc = min(max(hh, 0), 63), wc = min(max(ww, 0), 63);
      uint4 v = *(const uint4*)(xhatT + ((size_t)img * HWP + hc * 64 + wc) * CC + seg * 8);
      *(uint4*)(smem + r * 256 + ((seg * 16) ^ ((r & 7) << 4))) = v;
    }
  }
  __syncthreads();

  // phase 2: MFMA conv1. A = W1eff rows (L2-resident), B = halo rows in smem.
  f32x4 acc[4][7] = {};
#pragma unroll
  for (int ks = 0; ks < 4; ks++) {
    bf16x8 afr[4];
#pragma unroll
    for (int mf = 0; mf < 4; mf++)
      afr[mf] = *(const bf16x8*)(W1eff + (size_t)(e * DWC + w * 64 + mf * 16 + fr) * CC + ks * 32 + qf * 8);
#pragma unroll
    for (int nf = 0; nf < 7; nf++) {
      bf16x8 b = ldfrag((const ushort*)smem, nf * 16 + fr, ks * 64 + qf * 16);
#pragma unroll
      for (int mf = 0; mf < 4; mf++)
        acc[mf][nf] = __builtin_amdgcn_mfma_f32_16x16x32_bf16(afr[mf], b, acc[mf][nf], 0, 0, 0);
    }
  }
  float4 bv[4];
#pragma unroll
  for (int mf = 0; mf < 4; mf++)
    bv[mf] = *(const float4*)&b1eff[e * DWC + w * 64 + mf * 16 + qf * 4];
  __syncthreads();   // halo reads done; smem becomes channel-major Th

  // phase 3: t -> Th[ch][px], zero at invalid (zero-pad) px
  ushort* Th = (ushort*)smem;
#pragma unroll
  for (int nf = 0; nf < 7; nf++) {
    int px = nf * 16 + fr;
    if (px < HPX) {
      int hy = px / HR, hx = px - hy * HR;
      int hh = th + hy - 1, ww = tw + hx - 1;
      bool valid = (hh >= 0 && hh < 64 && ww >= 0 && ww < 64);
#pragma unroll
      for (int mf = 0; mf < 4; mf++) {
        int ch = w * 64 + mf * 16 + qf * 4;
        f32x4 v = acc[mf][nf];
        Th[(ch + 0) * TSTRIDE + px] = valid ? f2bf(v.x + bv[mf].x) : (ushort)0;
        Th[(ch + 1) * TSTRIDE + px] = valid ? f2bf(v.y + bv[mf].y) : (ushort)0;
        Th[(ch + 2) * TSTRIDE + px] = valid ? f2bf(v.z + bv[mf].z) : (ushort)0;
        Th[(ch + 3) * TSTRIDE + px] = valid ? f2bf(v.w + bv[mf].w) : (ushort)0;
      }
    }
  }
  __syncthreads();

  // phase 4: depthwise 3x3 + SG. thread = (channel-pair cp, row-half ph2).
  int cp = tid & 127, ph2 = tid >> 7;     // ph2: out rows ph2*4 .. ph2*4+3
  const float* wAp = conv2_w + ((size_t)e * DWC + cp) * 9;
  const float* wGp = conv2_w + ((size_t)(e * DWC + CC) + cp) * 9;
  float wA9[9], wG9[9];
#pragma unroll
  for (int k = 0; k < 9; k++) { wA9[k] = wAp[k]; wG9[k] = wGp[k]; }
  float ba = conv2_b[e * DWC + cp], bg = conv2_b[e * DWC + CC + cp];

  auto loadrow = [&](float* dst, const ushort* pp) {
#pragma unroll
    for (int q = 0; q < 5; q++) {
      uint u = *(const uint*)(pp + q * 2);
      dst[q * 2]     = bf2f((ushort)(u & 0xffffu));
      dst[q * 2 + 1] = bf2f((ushort)(u >> 16));
    }
  };
  auto comp3 = [&](const float* w9, const float* r0, const float* r1, const float* r2, float* out) {
#pragma unroll
    for (int ox = 0; ox < 8; ox++) {
      float a = r0[ox] * w9[0];
      a = fmaf(r0[ox + 1], w9[1], a); a = fmaf(r0[ox + 2], w9[2], a);
      a = fmaf(r1[ox],     w9[3], a); a = fmaf(r1[ox + 1], w9[4], a);
      a = fmaf(r1[ox + 2], w9[5], a);
      a = fmaf(r2[ox],     w9[6], a); a = fmaf(r2[ox + 1], w9[7], a);
      a = fmaf(r2[ox + 2], w9[8], a);
      out[ox] = a;
    }
  };

  float win[3][10];
  float outv[4][8];
  // A half: channel cp, halo rows ph2*4 .. ph2*4+5
  {
    const ushort* rA = Th + cp * TSTRIDE + ph2 * 40;
    loadrow(win[0], rA); loadrow(win[1], rA + 10); loadrow(win[2], rA + 20);
    comp3(wA9, win[0], win[1], win[2], outv[0]);
    loadrow(win[0], rA + 30);
    comp3(wA9, win[1], win[2], win[0], outv[1]);
    loadrow(win[1], rA + 40);
    comp3(wA9, win[2], win[0], win[1], outv[2]);
    loadrow(win[2], rA + 50);
    comp3(wA9, win[0], win[1], win[2], outv[3]);
  }
  // G half + SG combine -> packed bf16 pairs; csum for mean
  uint ypk[16];
  float csum = 0.f;
  {
    const ushort* rG = Th + (cp + 128) * TSTRIDE + ph2 * 40;
    float gtmp[8];
    loadrow(win[0], rG); loadrow(win[1], rG + 10); loadrow(win[2], rG + 20);
#pragma unroll
    for (int oy = 0; oy < 4; oy++) {
      if (oy == 1) { loadrow(win[0], rG + 30); }
      if (oy == 2) { loadrow(win[1], rG + 40); }
      if (oy == 3) { loadrow(win[2], rG + 50); }
      const float* r0 = (oy == 0) ? win[0] : (oy == 1) ? win[1] : (oy == 2) ? win[2] : win[0];
      const float* r1 = (oy == 0) ? win[1] : (oy == 1) ? win[2] : (oy == 2) ? win[0] : win[1];
      const float* r2 = (oy == 0) ? win[2] : (oy == 1) ? win[0] : (oy == 2) ? win[1] : win[2];
      comp3(wG9, r0, r1, r2, gtmp);
#pragma unroll
      for (int ox = 0; ox < 8; ox += 2) {
        float y0 = (outv[oy][ox]     + ba) * (gtmp[ox]     + bg);
        float y1 = (outv[oy][ox + 1] + ba) * (gtmp[ox + 1] + bg);
        csum += y0 + y1;
        ypk[oy * 4 + (ox >> 1)] = (uint)f2bf(y0) | ((uint)f2bf(y1) << 16);
      }
    }
  }
  __syncthreads();   // all Th reads done; smem becomes ystage + psum

  // phase 5: ystage scatter (swizzled), psum, coalesced drain + mean
  float* psum = (float*)(smem + 16384);
#pragma unroll
  for (int oy = 0; oy < 4; oy++)
#pragma unroll
    for (int ox = 0; ox < 8; ox++) {
      int opx = (ph2 * 4 + oy) * 8 + ox;
      uint pkv = ypk[oy * 4 + (ox >> 1)];
      ushort val = (ox & 1) ? (ushort)(pkv >> 16) : (ushort)(pkv & 0xffffu);
      *(ushort*)(smem + opx * 256 + ((cp * 2) ^ ((opx & 7) << 4))) = val;
    }
  psum[tid] = csum;
  __syncthreads();
#pragma unroll
  for (int i = 0; i < 4; i++) {
    int idx = tid + i * 256;
    int opx = idx >> 4, ck = idx & 15;
    uint4 v = *(const uint4*)(smem + opx * 256 + ((ck * 16) ^ ((opx & 7) << 4)));
    int n = (th + (opx >> 3)) * 64 + tw + (opx & 7);
    *(uint4*)((char*)(yT + ((size_t)pc * HWP + n) * CC) + ck * 16) = v;
  }
  if (tid < CC) {
    atomicAdd(&mean_raw[p * CC + tid], psum[tid] + psum[CC + tid]);
  }
}

// ---------------- SCA + W3eff fold merged ----------------
__global__ void sca_w3fold_kernel(const float* __restrict__ mean_raw,
                                  const float* __restrict__ sca_w, const float* __restrict__ sca_b,
                                  const float* __restrict__ conv3_w, const float* __restrict__ beta,
                                  const int* __restrict__ pair_e, int pair_lo,
                                  ushort* __restrict__ W3eff) {
  __shared__ float m[CC];
  __shared__ float sv[CC];
  int pc = blockIdx.x, p = pair_lo + pc, e = pair_e[p];
  int tid = threadIdx.x;
  if (tid < CC) m[tid] = mean_raw[p * CC + tid] * (1.f / HWP);
  __syncthreads();
  if (tid < CC) {
    const float* wr = sca_w + (size_t)(e * CC + tid) * CC;
    float acc = sca_b[e * CC + tid];
#pragma unroll 8
    for (int c = 0; c < CC; c++) acc = fmaf(wr[c], m[c], acc);
    sv[tid] = acc;
  }
  __syncthreads();
#pragma unroll
  for (int i = 0; i < 8; i++) {
    int idx = tid + i * 256;
    int o = idx >> 4, k0 = (idx & 15) * 8;
    float bt = beta[e * CC + o];
    const float* src = conv3_w + ((size_t)e * CC + o) * CC + k0;
    ushort* dst = W3eff + ((size_t)pc * CC + o) * CC + k0;
#pragma unroll
    for (int q = 0; q < 8; q++) dst[q] = f2bf(src[q] * sv[k0 + q] * bt);
  }
}

// ---------------- conv3 + residual + fused LN2 ----------------
__global__ __launch_bounds__(256, 2) void conv3_ln2_kernel(
    const ushort* __restrict__ W3eff, const float* __restrict__ b3eff,
    const ushort* __restrict__ yT, const ushort* __restrict__ featT,
    const int* __restrict__ pair_e, int pair_lo,
    ushort* __restrict__ x1T, ushort* __restrict__ xh2T) {
  __shared__ ushort Ws[CC * CC];
  __shared__ ushort As[CC * CC];
  int pc = blockIdx.z, p = pair_lo + pc, e = pair_e[p];
  int img = p / KT;
  int n0 = blockIdx.x * 128;
  int tid = threadIdx.x, lane = tid & 63, w = tid >> 6;
  stage_tile(W3eff + (size_t)pc * CC * CC, Ws, tid);
  stage_tile(yT + ((size_t)pc * HWP + n0) * CC, As, tid);
  __syncthreads();
  int wr = w >> 1, wc = w & 1, fr = lane & 15, kb0 = (lane >> 4) * 16, og = (lane >> 4) * 4;
  f32x4 acc[4][4] = {};
#pragma unroll
  for (int ks = 0; ks < 4; ks++) {
    bf16x8 a[4], b[4];
#pragma unroll
    for (int m = 0; m < 4; m++) a[m] = ldfrag(Ws, wr * 64 + m * 16 + fr, ks * 64 + kb0);
#pragma unroll
    for (int n = 0; n < 4; n++) b[n] = ldfrag(As, wc * 64 + n * 16 + fr, ks * 64 + kb0);
#pragma unroll
    for (int m = 0; m < 4; m++)
#pragma unroll
      for (int n = 0; n < 4; n++)
        acc[m][n] = __builtin_amdgcn_mfma_f32_16x16x32_bf16(a[m], b[n], acc[m][n], 0, 0, 0);
  }
  float s[4] = {}, s2[4] = {};
#pragma unroll
  for (int m = 0; m < 4; m++) {
    int o = wr * 64 + m * 16 + og;
    float4 bvv = *(const float4*)&b3eff[e * CC + o];
#pragma unroll
    for (int n = 0; n < 4; n++) {
      int px = wc * 64 + n * 16 + fr;
      ushort4 f4 = *(const ushort4*)(featT + ((size_t)img * HWP + n0 + px) * CC + o);
      f32x4 v = acc[m][n];
      v.x += bf2f(f4.x) + bvv.x; v.y += bf2f(f4.y) + bvv.y;
      v.z += bf2f(f4.z) + bvv.z; v.w += bf2f(f4.w) + bvv.w;
      acc[m][n] = v;
      s[n] += v.x + v.y + v.z + v.w;
      s2[n] += v.x * v.x + v.y * v.y + v.z * v.z + v.w * v.w;
    }
  }
#pragma unroll
  for (int n = 0; n < 4; n++) {
    s[n] += __shfl_xor(s[n], 16, 64); s[n] += __shfl_xor(s[n], 32, 64);
    s2[n] += __shfl_xor(s2[n], 16, 64); s2[n] += __shfl_xor(s2[n], 32, 64);
  }
  __syncthreads();
  float2* red = (float2*)As;
  if (lane < 16) {
#pragma unroll
    for (int n = 0; n < 4; n++) {
      float2 v; v.x = s[n]; v.y = s2[n];
      red[wr * 128 + wc * 64 + n * 16 + fr] = v;
    }
  }
  __syncthreads();
  float mu[4], rs[4];
#pragma unroll
  for (int n = 0; n < 4; n++) {
    int px = wc * 64 + n * 16 + fr;
    float2 r0 = red[px], r1 = red[128 + px];
    float m_ = (r0.x + r1.x) * (1.f / CC);
    float var = (r0.y + r1.y) * (1.f / CC) - m_ * m_;
    mu[n] = m_; rs[n] = rsqrtf(var + EPSLN);
  }
  __syncthreads();
#pragma unroll
  for (int m = 0; m < 4; m++) {
    int o = wr * 64 + m * 16 + og;
#pragma unroll
    for (int n = 0; n < 4; n++) {
      int px = wc * 64 + n * 16 + fr;
      f32x4 v = acc[m][n];
      stage8(As, px, o, pack4(v.x, v.y, v.z, v.w));
      stage8(Ws, px, o, pack4((v.x - mu[n]) * rs[n], (v.y - mu[n]) * rs[n],
                              (v.z - mu[n]) * rs[n], (v.w - mu[n]) * rs[n]));
    }
  }
  __syncthreads();
#pragma unroll
  for (int i = 0; i < 8; i++) {
    int idx = tid + i * 256;
    int px = idx >> 4, ck = idx & 15;
    size_t gb = ((size_t)pc * HWP + n0 + px) * CC;
    *(uint4*)((char*)(x1T + gb) + ck * 16)  = ldstage16(As, px, ck);
    *(uint4*)((char*)(xh2T + gb) + ck * 16) = ldstage16(Ws, px, ck);
  }
}

// ---------------- conv4 both halves + SimpleGate fused ----------------
__global__ __launch_bounds__(256, 2) void conv4sg_kernel(
    const ushort* __restrict__ W4eff, const float* __restrict__ b4eff,
    const ushort* __restrict__ xh2T, const int* __restrict__ pair_e,
    int pair_lo, ushort* __restrict__ g5T) {
  __shared__ ushort Ws[CC * CC];
  __shared__ ushort As[CC * CC];
  int pc = blockIdx.z, p = pair_lo + pc, e = pair_e[p];
  int n0 = blockIdx.x * 128;
  int tid = threadIdx.x, lane = tid & 63, w = tid >> 6;
  int wr = w >> 1, wc = w & 1, fr = lane & 15, kb0 = (lane >> 4) * 16, og = (lane >> 4) * 4;
  stage_tile(W4eff + (size_t)e * DWC * CC, Ws, tid);
  stage_tile(xh2T + ((size_t)pc * HWP + n0) * CC, As, tid);
  __syncthreads();
  f32x4 accA[4][4] = {}, accG[4][4] = {};
#pragma unroll
  for (int ks = 0; ks < 4; ks++) {
    bf16x8 a[4], b[4];
#pragma unroll
    for (int m = 0; m < 4; m++) a[m] = ldfrag(Ws, wr * 64 + m * 16 + fr, ks * 64 + kb0);
#pragma unroll
    for (int n = 0; n < 4; n++) b[n] = ldfrag(As, wc * 64 + n * 16 + fr, ks * 64 + kb0);
#pragma unroll
    for (int m = 0; m < 4; m++)
#pragma unroll
      for (int n = 0; n < 4; n++)
        accA[m][n] = __builtin_amdgcn_mfma_f32_16x16x32_bf16(a[m], b[n], accA[m][n], 0, 0, 0);
  }
  __syncthreads();
  stage_tile(W4eff + ((size_t)e * DWC + CC) * CC, Ws, tid);
  __syncthreads();
#pragma unroll
  for (int ks = 0; ks < 4; ks++) {
    bf16x8 a[4], b[4];
#pragma unroll
    for (int m = 0; m < 4; m++) a[m] = ldfrag(Ws, wr * 64 + m * 16 + fr, ks * 64 + kb0);
#pragma unroll
    for (int n = 0; n < 4; n++) b[n] = ldfrag(As, wc * 64 + n * 16 + fr, ks * 64 + kb0);
#pragma unroll
    for (int m = 0; m < 4; m++)
#pragma unroll
      for (int n = 0; n < 4; n++)
        accG[m][n] = __builtin_amdgcn_mfma_f32_16x16x32_bf16(a[m], b[n], accG[m][n], 0, 0, 0);
  }
  __syncthreads();
#pragma unroll
  for (int m = 0; m < 4; m++) {
    int o = wr * 64 + m * 16 + og;
    float4 ba = *(const float4*)&b4eff[e * DWC + o];
    float4 bg = *(const float4*)&b4eff[e * DWC + CC + o];
#pragma unroll
    for (int n = 0; n < 4; n++) {
      int px = wc * 64 + n * 16 + fr;
      f32x4 va = accA[m][n], vg = accG[m][n];
      stage8(Ws, px, o, pack4((va.x + ba.x) * (vg.x + bg.x), (va.y + ba.y) * (vg.y + bg.y),
                              (va.z + ba.z) * (vg.z + bg.z), (va.w + ba.w) * (vg.w + bg.w)));
    }
  }
  __syncthreads();
#pragma unroll
  for (int i = 0; i < 8; i++) {
    int idx = tid + i * 256;
    int px = idx >> 4, ck = idx & 15;
    uint4 v = ldstage16(Ws, px, ck);
    *(uint4*)((char*)(g5T + ((size_t)pc * HWP + n0 + px) * CC) + ck * 16) = v;
  }
}

// ---------------- conv5: 3-pair accumulated MFMA + transpose epilogue ----------------
__global__ __launch_bounds__(256, 2) void conv5_kernel(
    const ushort* __restrict__ W5eff, const float* __restrict__ b5tot,
    const ushort* __restrict__ g5T, const ushort* __restrict__ x1,
    const float* __restrict__ gate_w, int pair_lo, float* __restrict__ out) {
  __shared__ ushort Ws[CC * CC];
  __shared__ ushort As[CC * CC];
  int sl = blockIdx.z;
  int n0 = blockIdx.x * 128;
  int b = pair_lo / KT + sl;
  int tid = threadIdx.x, lane = tid & 63, w = tid >> 6;
  int wr = w >> 1, wc = w & 1;
  int fr = lane & 15, kb0 = (lane >> 4) * 16, og = (lane >> 4) * 4;
  f32x4 acc[4][4] = {};
  for (int j = 0; j < KT; j++) {
    int pc = sl * KT + j, p = pair_lo + pc;
    __syncthreads();
    stage_tile(W5eff + (size_t)p * CC * CC, Ws, tid);
    stage_tile(g5T + ((size_t)pc * HWP + n0) * CC, As, tid);
    __syncthreads();
#pragma unroll
    for (int ks = 0; ks < 4; ks++) {
      bf16x8 a[4], bfr[4];
#pragma unroll
      for (int m = 0; m < 4; m++) a[m] = ldfrag(Ws, wr * 64 + m * 16 + fr, ks * 64 + kb0);
#pragma unroll
      for (int n = 0; n < 4; n++) bfr[n] = ldfrag(As, wc * 64 + n * 16 + fr, ks * 64 + kb0);
#pragma unroll
      for (int m = 0; m < 4; m++)
#pragma unroll
        for (int n = 0; n < 4; n++)
          acc[m][n] = __builtin_amdgcn_mfma_f32_16x16x32_bf16(a[m], bfr[n], acc[m][n], 0, 0, 0);
    }
  }
  float gw0 = gate_w[pair_lo + sl * KT + 0];
  float gw1 = gate_w[pair_lo + sl * KT + 1];
  float gw2 = gate_w[pair_lo + sl * KT + 2];
  __syncthreads();
  ushort* Ct = As;
#pragma unroll
  for (int m = 0; m < 4; m++) {
    int o = wr * 64 + m * 16 + og;
    float4 bt = *(const float4*)&b5tot[b * CC + o];
#pragma unroll
    for (int n = 0; n < 4; n++) {
      int px = wc * 64 + n * 16 + fr;
      f32x4 v = acc[m][n];
      float r0 = v.x + bt.x, r1 = v.y + bt.y, r2 = v.z + bt.z, r3 = v.w + bt.w;
      size_t xoff = ((size_t)(sl * KT) * HWP + n0 + px) * CC + o;
      ushort4 xa = *(const ushort4*)(x1 + xoff);
      ushort4 xb = *(const ushort4*)(x1 + xoff + (size_t)HWP * CC);
      ushort4 xc = *(const ushort4*)(x1 + xoff + 2 * (size_t)HWP * CC);
      r0 += gw0 * bf2f(xa.x) + gw1 * bf2f(xb.x) + gw2 * bf2f(xc.x);
      r1 += gw0 * bf2f(xa.y) + gw1 * bf2f(xb.y) + gw2 * bf2f(xc.y);
      r2 += gw0 * bf2f(xa.z) + gw1 * bf2f(xb.z) + gw2 * bf2f(xc.z);
      r3 += gw0 * bf2f(xa.w) + gw1 * bf2f(xb.w) + gw2 * bf2f(xc.w);
      *(ushort*)((char*)Ct + (o+0) * 256 + ((px*2) ^ (((o+0) & 7) << 4))) = f2bf(r0);
      *(ushort*)((char*)Ct + (o+1) * 256 + ((px*2) ^ (((o+1) & 7) << 4))) = f2bf(r1);
      *(ushort*)((char*)Ct + (o+2) * 256 + ((px*2) ^ (((o+2) & 7) << 4))) = f2bf(r2);
      *(ushort*)((char*)Ct + (o+3) * 256 + ((px*2) ^ (((o+3) & 7) << 4))) = f2bf(r3);
    }
  }
  __syncthreads();
  int o = tid >> 1, ph = (tid & 1) * 64;
  float* orow = out + ((size_t)(b * CC + o)) * HWP + n0 + ph;
  int swz = (o & 7) << 4;
#pragma unroll
  for (int i = 0; i < 8; i++) {
    const ushort* lp = (const ushort*)((const char*)Ct + o * 256 + ((ph * 2 + i * 16) ^ swz));
    float4 f0, f1;
    f0.x = bf2f(lp[0]); f0.y = bf2f(lp[1]); f0.z = bf2f(lp[2]); f0.w = bf2f(lp[3]);
    f1.x = bf2f(lp[4]); f1.y = bf2f(lp[5]); f1.z = bf2f(lp[6]); f1.w = bf2f(lp[7]);
    *(float4*)(orow + i * 8) = f0;
    *(float4*)(orow + i * 8 + 4) = f1;
  }
}

extern "C" void kernel_launch(void* const* d_in, const int* in_sizes, int n_in,
                              void* d_out, int out_size, void* d_ws, size_t ws_size,
                              hipStream_t stream) {
  const float* feat    = (const float*)d_in[0];
  const float* weights = (const float*)d_in[1];
  const float* ln1_w   = (const float*)d_in[2];
  const float* ln1_b   = (const float*)d_in[3];
  const float* conv1_w = (const float*)d_in[4];
  const float* conv1_b = (const float*)d_in[5];
  const float* conv2_w = (const float*)d_in[6];
  const float* conv2_b = (const float*)d_in[7];
  const float* sca_w   = (const float*)d_in[8];
  const float* sca_b   = (const float*)d_in[9];
  const float* conv3_w = (const float*)d_in[10];
  const float* conv3_b = (const float*)d_in[11];
  const float* ln2_w   = (const float*)d_in[12];
  const float* ln2_b   = (const float*)d_in[13];
  const float* conv4_w = (const float*)d_in[14];
  const float* conv4_b = (const float*)d_in[15];
  const float* conv5_w = (const float*)d_in[16];
  const float* conv5_b = (const float*)d_in[17];
  const float* beta    = (const float*)d_in[18];
  const float* gamma   = (const float*)d_in[19];

  float* out = (float*)d_out;
  float* out_counts = out + (size_t)BB * CC * HWP;
  float* out_weights = out_counts + EN;

  char* base = (char*)d_ws;
  size_t off = 0;
  auto carveU = [&](size_t n) -> ushort* { ushort* p = (ushort*)(base + off); off += n * 2; return p; };
  auto carveF = [&](size_t n) -> float* { float* p = (float*)(base + off); off += n * 4; return p; };

  ushort* W1eff = carveU((size_t)EN * DWC * CC);
  ushort* W4eff = carveU((size_t)EN * DWC * CC);
  ushort* W5eff = carveU((size_t)NPAIR * CC * CC);
  ushort* W3eff = carveU((size_t)NPAIR * CC * CC);
  float* b1eff  = carveF(EN * DWC);
  float* b4eff  = carveF(EN * DWC);
  float* b3eff  = carveF(EN * CC);
  float* b5tot  = carveF(BB * CC);
  float* gate_w = carveF(64);
  int*   pair_e = (int*)carveF(64);
  float* mean_raw = carveF(NPAIR * CC);
  ushort* xhatT = carveU((size_t)BB * HWP * CC);
  ushort* featT = carveU((size_t)BB * HWP * CC);

  // per-pair: y (1MB, reused as xh2) + x1 (1MB) + g5 (1MB)
  const size_t per_pair = (size_t)3 * HWP * CC * 2;
  int ns = 16;
  while (ns > 1 && off + (size_t)ns * KT * per_pair > ws_size) ns >>= 1;
  size_t pr = (size_t)ns * KT;
  ushort* y_T   = carveU(pr * HWP * CC);
  ushort* x1_T  = carveU(pr * HWP * CC);
  ushort* g5_T  = carveU(pr * HWP * CC);
  ushort* xh2_T = y_T;   // alias: conv3_ln2 reads its own y tile to LDS before writing xh2

  gate_kernel<<<1, 256, 0, stream>>>(weights, gate_w, pair_e, out_counts, out_weights, mean_raw);
  fold_kernel<<<13, 256, 0, stream>>>(conv1_w, conv1_b, ln1_w, ln1_b,
                                      conv4_w, conv4_b, ln2_w, ln2_b,
                                      conv3_b, beta, W1eff, b1eff, W4eff, b4eff, b3eff);
  fold2_kernel<<<393, 256, 0, stream>>>(conv5_w, conv5_b, gamma, gate_w, pair_e, W5eff, b5tot);
  ln1_kernel<<<BB * 64, 256, 0, stream>>>(feat, xhatT, featT);

  for (int s0 = 0; s0 < BB; s0 += ns) {
    int np = ns * KT, plo = s0 * KT;
    c1dw_kernel<<<dim3(64, 1, np), 256, 0, stream>>>(W1eff, b1eff, xhatT, conv2_w, conv2_b,
                                                     pair_e, plo, y_T, mean_raw);
    sca_w3fold_kernel<<<np, 256, 0, stream>>>(mean_raw, sca_w, sca_b, conv3_w, beta,
                                              pair_e, plo, W3eff);
    conv3_ln2_kernel<<<dim3(32, 1, np), 256, 0, stream>>>(W3eff, b3eff, y_T, featT,
                                                          pair_e, plo, x1_T, xh2_T);
    conv4sg_kernel<<<dim3(32, 1, np), 256, 0, stream>>>(W4eff, b4eff, xh2_T, pair_e, plo, g5_T);
    conv5_kernel<<<dim3(32, 1, ns), 256, 0, stream>>>(W5eff, b5tot, g5_T, x1_T,
                                                      gate_w, plo, out);
  }
}

// Round 8
// 214.242 us; speedup vs baseline: 3.7043x; 1.0739x over previous
//
#include <hip/hip_runtime.h>

#define EN 5
#define KT 3
#define BB 16
#define CC 128
#define HWP 4096
#define DWC 256
#define NPAIR 48
#define EPSLN 1e-6f
#define HR 10        // 8x8 tile + 1px halo each side
#define HPX 100      // 10*10 halo pixels
#define TSTRIDE 106  // ushorts per Th channel row (212B; 53 words, odd -> all 32 banks)

typedef float f32x4 __attribute__((ext_vector_type(4)));
typedef __bf16 bf16x8 __attribute__((ext_vector_type(8)));

__device__ __forceinline__ float bf2f(ushort u) {
  union { unsigned int u; float f; } v; v.u = ((unsigned int)u) << 16; return v.f;
}
__device__ __forceinline__ uint cvtpk(float lo, float hi) {
  uint r;
  asm("v_cvt_pk_bf16_f32 %0, %1, %2" : "=v"(r) : "v"(lo), "v"(hi));
  return r;
}
__device__ __forceinline__ ushort f2bf(float f) {
  union { float f; unsigned int u; } v; v.f = f;
  unsigned int r = v.u + 0x7FFFu + ((v.u >> 16) & 1u);
  return (ushort)(r >> 16);
}
__device__ __forceinline__ ushort f2bf1(float f) {
  return (ushort)(cvtpk(f, f) & 0xffffu);
}
__device__ __forceinline__ ushort4 pack4(float a, float b, float c, float d) {
  union { uint2 u; ushort4 s; } v;
  v.u.x = cvtpk(a, b);
  v.u.y = cvtpk(c, d);
  return v.s;
}

// ---------------- gate ----------------
__global__ void gate_kernel(const float* __restrict__ weights, float* __restrict__ gate_w,
                            int* __restrict__ pair_e, float* __restrict__ out_counts,
                            float* __restrict__ out_weights, float* __restrict__ mean_raw) {
  __shared__ int sel[NPAIR];
  int tid = threadIdx.x;
  if (tid < BB) {
    float w[EN];
    for (int e = 0; e < EN; e++) w[e] = weights[tid * EN + e];
    int ch[KT]; float cv[KT]; float sum = 0.f;
    for (int j = 0; j < KT; j++) {
      int best = -1; float bv = -3.4e38f;
      for (int e = 0; e < EN; e++) {
        bool used = false;
        for (int q = 0; q < j; q++) if (ch[q] == e) used = true;
        if (!used && w[e] > bv) { bv = w[e]; best = e; }
      }
      ch[j] = best; cv[j] = bv; sum += bv;
    }
    float inv = 1.f / sum;
    for (int j = 0; j < KT; j++) {
      gate_w[tid * KT + j] = cv[j] * inv;
      pair_e[tid * KT + j] = ch[j];
      sel[tid * KT + j] = ch[j];
    }
  }
  for (int i = tid; i < NPAIR * CC; i += 256) mean_raw[i] = 0.f;
  __syncthreads();
  if (tid < EN) {
    int cnt = 0;
    for (int i = 0; i < NPAIR; i++) if (sel[i] == tid) cnt++;
    out_counts[tid] = (float)cnt;
  }
  if (tid < BB * EN) out_weights[tid] = weights[tid];
}

// ---------------- fold LN into conv1/conv4 ----------------
__global__ void fold_kernel(const float* __restrict__ conv1_w, const float* __restrict__ conv1_b,
                            const float* __restrict__ ln1_w, const float* __restrict__ ln1_b,
                            const float* __restrict__ conv4_w, const float* __restrict__ conv4_b,
                            const float* __restrict__ ln2_w, const float* __restrict__ ln2_b,
                            const float* __restrict__ conv3_b, const float* __restrict__ beta,
                            ushort* __restrict__ W1eff, float* __restrict__ b1eff,
                            ushort* __restrict__ W4eff, float* __restrict__ b4eff,
                            float* __restrict__ b3eff) {
  int gid = blockIdx.x * 256 + threadIdx.x;
  if (gid < 2 * EN * DWC) {
    int which = gid / (EN * DWC), rem = gid % (EN * DWC);
    int e = rem / DWC, o = rem % DWC;
    const float* src = (which ? conv4_w : conv1_w) + (size_t)(e * DWC + o) * CC;
    const float* lw = (which ? ln2_w : ln1_w) + e * CC;
    const float* lb = (which ? ln2_b : ln1_b) + e * CC;
    float bacc = (which ? conv4_b : conv1_b)[e * DWC + o];
    ushort* dst = (which ? W4eff : W1eff) + (size_t)(e * DWC + o) * CC;
    for (int c = 0; c < CC; c++) {
      float wv = src[c];
      dst[c] = f2bf(wv * lw[c]);
      bacc += wv * lb[c];
    }
    (which ? b4eff : b1eff)[e * DWC + o] = bacc;
  } else if (gid < 2 * EN * DWC + EN * CC) {
    int x = gid - 2 * EN * DWC;
    b3eff[x] = beta[x] * conv3_b[x];
  }
}

// ---------------- fold2: W5eff[p]=conv5_w[e]*gamma*gate; b5tot ----------------
__global__ void fold2_kernel(const float* __restrict__ conv5_w, const float* __restrict__ conv5_b,
                             const float* __restrict__ gamma, const float* __restrict__ gate_w,
                             const int* __restrict__ pair_e,
                             ushort* __restrict__ W5eff, float* __restrict__ b5tot) {
  int gid = blockIdx.x * 256 + threadIdx.x;
  const int nW = NPAIR * CC * CC / 8;
  if (gid < nW) {
    int base = gid * 8;
    int p = base >> 14, rem = base & 16383;
    int o = rem >> 7, k0 = rem & 127;
    int e = pair_e[p];
    float sc = gamma[e * CC + o] * gate_w[p];
    const float* src = conv5_w + ((size_t)e * CC + o) * CC + k0;
    ushort* dst = W5eff + ((size_t)p * CC + o) * CC + k0;
    for (int q = 0; q < 8; q++) dst[q] = f2bf(src[q] * sc);
  } else if (gid < nW + BB * CC) {
    int x = gid - nW;
    int b = x >> 7, o = x & 127;
    float s = 0.f;
    for (int j = 0; j < KT; j++) {
      int p = b * KT + j, e = pair_e[p];
      s += gate_w[p] * gamma[e * CC + o] * conv5_b[e * CC + o];
    }
    b5tot[x] = s;
  }
}

// ---------------- LN1 + transpose ----------------
__global__ __launch_bounds__(256) void ln1_kernel(const float* __restrict__ feat,
                                                  ushort* __restrict__ xhatT,
                                                  ushort* __restrict__ featT) {
  __shared__ float tile[CC * 64];
  __shared__ float pS[4][64], pS2[4][64], bcM[64], bcR[64];
  int bimg = blockIdx.x >> 6;
  int n0 = (blockIdx.x & 63) * 64;
  int tid = threadIdx.x;
  const float* src = feat + (size_t)bimg * CC * HWP + n0;
#pragma unroll
  for (int i = 0; i < 8; i++) {
    int ch = tid + i * 256;
    int row = ch >> 4, c16 = ch & 15;
    *(float4*)&tile[row * 64 + c16 * 4] = *(const float4*)(src + (size_t)row * HWP + c16 * 4);
  }
  __syncthreads();
  int lane = tid & 63, w = tid >> 6;
  float s = 0.f, s2 = 0.f;
#pragma unroll
  for (int i = 0; i < 32; i++) {
    float v = tile[(w * 32 + i) * 64 + lane];
    s += v; s2 += v * v;
  }
  pS[w][lane] = s; pS2[w][lane] = s2;
  __syncthreads();
  if (w == 0) {
    float t1 = pS[0][lane] + pS[1][lane] + pS[2][lane] + pS[3][lane];
    float t2 = pS2[0][lane] + pS2[1][lane] + pS2[2][lane] + pS2[3][lane];
    float mu = t1 * (1.f / CC);
    float var = t2 * (1.f / CC) - mu * mu;
    bcM[lane] = mu; bcR[lane] = rsqrtf(var + EPSLN);
  }
  __syncthreads();
  float mu = bcM[lane], r = bcR[lane];
  size_t obase = ((size_t)bimg * HWP + n0 + lane) * CC + w * 32;
#pragma unroll
  for (int i = 0; i < 4; i++) {
    float v[8];
#pragma unroll
    for (int q = 0; q < 8; q++) v[q] = tile[(w * 32 + i * 8 + q) * 64 + lane];
    *(ushort4*)(featT + obase + i * 8)     = pack4(v[0], v[1], v[2], v[3]);
    *(ushort4*)(featT + obase + i * 8 + 4) = pack4(v[4], v[5], v[6], v[7]);
    *(ushort4*)(xhatT + obase + i * 8)     = pack4((v[0]-mu)*r, (v[1]-mu)*r, (v[2]-mu)*r, (v[3]-mu)*r);
    *(ushort4*)(xhatT + obase + i * 8 + 4) = pack4((v[4]-mu)*r, (v[5]-mu)*r, (v[6]-mu)*r, (v[7]-mu)*r);
  }
}

// ---------------- shared helpers ----------------
__device__ __forceinline__ void stage_tile(const ushort* __restrict__ g, ushort* lds, int tid) {
#pragma unroll
  for (int i = 0; i < 8; i++) {
    int d = (tid + i * 256) * 16;
    int row = d >> 8;
    uint4 v = *(const uint4*)((const char*)g + d);
    *(uint4*)((char*)lds + (d ^ ((row & 7) << 4))) = v;
  }
}
__device__ __forceinline__ bf16x8 ldfrag(const ushort* lds, int row, int kb) {
  return *(const bf16x8*)((const char*)lds + row * 256 + (kb ^ ((row & 7) << 4)));
}
__device__ __forceinline__ void stage8(ushort* st, int px, int o, ushort4 v) {
  *(ushort4*)((char*)st + px * 256 + ((o * 2) ^ ((px & 7) << 4))) = v;
}
__device__ __forceinline__ uint4 ldstage16(const ushort* st, int px, int ck) {
  return *(const uint4*)((const char*)st + px * 256 + ((ck * 16) ^ ((px & 7) << 4)));
}

// ---------------- fused conv1 + depthwise3x3 + SimpleGate + mean (v3) ----------------
// Swapped-operand MFMA: D row = px, col = ch -> vectorized channel-major t stores.
__global__ __launch_bounds__(256, 3) void c1dw_kernel(
    const ushort* __restrict__ W1eff, const float* __restrict__ b1eff,
    const ushort* __restrict__ xhatT,
    const float* __restrict__ conv2_w, const float* __restrict__ conv2_b,
    const int* __restrict__ pair_e, int pair_lo,
    ushort* __restrict__ yT, float* __restrict__ mean_raw) {
  __shared__ __align__(16) char smem[DWC * TSTRIDE * 2];   // 54272 B
  int ts = blockIdx.x;
  int pc = blockIdx.z, p = pair_lo + pc, e = pair_e[p];
  int img = p / KT;
  int th = (ts >> 3) * 8, tw = (ts & 7) * 8;
  int tid = threadIdx.x, lane = tid & 63, w = tid >> 6;
  int fr = lane & 15, qf = lane >> 4;

  // phase 1: stage xhat halo (256B rows, swizzled)
#pragma unroll
  for (int i = 0; i < 7; i++) {
    int idx = tid + i * 256;
    if (idx < HPX * 16) {
      int r = idx >> 4, seg = idx & 15;
      int hy = r / HR, hx = r - hy * HR;
      int hh = th + hy - 1, ww = tw + hx - 1;
      int hc = min(max(hh, 0), 63), wc = min(max(ww, 0), 63);
      uint4 v = *(const uint4*)(xhatT + ((size_t)img * HWP + hc * 64 + wc) * CC + seg * 8);
      *(uint4*)(smem + r * 256 + ((seg * 16) ^ ((r & 7) << 4))) = v;
    }
  }
  __syncthreads();

  // phase 2: MFMA conv1, SWAPPED operands: a = halo px rows, b = W1eff ch rows.
  // D: row=(lane>>4)*4+reg = px (within nf group), col=lane&15 = ch (within mf group).
  f32x4 acc[7][4] = {};
#pragma unroll
  for (int ks = 0; ks < 4; ks++) {
    bf16x8 bfr[4];
#pragma unroll
    for (int mf = 0; mf < 4; mf++)
      bfr[mf] = *(const bf16x8*)(W1eff + (size_t)(e * DWC + w * 64 + mf * 16 + fr) * CC + ks * 32 + qf * 8);
#pragma unroll
    for (int nf = 0; nf < 7; nf++) {
      bf16x8 a = ldfrag((const ushort*)smem, nf * 16 + fr, ks * 64 + qf * 16);
#pragma unroll
      for (int mf = 0; mf < 4; mf++)
        acc[nf][mf] = __builtin_amdgcn_mfma_f32_16x16x32_bf16(a, bfr[mf], acc[nf][mf], 0, 0, 0);
    }
  }
  float bias[4];
#pragma unroll
  for (int mf = 0; mf < 4; mf++) bias[mf] = b1eff[e * DWC + w * 64 + mf * 16 + fr];
  __syncthreads();   // halo reads done; smem becomes channel-major Th

  // phase 3: t -> Th[ch][px], vectorized u32 stores (4 px per lane, cvt_pk packed).
  // No validity masking here: edge zero-padding applied in phase 4.
  ushort* Th = (ushort*)smem;
  int px0q = qf * 4;
#pragma unroll
  for (int nf = 0; nf < 7; nf++) {
    int px = nf * 16 + px0q;
    if (px < HPX) {
#pragma unroll
      for (int mf = 0; mf < 4; mf++) {
        int ch = w * 64 + mf * 16 + fr;
        f32x4 v = acc[nf][mf];
        float bb = bias[mf];
        uint u0 = cvtpk(v.x + bb, v.y + bb);
        uint u1 = cvtpk(v.z + bb, v.w + bb);
        ushort* dst = Th + ch * TSTRIDE + px;
        *(uint*)dst = u0;
        *(uint*)(dst + 2) = u1;
      }
    }
  }
  __syncthreads();

  // phase 4: depthwise 3x3 + SG with block-uniform edge zeroing.
  int cp = tid & 127, ph2 = tid >> 7;
  bool zTop = (ph2 == 0) && (th == 0);
  bool zBot = (ph2 == 1) && (th == 56);
  bool leftE = (tw == 0), rightE = (tw == 56);
  const float* wAp = conv2_w + ((size_t)e * DWC + cp) * 9;
  const float* wGp = conv2_w + ((size_t)(e * DWC + CC) + cp) * 9;
  float wA9[9], wG9[9];
#pragma unroll
  for (int k = 0; k < 9; k++) { wA9[k] = wAp[k]; wG9[k] = wGp[k]; }
  float ba = conv2_b[e * DWC + cp], bg = conv2_b[e * DWC + CC + cp];

  auto loadrowz = [&](float* dst, const ushort* pp, bool zrow) {
    if (zrow) {
#pragma unroll
      for (int q = 0; q < 10; q++) dst[q] = 0.f;
    } else {
#pragma unroll
      for (int q = 0; q < 5; q++) {
        uint u = *(const uint*)(pp + q * 2);
        dst[q * 2]     = bf2f((ushort)(u & 0xffffu));
        dst[q * 2 + 1] = bf2f((ushort)(u >> 16));
      }
      if (leftE) dst[0] = 0.f;
      if (rightE) dst[9] = 0.f;
    }
  };
  auto comp3 = [&](const float* w9, const float* r0, const float* r1, const float* r2, float* out) {
#pragma unroll
    for (int ox = 0; ox < 8; ox++) {
      float a = r0[ox] * w9[0];
      a = fmaf(r0[ox + 1], w9[1], a); a = fmaf(r0[ox + 2], w9[2], a);
      a = fmaf(r1[ox],     w9[3], a); a = fmaf(r1[ox + 1], w9[4], a);
      a = fmaf(r1[ox + 2], w9[5], a);
      a = fmaf(r2[ox],     w9[6], a); a = fmaf(r2[ox + 1], w9[7], a);
      a = fmaf(r2[ox + 2], w9[8], a);
      out[ox] = a;
    }
  };

  float win[3][10];
  float outv[4][8];
  {
    const ushort* rA = Th + cp * TSTRIDE + ph2 * 40;
    loadrowz(win[0], rA, zTop); loadrowz(win[1], rA + 10, false); loadrowz(win[2], rA + 20, false);
    comp3(wA9, win[0], win[1], win[2], outv[0]);
    loadrowz(win[0], rA + 30, false);
    comp3(wA9, win[1], win[2], win[0], outv[1]);
    loadrowz(win[1], rA + 40, false);
    comp3(wA9, win[2], win[0], win[1], outv[2]);
    loadrowz(win[2], rA + 50, zBot);
    comp3(wA9, win[0], win[1], win[2], outv[3]);
  }
  uint ypk[16];
  float csum = 0.f;
  {
    const ushort* rG = Th + (cp + 128) * TSTRIDE + ph2 * 40;
    float gtmp[8];
    loadrowz(win[0], rG, zTop); loadrowz(win[1], rG + 10, false); loadrowz(win[2], rG + 20, false);
#pragma unroll
    for (int oy = 0; oy < 4; oy++) {
      if (oy == 1) { loadrowz(win[0], rG + 30, false); }
      if (oy == 2) { loadrowz(win[1], rG + 40, false); }
      if (oy == 3) { loadrowz(win[2], rG + 50, zBot); }
      const float* r0 = (oy == 0) ? win[0] : (oy == 1) ? win[1] : (oy == 2) ? win[2] : win[0];
      const float* r1 = (oy == 0) ? win[1] : (oy == 1) ? win[2] : (oy == 2) ? win[0] : win[1];
      const float* r2 = (oy == 0) ? win[2] : (oy == 1) ? win[0] : (oy == 2) ? win[1] : win[2];
      comp3(wG9, r0, r1, r2, gtmp);
#pragma unroll
      for (int ox = 0; ox < 8; ox += 2) {
        float y0 = (outv[oy][ox]     + ba) * (gtmp[ox]     + bg);
        float y1 = (outv[oy][ox + 1] + ba) * (gtmp[ox + 1] + bg);
        csum += y0 + y1;
        ypk[oy * 4 + (ox >> 1)] = cvtpk(y0, y1);
      }
    }
  }
  __syncthreads();   // all Th reads done; smem becomes ystage + psum

  // phase 5: ystage scatter (swizzled), psum, coalesced drain + mean
  float* psum = (float*)(smem + 16384);
#pragma unroll
  for (int oy = 0; oy < 4; oy++)
#pragma unroll
    for (int ox = 0; ox < 8; ox++) {
      int opx = (ph2 * 4 + oy) * 8 + ox;
      uint pkv = ypk[oy * 4 + (ox >> 1)];
      ushort val = (ox & 1) ? (ushort)(pkv >> 16) : (ushort)(pkv & 0xffffu);
      *(ushort*)(smem + opx * 256 + ((cp * 2) ^ ((opx & 7) << 4))) = val;
    }
  psum[tid] = csum;
  __syncthreads();
#pragma unroll
  for (int i = 0; i < 4; i++) {
    int idx = tid + i * 256;
    int opx = idx >> 4, ck = idx & 15;
    uint4 v = *(const uint4*)(smem + opx * 256 + ((ck * 16) ^ ((opx & 7) << 4)));
    int n = (th + (opx >> 3)) * 64 + tw + (opx & 7);
    *(uint4*)((char*)(yT + ((size_t)pc * HWP + n) * CC) + ck * 16) = v;
  }
  if (tid < CC) {
    atomicAdd(&mean_raw[p * CC + tid], psum[tid] + psum[CC + tid]);
  }
}

// ---------------- SCA + W3eff fold merged ----------------
__global__ void sca_w3fold_kernel(const float* __restrict__ mean_raw,
                                  const float* __restrict__ sca_w, const float* __restrict__ sca_b,
                                  const float* __restrict__ conv3_w, const float* __restrict__ beta,
                                  const int* __restrict__ pair_e, int pair_lo,
                                  ushort* __restrict__ W3eff) {
  __shared__ float m[CC];
  __shared__ float sv[CC];
  int pc = blockIdx.x, p = pair_lo + pc, e = pair_e[p];
  int tid = threadIdx.x;
  if (tid < CC) m[tid] = mean_raw[p * CC + tid] * (1.f / HWP);
  __syncthreads();
  if (tid < CC) {
    const float* wr = sca_w + (size_t)(e * CC + tid) * CC;
    float acc = sca_b[e * CC + tid];
#pragma unroll 8
    for (int c = 0; c < CC; c++) acc = fmaf(wr[c], m[c], acc);
    sv[tid] = acc;
  }
  __syncthreads();
#pragma unroll
  for (int i = 0; i < 8; i++) {
    int idx = tid + i * 256;
    int o = idx >> 4, k0 = (idx & 15) * 8;
    float bt = beta[e * CC + o];
    const float* src = conv3_w + ((size_t)e * CC + o) * CC + k0;
    ushort* dst = W3eff + ((size_t)pc * CC + o) * CC + k0;
#pragma unroll
    for (int q = 0; q < 8; q++) dst[q] = f2bf(src[q] * sv[k0 + q] * bt);
  }
}

// ---------------- conv3 + residual + fused LN2 ----------------
__global__ __launch_bounds__(256, 2) void conv3_ln2_kernel(
    const ushort* __restrict__ W3eff, const float* __restrict__ b3eff,
    const ushort* __restrict__ yT, const ushort* __restrict__ featT,
    const int* __restrict__ pair_e, int pair_lo,
    ushort* __restrict__ x1T, ushort* __restrict__ xh2T) {
  __shared__ ushort Ws[CC * CC];
  __shared__ ushort As[CC * CC];
  int pc = blockIdx.z, p = pair_lo + pc, e = pair_e[p];
  int img = p / KT;
  int n0 = blockIdx.x * 128;
  int tid = threadIdx.x, lane = tid & 63, w = tid >> 6;
  stage_tile(W3eff + (size_t)pc * CC * CC, Ws, tid);
  stage_tile(yT + ((size_t)pc * HWP + n0) * CC, As, tid);
  __syncthreads();
  int wr = w >> 1, wc = w & 1, fr = lane & 15, kb0 = (lane >> 4) * 16, og = (lane >> 4) * 4;
  f32x4 acc[4][4] = {};
#pragma unroll
  for (int ks = 0; ks < 4; ks++) {
    bf16x8 a[4], b[4];
#pragma unroll
    for (int m = 0; m < 4; m++) a[m] = ldfrag(Ws, wr * 64 + m * 16 + fr, ks * 64 + kb0);
#pragma unroll
    for (int n = 0; n < 4; n++) b[n] = ldfrag(As, wc * 64 + n * 16 + fr, ks * 64 + kb0);
#pragma unroll
    for (int m = 0; m < 4; m++)
#pragma unroll
      for (int n = 0; n < 4; n++)
        acc[m][n] = __builtin_amdgcn_mfma_f32_16x16x32_bf16(a[m], b[n], acc[m][n], 0, 0, 0);
  }
  float s[4] = {}, s2[4] = {};
#pragma unroll
  for (int m = 0; m < 4; m++) {
    int o = wr * 64 + m * 16 + og;
    float4 bvv = *(const float4*)&b3eff[e * CC + o];
#pragma unroll
    for (int n = 0; n < 4; n++) {
      int px = wc * 64 + n * 16 + fr;
      ushort4 f4 = *(const ushort4*)(featT + ((size_t)img * HWP + n0 + px) * CC + o);
      f32x4 v = acc[m][n];
      v.x += bf2f(f4.x) + bvv.x; v.y += bf2f(f4.y) + bvv.y;
      v.z += bf2f(f4.z) + bvv.z; v.w += bf2f(f4.w) + bvv.w;
      acc[m][n] = v;
      s[n] += v.x + v.y + v.z + v.w;
      s2[n] += v.x * v.x + v.y * v.y + v.z * v.z + v.w * v.w;
    }
  }
#pragma unroll
  for (int n = 0; n < 4; n++) {
    s[n] += __shfl_xor(s[n], 16, 64); s[n] += __shfl_xor(s[n], 32, 64);
    s2[n] += __shfl_xor(s2[n], 16, 64); s2[n] += __shfl_xor(s2[n], 32, 64);
  }
  __syncthreads();
  float2* red = (float2*)As;
  if (lane < 16) {
#pragma unroll
    for (int n = 0; n < 4; n++) {
      float2 v; v.x = s[n]; v.y = s2[n];
      red[wr * 128 + wc * 64 + n * 16 + fr] = v;
    }
  }
  __syncthreads();
  float mu[4], rs[4];
#pragma unroll
  for (int n = 0; n < 4; n++) {
    int px = wc * 64 + n * 16 + fr;
    float2 r0 = red[px], r1 = red[128 + px];
    float m_ = (r0.x + r1.x) * (1.f / CC);
    float var = (r0.y + r1.y) * (1.f / CC) - m_ * m_;
    mu[n] = m_; rs[n] = rsqrtf(var + EPSLN);
  }
  __syncthreads();
#pragma unroll
  for (int m = 0; m < 4; m++) {
    int o = wr * 64 + m * 16 + og;
#pragma unroll
    for (int n = 0; n < 4; n++) {
      int px = wc * 64 + n * 16 + fr;
      f32x4 v = acc[m][n];
      stage8(As, px, o, pack4(v.x, v.y, v.z, v.w));
      stage8(Ws, px, o, pack4((v.x - mu[n]) * rs[n], (v.y - mu[n]) * rs[n],
                              (v.z - mu[n]) * rs[n], (v.w - mu[n]) * rs[n]));
    }
  }
  __syncthreads();
#pragma unroll
  for (int i = 0; i < 8; i++) {
    int idx = tid + i * 256;
    int px = idx >> 4, ck = idx & 15;
    size_t gb = ((size_t)pc * HWP + n0 + px) * CC;
    *(uint4*)((char*)(x1T + gb) + ck * 16)  = ldstage16(As, px, ck);
    *(uint4*)((char*)(xh2T + gb) + ck * 16) = ldstage16(Ws, px, ck);
  }
}

// ---------------- conv4 both halves + SimpleGate fused ----------------
__global__ __launch_bounds__(256, 2) void conv4sg_kernel(
    const ushort* __restrict__ W4eff, const float* __restrict__ b4eff,
    const ushort* __restrict__ xh2T, const int* __restrict__ pair_e,
    int pair_lo, ushort* __restrict__ g5T) {
  __shared__ ushort Ws[CC * CC];
  __shared__ ushort As[CC * CC];
  int pc = blockIdx.z, p = pair_lo + pc, e = pair_e[p];
  int n0 = blockIdx.x * 128;
  int tid = threadIdx.x, lane = tid & 63, w = tid >> 6;
  int wr = w >> 1, wc = w & 1, fr = lane & 15, kb0 = (lane >> 4) * 16, og = (lane >> 4) * 4;
  stage_tile(W4eff + (size_t)e * DWC * CC, Ws, tid);
  stage_tile(xh2T + ((size_t)pc * HWP + n0) * CC, As, tid);
  __syncthreads();
  f32x4 accA[4][4] = {}, accG[4][4] = {};
#pragma unroll
  for (int ks = 0; ks < 4; ks++) {
    bf16x8 a[4], b[4];
#pragma unroll
    for (int m = 0; m < 4; m++) a[m] = ldfrag(Ws, wr * 64 + m * 16 + fr, ks * 64 + kb0);
#pragma unroll
    for (int n = 0; n < 4; n++) b[n] = ldfrag(As, wc * 64 + n * 16 + fr, ks * 64 + kb0);
#pragma unroll
    for (int m = 0; m < 4; m++)
#pragma unroll
      for (int n = 0; n < 4; n++)
        accA[m][n] = __builtin_amdgcn_mfma_f32_16x16x32_bf16(a[m], b[n], accA[m][n], 0, 0, 0);
  }
  __syncthreads();
  stage_tile(W4eff + ((size_t)e * DWC + CC) * CC, Ws, tid);
  __syncthreads();
#pragma unroll
  for (int ks = 0; ks < 4; ks++) {
    bf16x8 a[4], b[4];
#pragma unroll
    for (int m = 0; m < 4; m++) a[m] = ldfrag(Ws, wr * 64 + m * 16 + fr, ks * 64 + kb0);
#pragma unroll
    for (int n = 0; n < 4; n++) b[n] = ldfrag(As, wc * 64 + n * 16 + fr, ks * 64 + kb0);
#pragma unroll
    for (int m = 0; m < 4; m++)
#pragma unroll
      for (int n = 0; n < 4; n++)
        accG[m][n] = __builtin_amdgcn_mfma_f32_16x16x32_bf16(a[m], b[n], accG[m][n], 0, 0, 0);
  }
  __syncthreads();
#pragma unroll
  for (int m = 0; m < 4; m++) {
    int o = wr * 64 + m * 16 + og;
    float4 ba = *(const float4*)&b4eff[e * DWC + o];
    float4 bg = *(const float4*)&b4eff[e * DWC + CC + o];
#pragma unroll
    for (int n = 0; n < 4; n++) {
      int px = wc * 64 + n * 16 + fr;
      f32x4 va = accA[m][n], vg = accG[m][n];
      stage8(Ws, px, o, pack4((va.x + ba.x) * (vg.x + bg.x), (va.y + ba.y) * (vg.y + bg.y),
                              (va.z + ba.z) * (vg.z + bg.z), (va.w + ba.w) * (vg.w + bg.w)));
    }
  }
  __syncthreads();
#pragma unroll
  for (int i = 0; i < 8; i++) {
    int idx = tid + i * 256;
    int px = idx >> 4, ck = idx & 15;
    uint4 v = ldstage16(Ws, px, ck);
    *(uint4*)((char*)(g5T + ((size_t)pc * HWP + n0 + px) * CC) + ck * 16) = v;
  }
}

// ---------------- conv5: 3-pair accumulated MFMA + transpose epilogue ----------------
__global__ __launch_bounds__(256, 2) void conv5_kernel(
    const ushort* __restrict__ W5eff, const float* __restrict__ b5tot,
    const ushort* __restrict__ g5T, const ushort* __restrict__ x1,
    const float* __restrict__ gate_w, int pair_lo, float* __restrict__ out) {
  __shared__ ushort Ws[CC * CC];
  __shared__ ushort As[CC * CC];
  int sl = blockIdx.z;
  int n0 = blockIdx.x * 128;
  int b = pair_lo / KT + sl;
  int tid = threadIdx.x, lane = tid & 63, w = tid >> 6;
  int wr = w >> 1, wc = w & 1;
  int fr = lane & 15, kb0 = (lane >> 4) * 16, og = (lane >> 4) * 4;
  f32x4 acc[4][4] = {};
  for (int j = 0; j < KT; j++) {
    int pc = sl * KT + j, p = pair_lo + pc;
    __syncthreads();
    stage_tile(W5eff + (size_t)p * CC * CC, Ws, tid);
    stage_tile(g5T + ((size_t)pc * HWP + n0) * CC, As, tid);
    __syncthreads();
#pragma unroll
    for (int ks = 0; ks < 4; ks++) {
      bf16x8 a[4], bfr[4];
#pragma unroll
      for (int m = 0; m < 4; m++) a[m] = ldfrag(Ws, wr * 64 + m * 16 + fr, ks * 64 + kb0);
#pragma unroll
      for (int n = 0; n < 4; n++) bfr[n] = ldfrag(As, wc * 64 + n * 16 + fr, ks * 64 + kb0);
#pragma unroll
      for (int m = 0; m < 4; m++)
#pragma unroll
        for (int n = 0; n < 4; n++)
          acc[m][n] = __builtin_amdgcn_mfma_f32_16x16x32_bf16(a[m], bfr[n], acc[m][n], 0, 0, 0);
    }
  }
  float gw0 = gate_w[pair_lo + sl * KT + 0];
  float gw1 = gate_w[pair_lo + sl * KT + 1];
  float gw2 = gate_w[pair_lo + sl * KT + 2];
  __syncthreads();
  ushort* Ct = As;
#pragma unroll
  for (int m = 0; m < 4; m++) {
    int o = wr * 64 + m * 16 + og;
    float4 bt = *(const float4*)&b5tot[b * CC + o];
#pragma unroll
    for (int n = 0; n < 4; n++) {
      int px = wc * 64 + n * 16 + fr;
      f32x4 v = acc[m][n];
      float r0 = v.x + bt.x, r1 = v.y + bt.y, r2 = v.z + bt.z, r3 = v.w + bt.w;
      size_t xoff = ((size_t)(sl * KT) * HWP + n0 + px) * CC + o;
      ushort4 xa = *(const ushort4*)(x1 + xoff);
      ushort4 xb = *(const ushort4*)(x1 + xoff + (size_t)HWP * CC);
      ushort4 xc = *(const ushort4*)(x1 + xoff + 2 * (size_t)HWP * CC);
      r0 += gw0 * bf2f(xa.x) + gw1 * bf2f(xb.x) + gw2 * bf2f(xc.x);
      r1 += gw0 * bf2f(xa.y) + gw1 * bf2f(xb.y) + gw2 * bf2f(xc.y);
      r2 += gw0 * bf2f(xa.z) + gw1 * bf2f(xb.z) + gw2 * bf2f(xc.z);
      r3 += gw0 * bf2f(xa.w) + gw1 * bf2f(xb.w) + gw2 * bf2f(xc.w);
      *(ushort*)((char*)Ct + (o+0) * 256 + ((px*2) ^ (((o+0) & 7) << 4))) = f2bf1(r0);
      *(ushort*)((char*)Ct + (o+1) * 256 + ((px*2) ^ (((o+1) & 7) << 4))) = f2bf1(r1);
      *(ushort*)((char*)Ct + (o+2) * 256 + ((px*2) ^ (((o+2) & 7) << 4))) = f2bf1(r2);
      *(ushort*)((char*)Ct + (o+3) * 256 + ((px*2) ^ (((o+3) & 7) << 4))) = f2bf1(r3);
    }
  }
  __syncthreads();
  int o = tid >> 1, ph = (tid & 1) * 64;
  float* orow = out + ((size_t)(b * CC + o)) * HWP + n0 + ph;
  int swz = (o & 7) << 4;
#pragma unroll
  for (int i = 0; i < 8; i++) {
    const ushort* lp = (const ushort*)((const char*)Ct + o * 256 + ((ph * 2 + i * 16) ^ swz));
    float4 f0, f1;
    f0.x = bf2f(lp[0]); f0.y = bf2f(lp[1]); f0.z = bf2f(lp[2]); f0.w = bf2f(lp[3]);
    f1.x = bf2f(lp[4]); f1.y = bf2f(lp[5]); f1.z = bf2f(lp[6]); f1.w = bf2f(lp[7]);
    *(float4*)(orow + i * 8) = f0;
    *(float4*)(orow + i * 8 + 4) = f1;
  }
}

extern "C" void kernel_launch(void* const* d_in, const int* in_sizes, int n_in,
                              void* d_out, int out_size, void* d_ws, size_t ws_size,
                              hipStream_t stream) {
  const float* feat    = (const float*)d_in[0];
  const float* weights = (const float*)d_in[1];
  const float* ln1_w   = (const float*)d_in[2];
  const float* ln1_b   = (const float*)d_in[3];
  const float* conv1_w = (const float*)d_in[4];
  const float* conv1_b = (const float*)d_in[5];
  const float* conv2_w = (const float*)d_in[6];
  const float* conv2_b = (const float*)d_in[7];
  const float* sca_w   = (const float*)d_in[8];
  const float* sca_b   = (const float*)d_in[9];
  const float* conv3_w = (const float*)d_in[10];
  const float* conv3_b = (const float*)d_in[11];
  const float* ln2_w   = (const float*)d_in[12];
  const float* ln2_b   = (const float*)d_in[13];
  const float* conv4_w = (const float*)d_in[14];
  const float* conv4_b = (const float*)d_in[15];
  const float* conv5_w = (const float*)d_in[16];
  const float* conv5_b = (const float*)d_in[17];
  const float* beta    = (const float*)d_in[18];
  const float* gamma   = (const float*)d_in[19];

  float* out = (float*)d_out;
  float* out_counts = out + (size_t)BB * CC * HWP;
  float* out_weights = out_counts + EN;

  char* base = (char*)d_ws;
  size_t off = 0;
  auto carveU = [&](size_t n) -> ushort* { ushort* p = (ushort*)(base + off); off += n * 2; return p; };
  auto carveF = [&](size_t n) -> float* { float* p = (float*)(base + off); off += n * 4; return p; };

  ushort* W1eff = carveU((size_t)EN * DWC * CC);
  ushort* W4eff = carveU((size_t)EN * DWC * CC);
  ushort* W5eff = carveU((size_t)NPAIR * CC * CC);
  ushort* W3eff = carveU((size_t)NPAIR * CC * CC);
  float* b1eff  = carveF(EN * DWC);
  float* b4eff  = carveF(EN * DWC);
  float* b3eff  = carveF(EN * CC);
  float* b5tot  = carveF(BB * CC);
  float* gate_w = carveF(64);
  int*   pair_e = (int*)carveF(64);
  float* mean_raw = carveF(NPAIR * CC);
  ushort* xhatT = carveU((size_t)BB * HWP * CC);
  ushort* featT = carveU((size_t)BB * HWP * CC);

  // per-pair: y (1MB, reused as xh2) + x1 (1MB) + g5 (1MB)
  const size_t per_pair = (size_t)3 * HWP * CC * 2;
  int ns = 16;
  while (ns > 1 && off + (size_t)ns * KT * per_pair > ws_size) ns >>= 1;
  size_t pr = (size_t)ns * KT;
  ushort* y_T   = carveU(pr * HWP * CC);
  ushort* x1_T  = carveU(pr * HWP * CC);
  ushort* g5_T  = carveU(pr * HWP * CC);
  ushort* xh2_T = y_T;   // alias: conv3_ln2 reads its own y tile to LDS before writing xh2

  gate_kernel<<<1, 256, 0, stream>>>(weights, gate_w, pair_e, out_counts, out_weights, mean_raw);
  fold_kernel<<<13, 256, 0, stream>>>(conv1_w, conv1_b, ln1_w, ln1_b,
                                      conv4_w, conv4_b, ln2_w, ln2_b,
                                      conv3_b, beta, W1eff, b1eff, W4eff, b4eff, b3eff);
  fold2_kernel<<<393, 256, 0, stream>>>(conv5_w, conv5_b, gamma, gate_w, pair_e, W5eff, b5tot);
  ln1_kernel<<<BB * 64, 256, 0, stream>>>(feat, xhatT, featT);

  for (int s0 = 0; s0 < BB; s0 += ns) {
    int np = ns * KT, plo = s0 * KT;
    c1dw_kernel<<<dim3(64, 1, np), 256, 0, stream>>>(W1eff, b1eff, xhatT, conv2_w, conv2_b,
                                                     pair_e, plo, y_T, mean_raw);
    sca_w3fold_kernel<<<np, 256, 0, stream>>>(mean_raw, sca_w, sca_b, conv3_w, beta,
                                              pair_e, plo, W3eff);
    conv3_ln2_kernel<<<dim3(32, 1, np), 256, 0, stream>>>(W3eff, b3eff, y_T, featT,
                                                          pair_e, plo, x1_T, xh2_T);
    conv4sg_kernel<<<dim3(32, 1, np), 256, 0, stream>>>(W4eff, b4eff, xh2_T, pair_e, plo, g5_T);
    conv5_kernel<<<dim3(32, 1, ns), 256, 0, stream>>>(W5eff, b5tot, g5_T, x1_T,
                                                      gate_w, plo, out);
  }
}